// Round 1
// baseline (1020.673 us; speedup 1.0000x reference)
//
#include <hip/hip_runtime.h>

static constexpr int BM = 64, BN = 64, BK = 16, TM = 4, TN = 4;

__device__ __forceinline__ void atomAddF(float* p, float v) {
    unsafeAtomicAdd(p, v);  // global_atomic_add_f32 on gfx950
}

// deg[col[e]] += 1
__global__ __launch_bounds__(256) void k_deg(const int* __restrict__ col,
                                             float* __restrict__ deg, int E) {
    int e = blockIdx.x * 256 + threadIdx.x;
    if (e < E) atomAddF(&deg[col[e]], 1.0f);
}

// deg -> deg^{-1/2} in place (0 where deg==0)
__global__ __launch_bounds__(256) void k_dis(float* __restrict__ deg, int n) {
    int i = blockIdx.x * 256 + threadIdx.x;
    if (i < n) {
        float d = deg[i];
        deg[i] = d > 0.f ? rsqrtf(d) : 0.f;
    }
}

// aggx[col] += norm * x[row]   (64 dims per edge; one lane per dim)
__global__ __launch_bounds__(256) void k_agg64(const float* __restrict__ x,
                                               const int* __restrict__ row,
                                               const int* __restrict__ col,
                                               const float* __restrict__ dis,
                                               float* __restrict__ aggx, int E) {
    long long gt = (long long)blockIdx.x * 256 + threadIdx.x;
    int e = (int)(gt >> 6);
    int d = (int)(gt & 63);
    if (e >= E) return;
    int r = row[e], c = col[e];
    float nrm = dis[r] * dis[c];
    float v = x[(long long)r * 64 + d] * nrm;
    atomAddF(&aggx[(long long)c * 64 + d], v);
}

// agg2[col] += norm * xw2[row]   (128 dims per edge)
__global__ __launch_bounds__(256) void k_agg128(const float* __restrict__ xw,
                                                const int* __restrict__ row,
                                                const int* __restrict__ col,
                                                const float* __restrict__ dis,
                                                float* __restrict__ agg, int E) {
    long long gt = (long long)blockIdx.x * 256 + threadIdx.x;
    int e = (int)(gt >> 7);
    int d = (int)(gt & 127);
    if (e >= E) return;
    int r = row[e], c = col[e];
    float nrm = dis[r] * dis[c];
    float v = xw[(long long)r * 128 + d] * nrm;
    atomAddF(&agg[(long long)c * 128 + d], v);
}

// out[col] += norm * s[row]   (scalar per edge)
__global__ __launch_bounds__(256) void k_agg1(const float* __restrict__ s,
                                              const int* __restrict__ row,
                                              const int* __restrict__ col,
                                              const float* __restrict__ dis,
                                              float* __restrict__ out, int E) {
    int e = blockIdx.x * 256 + threadIdx.x;
    if (e >= E) return;
    int r = row[e], c = col[e];
    atomAddF(&out[c], dis[r] * dis[c] * s[r]);
}

// C[M,N] = act(A[M,K] @ B[K,N] + bias); N multiple of 64, K multiple of 16.
// blockDim 256 = 16x16 threads, each computes 4x4 outputs.
__global__ __launch_bounds__(256) void k_gemm(const float* __restrict__ A, int lda,
                                              const float* __restrict__ B, int ldb,
                                              float* __restrict__ C, int ldc,
                                              const float* __restrict__ bias,
                                              int relu, int M, int K) {
    __shared__ float As[BK][BM + 4];
    __shared__ float Bs[BK][BN];
    int t = threadIdx.x;
    int tx = t & 15, ty = t >> 4;
    int row0 = blockIdx.x * BM;
    int col0 = blockIdx.y * BN;

    float acc[TM][TN] = {};

    for (int kt = 0; kt < K; kt += BK) {
        // A tile: 64x16. l -> (m = l/16, k = l%16): 16 consecutive lanes read
        // 16 consecutive floats of one row (64B segments).
        #pragma unroll
        for (int i = 0; i < 4; i++) {
            int l = i * 256 + t;
            int m = l >> 4;
            int k = l & 15;
            int gm = row0 + m;
            float v = 0.f;
            if (gm < M) v = A[(long long)gm * lda + kt + k];
            As[k][m] = v;
        }
        // B tile: 16x64, coalesced (n contiguous across lanes).
        #pragma unroll
        for (int i = 0; i < 4; i++) {
            int l = i * 256 + t;
            int n = l & 63;
            int k = l >> 6;
            Bs[k][n] = B[(long long)(kt + k) * ldb + col0 + n];
        }
        __syncthreads();
        #pragma unroll
        for (int k = 0; k < BK; k++) {
            float4 a4 = *reinterpret_cast<const float4*>(&As[k][ty * TM]);
            float4 b4 = *reinterpret_cast<const float4*>(&Bs[k][tx * TN]);
            float a[TM] = {a4.x, a4.y, a4.z, a4.w};
            float b[TN] = {b4.x, b4.y, b4.z, b4.w};
            #pragma unroll
            for (int i = 0; i < TM; i++)
                #pragma unroll
                for (int j = 0; j < TN; j++)
                    acc[i][j] += a[i] * b[j];
        }
        __syncthreads();
    }

    #pragma unroll
    for (int i = 0; i < TM; i++) {
        int gm = row0 + ty * TM + i;
        if (gm >= M) continue;
        #pragma unroll
        for (int j = 0; j < TN; j++) {
            int gn = col0 + tx * TN + j;
            float v = acc[i][j];
            if (bias) v += bias[gn];
            if (relu) v = fmaxf(v, 0.f);
            C[(long long)gm * ldc + gn] = v;
        }
    }
}

// x7 = x5 + relu(agg2 + b_conv2)  (in place into x5)
__global__ __launch_bounds__(256) void k_x7(float* __restrict__ x5,
                                            const float* __restrict__ agg2,
                                            const float* __restrict__ b2, int total) {
    int i = blockIdx.x * 256 + threadIdx.x;
    if (i < total) {
        float v = agg2[i] + b2[i & 127];
        x5[i] += fmaxf(v, 0.f);
    }
}

// per node: out[n] = x7[n]·w_fc2 + b_fc2 + b_conv3 ; xw3[n] = x7[n]·w_conv3
__global__ __launch_bounds__(256) void k_dot(const float* __restrict__ x7,
                                             const float* __restrict__ wfc2,
                                             const float* __restrict__ bfc2,
                                             const float* __restrict__ wc3,
                                             const float* __restrict__ bc3,
                                             float* __restrict__ out,
                                             float* __restrict__ xw3, int n) {
    int lane = threadIdx.x & 63;
    int wv = threadIdx.x >> 6;
    int node = blockIdx.x * 4 + wv;
    if (node >= n) return;
    const float* xr = x7 + (long long)node * 128;
    float v0 = xr[lane], v1 = xr[64 + lane];
    float s1 = v0 * wfc2[lane] + v1 * wfc2[64 + lane];
    float s2 = v0 * wc3[lane] + v1 * wc3[64 + lane];
    #pragma unroll
    for (int o = 32; o > 0; o >>= 1) {
        s1 += __shfl_down(s1, o);
        s2 += __shfl_down(s2, o);
    }
    if (lane == 0) {
        out[node] = s1 + bfc2[0] + bc3[0];
        xw3[node] = s2;
    }
}

extern "C" void kernel_launch(void* const* d_in, const int* in_sizes, int n_in,
                              void* d_out, int out_size, void* d_ws, size_t ws_size,
                              hipStream_t stream) {
    const float* x       = (const float*)d_in[0];
    const int*   ei      = (const int*)d_in[1];
    const float* w_fc    = (const float*)d_in[2];
    const float* b_fc    = (const float*)d_in[3];
    const float* w_conv1 = (const float*)d_in[4];
    const float* b_conv1 = (const float*)d_in[5];
    const float* w_fc1   = (const float*)d_in[6];
    const float* b_fc1   = (const float*)d_in[7];
    const float* w_conv2 = (const float*)d_in[8];
    const float* b_conv2 = (const float*)d_in[9];
    const float* w_fc2   = (const float*)d_in[10];
    const float* b_fc2   = (const float*)d_in[11];
    const float* w_conv3 = (const float*)d_in[12];
    const float* b_conv3 = (const float*)d_in[13];

    const int N = in_sizes[0] / 64;       // 50000
    const int E = in_sizes[1] / 2;        // 800000
    const int* row = ei;
    const int* col = ei + E;

    float* ws   = (float*)d_ws;
    float* dis  = ws;                         // N
    float* aggx = dis  + N;                   // N*64
    float* x3   = aggx + (long long)N * 64;   // N*512  (x1 | x2)
    float* x5   = x3   + (long long)N * 512;  // N*128  (becomes x7)
    float* xw2  = x5   + (long long)N * 128;  // N*128
    float* agg2 = xw2  + (long long)N * 128;  // N*128
    float* xw3  = agg2 + (long long)N * 128;  // N

    float* out = (float*)d_out;

    // zero accumulation buffers (ws is poisoned 0xAA before every call)
    hipMemsetAsync(dis,  0, (size_t)N * sizeof(float), stream);
    hipMemsetAsync(aggx, 0, (size_t)N * 64 * sizeof(float), stream);
    hipMemsetAsync(agg2, 0, (size_t)N * 128 * sizeof(float), stream);

    // degree + norm
    k_deg<<<(E + 255) / 256, 256, 0, stream>>>(col, dis, E);
    k_dis<<<(N + 255) / 256, 256, 0, stream>>>(dis, N);

    // conv1: propagate-then-transform. aggx = A_norm @ x
    k_agg64<<<(int)(((long long)E * 64 + 255) / 256), 256, 0, stream>>>(
        x, row, col, dis, aggx, E);

    dim3 g1((N + BM - 1) / BM, 256 / BN);   // (782, 4)
    dim3 g2((N + BM - 1) / BM, 128 / BN);   // (782, 2)

    // x1 = relu(x @ w_fc + b_fc)        -> x3[:, 0:256]
    k_gemm<<<g1, 256, 0, stream>>>(x, 64, w_fc, 256, x3, 512, b_fc, 1, N, 64);
    // x2 = relu(aggx @ w_conv1 + b_conv1) -> x3[:, 256:512]
    k_gemm<<<g1, 256, 0, stream>>>(aggx, 64, w_conv1, 256, x3 + 256, 512, b_conv1, 1, N, 64);

    // x5 = relu(x3 @ w_fc1 + b_fc1)
    k_gemm<<<g2, 256, 0, stream>>>(x3, 512, w_fc1, 128, x5, 128, b_fc1, 1, N, 512);
    // xw2 = x3 @ w_conv2   (transform-then-propagate)
    k_gemm<<<g2, 256, 0, stream>>>(x3, 512, w_conv2, 128, xw2, 128, nullptr, 0, N, 512);

    // agg2 = A_norm @ xw2
    k_agg128<<<(int)(((long long)E * 128 + 255) / 256), 256, 0, stream>>>(
        xw2, row, col, dis, agg2, E);

    // x7 = x5 + relu(agg2 + b_conv2)   (in place in x5)
    k_x7<<<((N * 128) + 255) / 256, 256, 0, stream>>>(x5, agg2, b_conv2, N * 128);

    // out = x7 @ w_fc2 + b_fc2 + b_conv3 ; xw3 = x7 @ w_conv3
    k_dot<<<(N + 3) / 4, 256, 0, stream>>>(x5, w_fc2, b_fc2, w_conv3, b_conv3, out, xw3, N);

    // out[col] += norm * xw3[row]
    k_agg1<<<(E + 255) / 256, 256, 0, stream>>>(xw3, row, col, dis, out, E);
}

// Round 2
// 640.753 us; speedup vs baseline: 1.5929x; 1.5929x over previous
//
#include <hip/hip_runtime.h>

static constexpr int BM = 64, BN = 64, BK = 16, TM = 4, TN = 4;

// ---------------- CSR build ----------------

// degi[col[e]] += 1
__global__ __launch_bounds__(256) void k_count(const int* __restrict__ col,
                                               int* __restrict__ degi, int E) {
    int e = blockIdx.x * 256 + threadIdx.x;
    if (e < E) atomicAdd(&degi[col[e]], 1);
}

// per-block exclusive scan of degi -> excl (within-block), block totals -> bsum
__global__ __launch_bounds__(256) void k_scan1(const int* __restrict__ degi,
                                               int* __restrict__ excl,
                                               int* __restrict__ bsum, int n) {
    int i = blockIdx.x * 256 + threadIdx.x;
    int v = (i < n) ? degi[i] : 0;
    int lane = threadIdx.x & 63, w = threadIdx.x >> 6;
    int s = v;
    #pragma unroll
    for (int o = 1; o < 64; o <<= 1) {
        int t = __shfl_up(s, o);
        if (lane >= o) s += t;
    }
    __shared__ int wsum[4];
    if (lane == 63) wsum[w] = s;
    __syncthreads();
    int add = 0;
    for (int ww = 0; ww < w; ww++) add += wsum[ww];
    int incl = s + add;
    if (i < n) excl[i] = incl - v;
    if (threadIdx.x == 255) bsum[blockIdx.x] = incl;
}

// single-block exclusive scan of bsum[nb] in place (nb <= 256)
__global__ __launch_bounds__(256) void k_scan2(int* __restrict__ bsum, int nb) {
    int i = threadIdx.x;
    int v = (i < nb) ? bsum[i] : 0;
    int lane = i & 63, w = i >> 6;
    int s = v;
    #pragma unroll
    for (int o = 1; o < 64; o <<= 1) {
        int t = __shfl_up(s, o);
        if (lane >= o) s += t;
    }
    __shared__ int wsum[4];
    if (lane == 63) wsum[w] = s;
    __syncthreads();
    int add = 0;
    for (int ww = 0; ww < w; ww++) add += wsum[ww];
    if (i < nb) bsum[i] = (s + add) - v;  // exclusive
}

// rowptr = excl + bsum[block]; cursor = rowptr; dis = deg^-1/2; rowptr[n]=E
__global__ __launch_bounds__(256) void k_scan3(const int* __restrict__ excl,
                                               const int* __restrict__ bsum,
                                               const int* __restrict__ degi,
                                               int* __restrict__ rowptr,
                                               int* __restrict__ cursor,
                                               float* __restrict__ dis,
                                               int n, int E) {
    int i = blockIdx.x * 256 + threadIdx.x;
    if (i < n) {
        int p = excl[i] + bsum[blockIdx.x];
        rowptr[i] = p;
        cursor[i] = p;
        int d = degi[i];
        dis[i] = d > 0 ? rsqrtf((float)d) : 0.f;
    }
    if (i == 0) rowptr[n] = E;
}

// scatter edges into CSR slots: csr_row[p] = row, csr_nrm[p] = dis[row]*dis[col]
__global__ __launch_bounds__(256) void k_scatter(const int* __restrict__ row,
                                                 const int* __restrict__ col,
                                                 const float* __restrict__ dis,
                                                 int* __restrict__ cursor,
                                                 int* __restrict__ csr_row,
                                                 float* __restrict__ csr_nrm, int E) {
    int e = blockIdx.x * 256 + threadIdx.x;
    if (e >= E) return;
    int c = col[e], r = row[e];
    int p = atomicAdd(&cursor[c], 1);
    csr_row[p] = r;
    csr_nrm[p] = dis[r] * dis[c];
}

// ---------------- CSR aggregations (gather, no atomics) ----------------

// aggx[node][0:64] = sum_e nrm * x[row_e][0:64] ; one wave per node, 1 lane/dim
__global__ __launch_bounds__(256) void k_agg64_csr(const float* __restrict__ x,
                                                   const int* __restrict__ rowptr,
                                                   const int* __restrict__ csr_row,
                                                   const float* __restrict__ csr_nrm,
                                                   float* __restrict__ aggx, int n) {
    int node = blockIdx.x * 4 + (threadIdx.x >> 6);
    if (node >= n) return;
    int lane = threadIdx.x & 63;
    int s = rowptr[node], t = rowptr[node + 1];
    float acc = 0.f;
    for (int p = s; p < t; ++p) {
        int r = csr_row[p];          // wave-uniform
        float w = csr_nrm[p];        // wave-uniform
        acc += w * x[(long long)r * 64 + lane];
    }
    aggx[(long long)node * 64 + lane] = acc;
}

// x7 fused: x5[node] += relu( (sum_e nrm * xw[row_e]) + b2 ) ; wave/node, float2/lane
__global__ __launch_bounds__(256) void k_agg128_x7(const float* __restrict__ xw,
                                                   const int* __restrict__ rowptr,
                                                   const int* __restrict__ csr_row,
                                                   const float* __restrict__ csr_nrm,
                                                   const float* __restrict__ b2,
                                                   float* __restrict__ x5, int n) {
    int node = blockIdx.x * 4 + (threadIdx.x >> 6);
    if (node >= n) return;
    int lane = threadIdx.x & 63;
    int s = rowptr[node], t = rowptr[node + 1];
    float2 acc = {0.f, 0.f};
    for (int p = s; p < t; ++p) {
        int r = csr_row[p];
        float w = csr_nrm[p];
        float2 v = *reinterpret_cast<const float2*>(&xw[(long long)r * 128 + lane * 2]);
        acc.x += w * v.x;
        acc.y += w * v.y;
    }
    float2 b = *reinterpret_cast<const float2*>(&b2[lane * 2]);
    float2* o = reinterpret_cast<float2*>(&x5[(long long)node * 128 + lane * 2]);
    float2 cur = *o;
    cur.x += fmaxf(acc.x + b.x, 0.f);
    cur.y += fmaxf(acc.y + b.y, 0.f);
    *o = cur;
}

// out[node] += sum_e nrm * s[row_e] ; thread per node (s is 200KB, L2-resident)
__global__ __launch_bounds__(256) void k_agg1_csr(const float* __restrict__ sv,
                                                  const int* __restrict__ rowptr,
                                                  const int* __restrict__ csr_row,
                                                  const float* __restrict__ csr_nrm,
                                                  float* __restrict__ out, int n) {
    int i = blockIdx.x * 256 + threadIdx.x;
    if (i >= n) return;
    int s = rowptr[i], t = rowptr[i + 1];
    float a = 0.f;
    for (int p = s; p < t; ++p) a += csr_nrm[p] * sv[csr_row[p]];
    out[i] += a;
}

// ---------------- GEMMs ----------------

// C[M,N] = act(A[M,K] @ B[K,N] + bias); N multiple of 64, K multiple of 16.
__global__ __launch_bounds__(256) void k_gemm(const float* __restrict__ A, int lda,
                                              const float* __restrict__ B, int ldb,
                                              float* __restrict__ C, int ldc,
                                              const float* __restrict__ bias,
                                              int relu, int M, int K) {
    __shared__ float As[BK][BM + 4];
    __shared__ float Bs[BK][BN];
    int t = threadIdx.x;
    int tx = t & 15, ty = t >> 4;
    int row0 = blockIdx.x * BM;
    int col0 = blockIdx.y * BN;

    float acc[TM][TN] = {};

    for (int kt = 0; kt < K; kt += BK) {
        #pragma unroll
        for (int i = 0; i < 4; i++) {
            int l = i * 256 + t;
            int m = l >> 4;
            int k = l & 15;
            int gm = row0 + m;
            float v = 0.f;
            if (gm < M) v = A[(long long)gm * lda + kt + k];
            As[k][m] = v;
        }
        #pragma unroll
        for (int i = 0; i < 4; i++) {
            int l = i * 256 + t;
            int nn = l & 63;
            int k = l >> 6;
            Bs[k][nn] = B[(long long)(kt + k) * ldb + col0 + nn];
        }
        __syncthreads();
        #pragma unroll
        for (int k = 0; k < BK; k++) {
            float4 a4 = *reinterpret_cast<const float4*>(&As[k][ty * TM]);
            float4 b4 = *reinterpret_cast<const float4*>(&Bs[k][tx * TN]);
            #pragma unroll
            for (int i = 0; i < TM; i++) {
                float a = (&a4.x)[i];
                #pragma unroll
                for (int j = 0; j < TN; j++)
                    acc[i][j] += a * (&b4.x)[j];
            }
        }
        __syncthreads();
    }

    #pragma unroll
    for (int i = 0; i < TM; i++) {
        int gm = row0 + ty * TM + i;
        if (gm >= M) continue;
        #pragma unroll
        for (int j = 0; j < TN; j++) {
            int gn = col0 + tx * TN + j;
            float v = acc[i][j];
            if (bias) v += bias[gn];
            if (relu) v = fmaxf(v, 0.f);
            C[(long long)gm * ldc + gn] = v;
        }
    }
}

// Dual-output GEMM sharing the A tile:
//   C1 = relu(A @ B1 + bias1),  C2 = A @ B2   (both [M,128], same 64-col band)
__global__ __launch_bounds__(256) void k_gemm2(const float* __restrict__ A, int lda,
                                               const float* __restrict__ B1,
                                               const float* __restrict__ B2, int ldb,
                                               float* __restrict__ C1,
                                               float* __restrict__ C2, int ldc,
                                               const float* __restrict__ bias1,
                                               int M, int K) {
    __shared__ float As[BK][BM + 4];
    __shared__ float Bs1[BK][BN];
    __shared__ float Bs2[BK][BN];
    int t = threadIdx.x;
    int tx = t & 15, ty = t >> 4;
    int row0 = blockIdx.x * BM;
    int col0 = blockIdx.y * BN;

    float acc1[TM][TN] = {};
    float acc2[TM][TN] = {};

    for (int kt = 0; kt < K; kt += BK) {
        #pragma unroll
        for (int i = 0; i < 4; i++) {
            int l = i * 256 + t;
            int m = l >> 4;
            int k = l & 15;
            int gm = row0 + m;
            float v = 0.f;
            if (gm < M) v = A[(long long)gm * lda + kt + k];
            As[k][m] = v;
        }
        #pragma unroll
        for (int i = 0; i < 4; i++) {
            int l = i * 256 + t;
            int nn = l & 63;
            int k = l >> 6;
            Bs1[k][nn] = B1[(long long)(kt + k) * ldb + col0 + nn];
            Bs2[k][nn] = B2[(long long)(kt + k) * ldb + col0 + nn];
        }
        __syncthreads();
        #pragma unroll
        for (int k = 0; k < BK; k++) {
            float4 a4 = *reinterpret_cast<const float4*>(&As[k][ty * TM]);
            float4 b4 = *reinterpret_cast<const float4*>(&Bs1[k][tx * TN]);
            float4 c4 = *reinterpret_cast<const float4*>(&Bs2[k][tx * TN]);
            #pragma unroll
            for (int i = 0; i < TM; i++) {
                float a = (&a4.x)[i];
                #pragma unroll
                for (int j = 0; j < TN; j++) {
                    acc1[i][j] += a * (&b4.x)[j];
                    acc2[i][j] += a * (&c4.x)[j];
                }
            }
        }
        __syncthreads();
    }

    #pragma unroll
    for (int i = 0; i < TM; i++) {
        int gm = row0 + ty * TM + i;
        if (gm >= M) continue;
        #pragma unroll
        for (int j = 0; j < TN; j++) {
            int gn = col0 + tx * TN + j;
            float v1 = acc1[i][j] + bias1[gn];
            C1[(long long)gm * ldc + gn] = fmaxf(v1, 0.f);
            C2[(long long)gm * ldc + gn] = acc2[i][j];
        }
    }
}

// per node: out[n] = x7[n]·w_fc2 + b_fc2 + b_conv3 ; xw3[n] = x7[n]·w_conv3
__global__ __launch_bounds__(256) void k_dot(const float* __restrict__ x7,
                                             const float* __restrict__ wfc2,
                                             const float* __restrict__ bfc2,
                                             const float* __restrict__ wc3,
                                             const float* __restrict__ bc3,
                                             float* __restrict__ out,
                                             float* __restrict__ xw3, int n) {
    int lane = threadIdx.x & 63;
    int wv = threadIdx.x >> 6;
    int node = blockIdx.x * 4 + wv;
    if (node >= n) return;
    const float* xr = x7 + (long long)node * 128;
    float v0 = xr[lane], v1 = xr[64 + lane];
    float s1 = v0 * wfc2[lane] + v1 * wfc2[64 + lane];
    float s2 = v0 * wc3[lane] + v1 * wc3[64 + lane];
    #pragma unroll
    for (int o = 32; o > 0; o >>= 1) {
        s1 += __shfl_down(s1, o);
        s2 += __shfl_down(s2, o);
    }
    if (lane == 0) {
        out[node] = s1 + bfc2[0] + bc3[0];
        xw3[node] = s2;
    }
}

extern "C" void kernel_launch(void* const* d_in, const int* in_sizes, int n_in,
                              void* d_out, int out_size, void* d_ws, size_t ws_size,
                              hipStream_t stream) {
    const float* x       = (const float*)d_in[0];
    const int*   ei      = (const int*)d_in[1];
    const float* w_fc    = (const float*)d_in[2];
    const float* b_fc    = (const float*)d_in[3];
    const float* w_conv1 = (const float*)d_in[4];
    const float* b_conv1 = (const float*)d_in[5];
    const float* w_fc1   = (const float*)d_in[6];
    const float* b_fc1   = (const float*)d_in[7];
    const float* w_conv2 = (const float*)d_in[8];
    const float* b_conv2 = (const float*)d_in[9];
    const float* w_fc2   = (const float*)d_in[10];
    const float* b_fc2   = (const float*)d_in[11];
    const float* w_conv3 = (const float*)d_in[12];
    const float* b_conv3 = (const float*)d_in[13];

    const int N = in_sizes[0] / 64;       // 50000
    const int E = in_sizes[1] / 2;        // 800000
    const int* row = ei;
    const int* col = ei + E;

    const int nb = (N + 255) / 256;       // 196 scan blocks

    // workspace layout
    char* p = (char*)d_ws;
    auto alloc = [&](size_t elems) { void* q = p; p += elems * 4; return q; };
    int*   degi    = (int*)  alloc(N);
    int*   excl    = (int*)  alloc(N);
    int*   bsum    = (int*)  alloc(256);
    int*   rowptr  = (int*)  alloc(N + 2);
    int*   cursor  = (int*)  alloc(N);
    int*   csr_row = (int*)  alloc(E);
    float* csr_nrm = (float*)alloc(E);
    float* dis     = (float*)alloc(N);
    float* aggx    = (float*)alloc((size_t)N * 64);
    float* x3      = (float*)alloc((size_t)N * 512);
    float* x5      = (float*)alloc((size_t)N * 128);
    float* xw2     = (float*)alloc((size_t)N * 128);
    float* xw3     = (float*)alloc(N);

    float* out = (float*)d_out;

    // ---- CSR build ----
    hipMemsetAsync(degi, 0, (size_t)N * sizeof(int), stream);
    k_count<<<(E + 255) / 256, 256, 0, stream>>>(col, degi, E);
    k_scan1<<<nb, 256, 0, stream>>>(degi, excl, bsum, N);
    k_scan2<<<1, 256, 0, stream>>>(bsum, nb);
    k_scan3<<<nb, 256, 0, stream>>>(excl, bsum, degi, rowptr, cursor, dis, N, E);
    k_scatter<<<(E + 255) / 256, 256, 0, stream>>>(row, col, dis, cursor, csr_row, csr_nrm, E);

    // conv1 propagate: aggx = A_norm @ x
    k_agg64_csr<<<(N + 3) / 4, 256, 0, stream>>>(x, rowptr, csr_row, csr_nrm, aggx, N);

    dim3 g1((N + BM - 1) / BM, 256 / BN);   // (782, 4)
    dim3 g2((N + BM - 1) / BM, 128 / BN);   // (782, 2)

    // x1 = relu(x @ w_fc + b_fc)          -> x3[:, 0:256]
    k_gemm<<<g1, 256, 0, stream>>>(x, 64, w_fc, 256, x3, 512, b_fc, 1, N, 64);
    // x2 = relu(aggx @ w_conv1 + b_conv1) -> x3[:, 256:512]
    k_gemm<<<g1, 256, 0, stream>>>(aggx, 64, w_conv1, 256, x3 + 256, 512, b_conv1, 1, N, 64);

    // x5 = relu(x3 @ w_fc1 + b_fc1) ; xw2 = x3 @ w_conv2  (shared A tiles)
    k_gemm2<<<g2, 256, 0, stream>>>(x3, 512, w_fc1, w_conv2, 128, x5, xw2, 128, b_fc1, N, 512);

    // x7 = x5 + relu(A_norm @ xw2 + b_conv2)   (fused, in place in x5)
    k_agg128_x7<<<(N + 3) / 4, 256, 0, stream>>>(xw2, rowptr, csr_row, csr_nrm, b_conv2, x5, N);

    // out = x7 @ w_fc2 + b_fc2 + b_conv3 ; xw3 = x7 @ w_conv3
    k_dot<<<(N + 3) / 4, 256, 0, stream>>>(x5, w_fc2, b_fc2, w_conv3, b_conv3, out, xw3, N);

    // out += A_norm @ xw3
    k_agg1_csr<<<(N + 255) / 256, 256, 0, stream>>>(xw3, rowptr, csr_row, csr_nrm, out, N);
}

// Round 3
// 530.180 us; speedup vs baseline: 1.9251x; 1.2086x over previous
//
#include <hip/hip_runtime.h>
#include <hip/hip_bf16.h>

static constexpr int BM = 64, BN = 64, BK = 16, TM = 4, TN = 4;

typedef __attribute__((ext_vector_type(8))) short short8;
typedef __attribute__((ext_vector_type(4))) float f32x4;

__device__ __forceinline__ ushort bf16_bits(float v) {
    __hip_bfloat16 h = __float2bfloat16(v);
    return *reinterpret_cast<ushort*>(&h);
}
__device__ __forceinline__ float bf16_val(float v) {
    __hip_bfloat16 h = __float2bfloat16(v);
    return __bfloat162float(h);
}

// ---------------- CSR build ----------------

__global__ __launch_bounds__(256) void k_count(const int* __restrict__ col,
                                               int* __restrict__ degi, int E) {
    int e = blockIdx.x * 256 + threadIdx.x;
    if (e < E) atomicAdd(&degi[col[e]], 1);
}

__global__ __launch_bounds__(256) void k_scan1(const int* __restrict__ degi,
                                               int* __restrict__ excl,
                                               int* __restrict__ bsum, int n) {
    int i = blockIdx.x * 256 + threadIdx.x;
    int v = (i < n) ? degi[i] : 0;
    int lane = threadIdx.x & 63, w = threadIdx.x >> 6;
    int s = v;
    #pragma unroll
    for (int o = 1; o < 64; o <<= 1) {
        int t = __shfl_up(s, o);
        if (lane >= o) s += t;
    }
    __shared__ int wsum[4];
    if (lane == 63) wsum[w] = s;
    __syncthreads();
    int add = 0;
    for (int ww = 0; ww < w; ww++) add += wsum[ww];
    int incl = s + add;
    if (i < n) excl[i] = incl - v;
    if (threadIdx.x == 255) bsum[blockIdx.x] = incl;
}

__global__ __launch_bounds__(256) void k_scan2(int* __restrict__ bsum, int nb) {
    int i = threadIdx.x;
    int v = (i < nb) ? bsum[i] : 0;
    int lane = i & 63, w = i >> 6;
    int s = v;
    #pragma unroll
    for (int o = 1; o < 64; o <<= 1) {
        int t = __shfl_up(s, o);
        if (lane >= o) s += t;
    }
    __shared__ int wsum[4];
    if (lane == 63) wsum[w] = s;
    __syncthreads();
    int add = 0;
    for (int ww = 0; ww < w; ww++) add += wsum[ww];
    if (i < nb) bsum[i] = (s + add) - v;
}

__global__ __launch_bounds__(256) void k_scan3(const int* __restrict__ excl,
                                               const int* __restrict__ bsum,
                                               const int* __restrict__ degi,
                                               int* __restrict__ rowptr,
                                               int* __restrict__ cursor,
                                               float* __restrict__ dis,
                                               int n, int E) {
    int i = blockIdx.x * 256 + threadIdx.x;
    if (i < n) {
        int p = excl[i] + bsum[blockIdx.x];
        rowptr[i] = p;
        cursor[i] = p;
        int d = degi[i];
        dis[i] = d > 0 ? rsqrtf((float)d) : 0.f;
    }
    if (i == 0) rowptr[n] = E;
}

__global__ __launch_bounds__(256) void k_scatter(const int* __restrict__ row,
                                                 const int* __restrict__ col,
                                                 const float* __restrict__ dis,
                                                 int* __restrict__ cursor,
                                                 int* __restrict__ csr_row,
                                                 float* __restrict__ csr_nrm, int E) {
    int e = blockIdx.x * 256 + threadIdx.x;
    if (e >= E) return;
    int c = col[e], r = row[e];
    int p = atomicAdd(&cursor[c], 1);
    csr_row[p] = r;
    csr_nrm[p] = dis[r] * dis[c];
}

// ---------------- CSR aggregations (gather, no atomics) ----------------

__global__ __launch_bounds__(256) void k_agg64_csr(const float* __restrict__ x,
                                                   const int* __restrict__ rowptr,
                                                   const int* __restrict__ csr_row,
                                                   const float* __restrict__ csr_nrm,
                                                   float* __restrict__ aggx, int n) {
    int node = blockIdx.x * 4 + (threadIdx.x >> 6);
    if (node >= n) return;
    int lane = threadIdx.x & 63;
    int s = rowptr[node], t = rowptr[node + 1];
    float acc = 0.f;
    for (int p = s; p < t; ++p) {
        int r = csr_row[p];
        float w = csr_nrm[p];
        acc += w * x[(long long)r * 64 + lane];
    }
    aggx[(long long)node * 64 + lane] = acc;
}

__global__ __launch_bounds__(256) void k_agg128_x7(const float* __restrict__ xw,
                                                   const int* __restrict__ rowptr,
                                                   const int* __restrict__ csr_row,
                                                   const float* __restrict__ csr_nrm,
                                                   const float* __restrict__ b2,
                                                   float* __restrict__ x5, int n) {
    int node = blockIdx.x * 4 + (threadIdx.x >> 6);
    if (node >= n) return;
    int lane = threadIdx.x & 63;
    int s = rowptr[node], t = rowptr[node + 1];
    float2 acc = {0.f, 0.f};
    for (int p = s; p < t; ++p) {
        int r = csr_row[p];
        float w = csr_nrm[p];
        float2 v = *reinterpret_cast<const float2*>(&xw[(long long)r * 128 + lane * 2]);
        acc.x += w * v.x;
        acc.y += w * v.y;
    }
    float2 b = *reinterpret_cast<const float2*>(&b2[lane * 2]);
    float2* o = reinterpret_cast<float2*>(&x5[(long long)node * 128 + lane * 2]);
    float2 cur = *o;
    cur.x += fmaxf(acc.x + b.x, 0.f);
    cur.y += fmaxf(acc.y + b.y, 0.f);
    *o = cur;
}

__global__ __launch_bounds__(256) void k_agg1_csr(const float* __restrict__ sv,
                                                  const int* __restrict__ rowptr,
                                                  const int* __restrict__ csr_row,
                                                  const float* __restrict__ csr_nrm,
                                                  float* __restrict__ out, int n) {
    int i = blockIdx.x * 256 + threadIdx.x;
    if (i >= n) return;
    int s = rowptr[i], t = rowptr[i + 1];
    float a = 0.f;
    for (int p = s; p < t; ++p) a += csr_nrm[p] * sv[csr_row[p]];
    out[i] += a;
}

// ---------------- GEMMs ----------------

// fp32 vector GEMM (K=64 layers), epilogue writes bf16 hi/lo pair (ldc=512).
__global__ __launch_bounds__(256) void k_gemm(const float* __restrict__ A, int lda,
                                              const float* __restrict__ B, int ldb,
                                              ushort* __restrict__ Ch,
                                              ushort* __restrict__ Cl,
                                              const float* __restrict__ bias,
                                              int M, int K) {
    __shared__ float As[BK][BM + 4];
    __shared__ float Bs[BK][BN];
    int t = threadIdx.x;
    int tx = t & 15, ty = t >> 4;
    int row0 = blockIdx.x * BM;
    int col0 = blockIdx.y * BN;

    float acc[TM][TN] = {};

    for (int kt = 0; kt < K; kt += BK) {
        #pragma unroll
        for (int i = 0; i < 4; i++) {
            int l = i * 256 + t;
            int m = l >> 4;
            int k = l & 15;
            int gm = row0 + m;
            float v = 0.f;
            if (gm < M) v = A[(long long)gm * lda + kt + k];
            As[k][m] = v;
        }
        #pragma unroll
        for (int i = 0; i < 4; i++) {
            int l = i * 256 + t;
            int nn = l & 63;
            int k = l >> 6;
            Bs[k][nn] = B[(long long)(kt + k) * ldb + col0 + nn];
        }
        __syncthreads();
        #pragma unroll
        for (int k = 0; k < BK; k++) {
            float4 a4 = *reinterpret_cast<const float4*>(&As[k][ty * TM]);
            float4 b4 = *reinterpret_cast<const float4*>(&Bs[k][tx * TN]);
            #pragma unroll
            for (int i = 0; i < TM; i++) {
                float a = (&a4.x)[i];
                #pragma unroll
                for (int j = 0; j < TN; j++)
                    acc[i][j] += a * (&b4.x)[j];
            }
        }
        __syncthreads();
    }

    #pragma unroll
    for (int i = 0; i < TM; i++) {
        int gm = row0 + ty * TM + i;
        if (gm >= M) continue;
        #pragma unroll
        for (int j = 0; j < TN; j++) {
            int gn = col0 + tx * TN + j;
            float v = fmaxf(acc[i][j] + bias[gn], 0.f);
            float hf = bf16_val(v);
            Ch[(long long)gm * 512 + gn] = bf16_bits(v);
            Cl[(long long)gm * 512 + gn] = bf16_bits(v - hf);
        }
    }
}

// split+transpose weights: Bt[n][k], n<128 -> w_fc1[:,n], else w_conv2[:,n-128]
__global__ __launch_bounds__(256) void k_prepB(const float* __restrict__ w1,
                                               const float* __restrict__ w2,
                                               ushort* __restrict__ Bh,
                                               ushort* __restrict__ Bl) {
    int id = blockIdx.x * 256 + threadIdx.x;   // 256*512
    if (id >= 256 * 512) return;
    int n = id >> 9, k = id & 511;
    float v = (n < 128) ? w1[(long long)k * 128 + n] : w2[(long long)k * 128 + (n - 128)];
    float hf = bf16_val(v);
    Bh[id] = bf16_bits(v);
    Bl[id] = bf16_bits(v - hf);
}

// Split-precision MFMA dual GEMM:
//   [C1 | C2] = (Ah+Al)[M,512] @ (Bh+Bl)^T[512,256]   (3-term split)
//   C1 = relu(cols 0..127 + bias1) -> x5 ; C2 = cols 128..255 -> xw2
// Block: 64 rows x 256 cols, 4 waves (wave w -> cols w*64..w*64+64).
__global__ __launch_bounds__(256) void k_gemm2_mfma(
    const ushort* __restrict__ Ah, const ushort* __restrict__ Al,
    const ushort* __restrict__ Bh, const ushort* __restrict__ Bl,
    const float* __restrict__ bias1,
    float* __restrict__ C1, float* __restrict__ C2, int M) {
    // row stride 40 bf16 (80B): b128 reads land 2-way on banks (free)
    __shared__ ushort sA[2][64][40];
    __shared__ ushort sB[2][256][40];
    const int t = threadIdx.x;
    const int lane = t & 63;
    const int wv = t >> 6;          // column group
    const int m0 = blockIdx.x * 64;
    const int ln15 = lane & 15;
    const int quad = lane >> 4;

    f32x4 acc[4][4] = {};           // [mt][nt], 16x16 tiles

    for (int k0 = 0; k0 < 512; k0 += 32) {
        // stage A hi/lo: 2 arrays * 64 rows * 4 chunks = 512 x 16B
        #pragma unroll
        for (int i = 0; i < 2; i++) {
            int c = i * 256 + t;
            int arr = c >> 8, r = (c >> 2) & 63, part = c & 3;
            const ushort* src = arr == 0 ? Ah : Al;
            int4 v = make_int4(0, 0, 0, 0);
            int gm = m0 + r;
            if (gm < M) v = *reinterpret_cast<const int4*>(&src[(long long)gm * 512 + k0 + part * 8]);
            *reinterpret_cast<int4*>(&sA[arr][r][part * 8]) = v;
        }
        // stage B hi/lo: 2 * 256 * 4 = 2048 x 16B
        #pragma unroll
        for (int i = 0; i < 8; i++) {
            int c = i * 256 + t;
            int arr = c >> 10, r = (c >> 2) & 255, part = c & 3;
            const ushort* src = arr == 0 ? Bh : Bl;
            int4 v = *reinterpret_cast<const int4*>(&src[(long long)r * 512 + k0 + part * 8]);
            *reinterpret_cast<int4*>(&sB[arr][r][part * 8]) = v;
        }
        __syncthreads();

        short8 ah[4], al[4], bh[4], bl[4];
        #pragma unroll
        for (int mt = 0; mt < 4; mt++) {
            ah[mt] = *reinterpret_cast<const short8*>(&sA[0][mt * 16 + ln15][quad * 8]);
            al[mt] = *reinterpret_cast<const short8*>(&sA[1][mt * 16 + ln15][quad * 8]);
        }
        #pragma unroll
        for (int nt = 0; nt < 4; nt++) {
            int n = wv * 64 + nt * 16 + ln15;
            bh[nt] = *reinterpret_cast<const short8*>(&sB[0][n][quad * 8]);
            bl[nt] = *reinterpret_cast<const short8*>(&sB[1][n][quad * 8]);
        }
        #pragma unroll
        for (int mt = 0; mt < 4; mt++)
            #pragma unroll
            for (int nt = 0; nt < 4; nt++) {
                acc[mt][nt] = __builtin_amdgcn_mfma_f32_16x16x32_bf16(ah[mt], bh[nt], acc[mt][nt], 0, 0, 0);
                acc[mt][nt] = __builtin_amdgcn_mfma_f32_16x16x32_bf16(ah[mt], bl[nt], acc[mt][nt], 0, 0, 0);
                acc[mt][nt] = __builtin_amdgcn_mfma_f32_16x16x32_bf16(al[mt], bh[nt], acc[mt][nt], 0, 0, 0);
            }
        __syncthreads();
    }

    // epilogue: C/D layout col=lane&15, row=quad*4+reg
    #pragma unroll
    for (int mt = 0; mt < 4; mt++) {
        #pragma unroll
        for (int nt = 0; nt < 4; nt++) {
            int gn = wv * 64 + nt * 16 + ln15;   // 0..255
            #pragma unroll
            for (int r = 0; r < 4; r++) {
                int gm = m0 + mt * 16 + quad * 4 + r;
                if (gm >= M) continue;
                float v = acc[mt][nt][r];
                if (gn < 128) {
                    C1[(long long)gm * 128 + gn] = fmaxf(v + bias1[gn], 0.f);
                } else {
                    C2[(long long)gm * 128 + (gn - 128)] = v;
                }
            }
        }
    }
}

// per node: out[n] = x7[n]·w_fc2 + b_fc2 + b_conv3 ; xw3[n] = x7[n]·w_conv3
__global__ __launch_bounds__(256) void k_dot(const float* __restrict__ x7,
                                             const float* __restrict__ wfc2,
                                             const float* __restrict__ bfc2,
                                             const float* __restrict__ wc3,
                                             const float* __restrict__ bc3,
                                             float* __restrict__ out,
                                             float* __restrict__ xw3, int n) {
    int lane = threadIdx.x & 63;
    int wv = threadIdx.x >> 6;
    int node = blockIdx.x * 4 + wv;
    if (node >= n) return;
    const float* xr = x7 + (long long)node * 128;
    float v0 = xr[lane], v1 = xr[64 + lane];
    float s1 = v0 * wfc2[lane] + v1 * wfc2[64 + lane];
    float s2 = v0 * wc3[lane] + v1 * wc3[64 + lane];
    #pragma unroll
    for (int o = 32; o > 0; o >>= 1) {
        s1 += __shfl_down(s1, o);
        s2 += __shfl_down(s2, o);
    }
    if (lane == 0) {
        out[node] = s1 + bfc2[0] + bc3[0];
        xw3[node] = s2;
    }
}

extern "C" void kernel_launch(void* const* d_in, const int* in_sizes, int n_in,
                              void* d_out, int out_size, void* d_ws, size_t ws_size,
                              hipStream_t stream) {
    const float* x       = (const float*)d_in[0];
    const int*   ei      = (const int*)d_in[1];
    const float* w_fc    = (const float*)d_in[2];
    const float* b_fc    = (const float*)d_in[3];
    const float* w_conv1 = (const float*)d_in[4];
    const float* b_conv1 = (const float*)d_in[5];
    const float* w_fc1   = (const float*)d_in[6];
    const float* b_fc1   = (const float*)d_in[7];
    const float* w_conv2 = (const float*)d_in[8];
    const float* b_conv2 = (const float*)d_in[9];
    const float* w_fc2   = (const float*)d_in[10];
    const float* b_fc2   = (const float*)d_in[11];
    const float* w_conv3 = (const float*)d_in[12];
    const float* b_conv3 = (const float*)d_in[13];

    const int N = in_sizes[0] / 64;       // 50000
    const int E = in_sizes[1] / 2;        // 800000
    const int* row = ei;
    const int* col = ei + E;

    const int nb = (N + 255) / 256;

    // workspace layout (all chunks multiple of 16B; ws base is 16B-aligned)
    char* p = (char*)d_ws;
    auto alloc = [&](size_t elems) {       // elems of 4 bytes, padded to x4
        void* q = p; p += ((elems + 3) & ~(size_t)3) * 4; return q;
    };
    int*    degi    = (int*)   alloc(N);
    int*    excl    = (int*)   alloc(N);
    int*    bsum    = (int*)   alloc(256);
    int*    rowptr  = (int*)   alloc(N + 4);
    int*    cursor  = (int*)   alloc(N);
    int*    csr_row = (int*)   alloc(E);
    float*  csr_nrm = (float*) alloc(E);
    float*  dis     = (float*) alloc(N);
    float*  aggx    = (float*) alloc((size_t)N * 64);
    ushort* x3h     = (ushort*)alloc((size_t)N * 256);   // N*512 bf16
    ushort* x3l     = (ushort*)alloc((size_t)N * 256);
    ushort* Bht     = (ushort*)alloc(256 * 512 / 2);
    ushort* Blt     = (ushort*)alloc(256 * 512 / 2);
    float*  x5      = (float*) alloc((size_t)N * 128);
    float*  xw2     = (float*) alloc((size_t)N * 128);
    float*  xw3     = (float*) alloc(N);

    float* out = (float*)d_out;

    // ---- CSR build ----
    hipMemsetAsync(degi, 0, (size_t)N * sizeof(int), stream);
    k_count<<<(E + 255) / 256, 256, 0, stream>>>(col, degi, E);
    k_scan1<<<nb, 256, 0, stream>>>(degi, excl, bsum, N);
    k_scan2<<<1, 256, 0, stream>>>(bsum, nb);
    k_scan3<<<nb, 256, 0, stream>>>(excl, bsum, degi, rowptr, cursor, dis, N, E);
    k_scatter<<<(E + 255) / 256, 256, 0, stream>>>(row, col, dis, cursor, csr_row, csr_nrm, E);

    // weight split+transpose for the MFMA GEMM (independent; overlaps CSR deps)
    k_prepB<<<(256 * 512 + 255) / 256, 256, 0, stream>>>(w_fc1, w_conv2, Bht, Blt);

    // conv1 propagate: aggx = A_norm @ x
    k_agg64_csr<<<(N + 3) / 4, 256, 0, stream>>>(x, rowptr, csr_row, csr_nrm, aggx, N);

    dim3 g1((N + BM - 1) / BM, 256 / BN);   // (782, 4)

    // x1 = relu(x @ w_fc + b_fc)          -> x3[:, 0:256] (bf16 hi/lo)
    k_gemm<<<g1, 256, 0, stream>>>(x, 64, w_fc, 256, x3h, x3l, b_fc, N, 64);
    // x2 = relu(aggx @ w_conv1 + b_conv1) -> x3[:, 256:512]
    k_gemm<<<g1, 256, 0, stream>>>(aggx, 64, w_conv1, 256, x3h + 256, x3l + 256, b_conv1, N, 64);

    // x5 = relu(x3 @ w_fc1 + b_fc1) ; xw2 = x3 @ w_conv2   (split-bf16 MFMA)
    k_gemm2_mfma<<<(N + 63) / 64, 256, 0, stream>>>(x3h, x3l, Bht, Blt, b_fc1, x5, xw2, N);

    // x7 = x5 + relu(A_norm @ xw2 + b_conv2)   (fused, in place in x5)
    k_agg128_x7<<<(N + 3) / 4, 256, 0, stream>>>(xw2, rowptr, csr_row, csr_nrm, b_conv2, x5, N);

    // out = x7 @ w_fc2 + b_fc2 + b_conv3 ; xw3 = x7 @ w_conv3
    k_dot<<<(N + 3) / 4, 256, 0, stream>>>(x5, w_fc2, b_fc2, w_conv3, b_conv3, out, xw3, N);

    // out += A_norm @ xw3
    k_agg1_csr<<<(N + 255) / 256, 256, 0, stream>>>(xw3, rowptr, csr_row, csr_nrm, out, N);
}

// Round 4
// 509.589 us; speedup vs baseline: 2.0029x; 1.0404x over previous
//
#include <hip/hip_runtime.h>
#include <hip/hip_bf16.h>

static constexpr int BM = 64, BN = 64, BK = 16;

typedef __attribute__((ext_vector_type(8))) short short8;
typedef __attribute__((ext_vector_type(4))) float f32x4;

__device__ __forceinline__ ushort bf16_bits(float v) {
    __hip_bfloat16 h = __float2bfloat16(v);
    return *reinterpret_cast<ushort*>(&h);
}
__device__ __forceinline__ float bf16_val(float v) {
    __hip_bfloat16 h = __float2bfloat16(v);
    return __bfloat162float(h);
}

// ---------------- CSR build ----------------

__global__ __launch_bounds__(256) void k_count(const int* __restrict__ col,
                                               int* __restrict__ degi, int E) {
    int e = blockIdx.x * 256 + threadIdx.x;
    if (e < E) atomicAdd(&degi[col[e]], 1);
}

__global__ __launch_bounds__(256) void k_scan1(const int* __restrict__ degi,
                                               int* __restrict__ excl,
                                               int* __restrict__ bsum, int n) {
    int i = blockIdx.x * 256 + threadIdx.x;
    int v = (i < n) ? degi[i] : 0;
    int lane = threadIdx.x & 63, w = threadIdx.x >> 6;
    int s = v;
    #pragma unroll
    for (int o = 1; o < 64; o <<= 1) {
        int t = __shfl_up(s, o);
        if (lane >= o) s += t;
    }
    __shared__ int wsum[4];
    if (lane == 63) wsum[w] = s;
    __syncthreads();
    int add = 0;
    for (int ww = 0; ww < w; ww++) add += wsum[ww];
    int incl = s + add;
    if (i < n) excl[i] = incl - v;
    if (threadIdx.x == 255) bsum[blockIdx.x] = incl;
}

__global__ __launch_bounds__(256) void k_scan2(int* __restrict__ bsum, int nb) {
    int i = threadIdx.x;
    int v = (i < nb) ? bsum[i] : 0;
    int lane = i & 63, w = i >> 6;
    int s = v;
    #pragma unroll
    for (int o = 1; o < 64; o <<= 1) {
        int t = __shfl_up(s, o);
        if (lane >= o) s += t;
    }
    __shared__ int wsum[4];
    if (lane == 63) wsum[w] = s;
    __syncthreads();
    int add = 0;
    for (int ww = 0; ww < w; ww++) add += wsum[ww];
    if (i < nb) bsum[i] = (s + add) - v;
}

__global__ __launch_bounds__(256) void k_scan3(const int* __restrict__ excl,
                                               const int* __restrict__ bsum,
                                               const int* __restrict__ degi,
                                               int* __restrict__ rowptr,
                                               int* __restrict__ cursor,
                                               float* __restrict__ dis,
                                               int n, int E) {
    int i = blockIdx.x * 256 + threadIdx.x;
    if (i < n) {
        int p = excl[i] + bsum[blockIdx.x];
        rowptr[i] = p;
        cursor[i] = p;
        int d = degi[i];
        dis[i] = d > 0 ? rsqrtf((float)d) : 0.f;
    }
    if (i == 0) rowptr[n] = E;
}

__global__ __launch_bounds__(256) void k_scatter(const int* __restrict__ row,
                                                 const int* __restrict__ col,
                                                 const float* __restrict__ dis,
                                                 int* __restrict__ cursor,
                                                 int* __restrict__ csr_row,
                                                 float* __restrict__ csr_nrm, int E) {
    int e = blockIdx.x * 256 + threadIdx.x;
    if (e >= E) return;
    int c = col[e], r = row[e];
    int p = atomicAdd(&cursor[c], 1);
    csr_row[p] = r;
    csr_nrm[p] = dis[r] * dis[c];
}

// ---------------- CSR aggregations (gather, no atomics) ----------------

__global__ __launch_bounds__(256) void k_agg64_csr(const float* __restrict__ x,
                                                   const int* __restrict__ rowptr,
                                                   const int* __restrict__ csr_row,
                                                   const float* __restrict__ csr_nrm,
                                                   float* __restrict__ aggx, int n) {
    int node = blockIdx.x * 4 + (threadIdx.x >> 6);
    if (node >= n) return;
    int lane = threadIdx.x & 63;
    int s = rowptr[node], t = rowptr[node + 1];
    float acc = 0.f;
    for (int p = s; p < t; ++p) {
        int r = csr_row[p];
        float w = csr_nrm[p];
        acc += w * x[(long long)r * 64 + lane];
    }
    aggx[(long long)node * 64 + lane] = acc;
}

__global__ __launch_bounds__(256) void k_agg128_x7(const float* __restrict__ xw,
                                                   const int* __restrict__ rowptr,
                                                   const int* __restrict__ csr_row,
                                                   const float* __restrict__ csr_nrm,
                                                   const float* __restrict__ b2,
                                                   float* __restrict__ x5, int n) {
    int node = blockIdx.x * 4 + (threadIdx.x >> 6);
    if (node >= n) return;
    int lane = threadIdx.x & 63;
    int s = rowptr[node], t = rowptr[node + 1];
    float2 acc = {0.f, 0.f};
    for (int p = s; p < t; ++p) {
        int r = csr_row[p];
        float w = csr_nrm[p];
        float2 v = *reinterpret_cast<const float2*>(&xw[(long long)r * 128 + lane * 2]);
        acc.x += w * v.x;
        acc.y += w * v.y;
    }
    float2 b = *reinterpret_cast<const float2*>(&b2[lane * 2]);
    float2* o = reinterpret_cast<float2*>(&x5[(long long)node * 128 + lane * 2]);
    float2 cur = *o;
    cur.x += fmaxf(acc.x + b.x, 0.f);
    cur.y += fmaxf(acc.y + b.y, 0.f);
    *o = cur;
}

__global__ __launch_bounds__(256) void k_agg1_csr(const float* __restrict__ sv,
                                                  const int* __restrict__ rowptr,
                                                  const int* __restrict__ csr_row,
                                                  const float* __restrict__ csr_nrm,
                                                  float* __restrict__ out, int n) {
    int i = blockIdx.x * 256 + threadIdx.x;
    if (i >= n) return;
    int s = rowptr[i], t = rowptr[i + 1];
    float a = 0.f;
    for (int p = s; p < t; ++p) a += csr_nrm[p] * sv[csr_row[p]];
    out[i] += a;
}

// ---------------- GEMMs ----------------

// fp32 vector GEMM (K=64 layers). Epilogue: relu(+bias), bf16 hi/lo split,
// stored directly in MFMA A-fragment order:
//   Af[arr][mtile][k0i][lane][8] ; lane = q*16 + (row&15),
//   element = x3[row][k0i*32 + q*8 + j], global x3 col = colbase + local col.
// Thread map: tx = t&7 owns 8 consecutive cols (= one 16B chunk), ty = t>>3
// owns 2 rows -> one int4 store per (row, arr).
__global__ __launch_bounds__(256) void k_gemm_bf(const float* __restrict__ A, int lda,
                                                 const float* __restrict__ B, int ldb,
                                                 const float* __restrict__ bias,
                                                 ushort* __restrict__ Af,
                                                 int Mt, int colbase, int M, int K) {
    __shared__ float As[BK][BM + 4];
    __shared__ float Bs[BK][BN];
    int t = threadIdx.x;
    int tx = t & 7, ty = t >> 3;
    int row0 = blockIdx.x * BM;
    int col0 = blockIdx.y * BN;   // local col within this layer's 256

    float acc[2][8] = {};

    for (int kt = 0; kt < K; kt += BK) {
        #pragma unroll
        for (int i = 0; i < 4; i++) {
            int l = i * 256 + t;
            int m = l >> 4;
            int k = l & 15;
            int gm = row0 + m;
            float v = 0.f;
            if (gm < M) v = A[(long long)gm * lda + kt + k];
            As[k][m] = v;
        }
        #pragma unroll
        for (int i = 0; i < 4; i++) {
            int l = i * 256 + t;
            int nn = l & 63;
            int k = l >> 6;
            Bs[k][nn] = B[(long long)(kt + k) * ldb + col0 + nn];
        }
        __syncthreads();
        #pragma unroll
        for (int k = 0; k < BK; k++) {
            float a0 = As[k][ty * 2];
            float a1 = As[k][ty * 2 + 1];
            float4 b0 = *reinterpret_cast<const float4*>(&Bs[k][tx * 8]);
            float4 b1 = *reinterpret_cast<const float4*>(&Bs[k][tx * 8 + 4]);
            float b[8] = {b0.x, b0.y, b0.z, b0.w, b1.x, b1.y, b1.z, b1.w};
            #pragma unroll
            for (int j = 0; j < 8; j++) {
                acc[0][j] += a0 * b[j];
                acc[1][j] += a1 * b[j];
            }
        }
        __syncthreads();
    }

    int gn0 = col0 + tx * 8;          // local col in [0,256)
    int gcol = gn0 + colbase;         // x3 col in [0,512)
    int k0i = gcol >> 5;
    int q = (gcol >> 3) & 3;
    #pragma unroll
    for (int i = 0; i < 2; i++) {
        int gm = row0 + ty * 2 + i;   // grid covers exactly Mt*16 rows
        int mtile = gm >> 4, l = gm & 15;
        int lane = q * 16 + l;
        ushort hi[8], lo[8];
        #pragma unroll
        for (int j = 0; j < 8; j++) {
            float v = fmaxf(acc[i][j] + bias[gn0 + j], 0.f);
            float hf = bf16_val(v);
            hi[j] = bf16_bits(v);
            lo[j] = bf16_bits(v - hf);
        }
        size_t bh = (((size_t)mtile * 16 + k0i) * 64 + lane) * 8;
        size_t bl = (((size_t)(Mt + mtile) * 16 + k0i) * 64 + lane) * 8;
        *reinterpret_cast<int4*>(&Af[bh]) = *reinterpret_cast<const int4*>(hi);
        *reinterpret_cast<int4*>(&Af[bl]) = *reinterpret_cast<const int4*>(lo);
    }
}

// split+transpose weights into MFMA B-fragment order:
//   Bf[arr][k0i][nt][lane][8], element = W[k0i*32+(lane>>4)*8+j][nt*16+(lane&15)]
//   (col < 128 -> w_fc1, else w_conv2)
__global__ __launch_bounds__(256) void k_prepB(const float* __restrict__ w1,
                                               const float* __restrict__ w2,
                                               ushort* __restrict__ Bf) {
    int id = blockIdx.x * 256 + threadIdx.x;    // 2*16*16*64 = 32768
    if (id >= 32768) return;
    int lane = id & 63;
    int nt   = (id >> 6) & 15;
    int k0i  = (id >> 10) & 15;
    int arr  = id >> 14;
    int n = nt * 16 + (lane & 15);
    int kbase = k0i * 32 + (lane >> 4) * 8;
    ushort outv[8];
    #pragma unroll
    for (int j = 0; j < 8; j++) {
        int k = kbase + j;
        float v = (n < 128) ? w1[(long long)k * 128 + n]
                            : w2[(long long)k * 128 + (n - 128)];
        if (arr == 0) {
            outv[j] = bf16_bits(v);
        } else {
            float hf = bf16_val(v);
            outv[j] = bf16_bits(v - hf);
        }
    }
    *reinterpret_cast<int4*>(&Bf[(size_t)id * 8]) = *reinterpret_cast<const int4*>(outv);
}

// LDS-free split-precision MFMA dual GEMM:
//   [C1 | C2] = (Ah+Al)[M,512] @ (Bh+Bl)^T[512,256]  (3-term split)
// Block: 64 rows x 256 cols, 4 waves; wave wv -> cols wv*64..+63.
// All operands pre-packed in fragment order -> coalesced 16B/lane loads.
__global__ __launch_bounds__(256) void k_gemm2_mfma(
    const ushort* __restrict__ Af, const ushort* __restrict__ Bf,
    const float* __restrict__ bias1,
    float* __restrict__ C1, float* __restrict__ C2, int M, int Mt) {
    const int t = threadIdx.x;
    const int lane = t & 63;
    const int wv = t >> 6;
    const int mt0 = blockIdx.x * 4;
    const int ln15 = lane & 15;
    const int quad = lane >> 4;

    f32x4 acc[4][4] = {};

    const size_t laneOff = (size_t)lane * 8;

    for (int k0i = 0; k0i < 16; k0i++) {
        short8 bh[4], bl[4];
        #pragma unroll
        for (int nt = 0; nt < 4; nt++) {
            size_t ib = (((size_t)k0i * 16) + (wv * 4 + nt)) * 512 + laneOff;
            bh[nt] = *reinterpret_cast<const short8*>(&Bf[ib]);
            bl[nt] = *reinterpret_cast<const short8*>(&Bf[ib + 131072]); // +16*16*64*8
        }
        #pragma unroll
        for (int mt = 0; mt < 4; mt++) {
            size_t ia = (((size_t)(mt0 + mt) * 16) + k0i) * 512 + laneOff;
            short8 ah = *reinterpret_cast<const short8*>(&Af[ia]);
            short8 al = *reinterpret_cast<const short8*>(&Af[ia + (size_t)Mt * 8192]);
            #pragma unroll
            for (int nt = 0; nt < 4; nt++) {
                acc[mt][nt] = __builtin_amdgcn_mfma_f32_16x16x32_bf16(ah, bh[nt], acc[mt][nt], 0, 0, 0);
                acc[mt][nt] = __builtin_amdgcn_mfma_f32_16x16x32_bf16(ah, bl[nt], acc[mt][nt], 0, 0, 0);
                acc[mt][nt] = __builtin_amdgcn_mfma_f32_16x16x32_bf16(al, bh[nt], acc[mt][nt], 0, 0, 0);
            }
        }
    }

    // epilogue: C/D layout col=lane&15, row=quad*4+reg
    #pragma unroll
    for (int mt = 0; mt < 4; mt++) {
        #pragma unroll
        for (int nt = 0; nt < 4; nt++) {
            int gn = wv * 64 + nt * 16 + ln15;   // 0..255
            #pragma unroll
            for (int r = 0; r < 4; r++) {
                int gm = mt0 * 16 + mt * 16 + quad * 4 + r;
                if (gm >= M) continue;
                float v = acc[mt][nt][r];
                if (gn < 128) {
                    C1[(long long)gm * 128 + gn] = fmaxf(v + bias1[gn], 0.f);
                } else {
                    C2[(long long)gm * 128 + (gn - 128)] = v;
                }
            }
        }
    }
}

// per node: out[n] = x7[n]·w_fc2 + b_fc2 + b_conv3 ; xw3[n] = x7[n]·w_conv3
__global__ __launch_bounds__(256) void k_dot(const float* __restrict__ x7,
                                             const float* __restrict__ wfc2,
                                             const float* __restrict__ bfc2,
                                             const float* __restrict__ wc3,
                                             const float* __restrict__ bc3,
                                             float* __restrict__ out,
                                             float* __restrict__ xw3, int n) {
    int lane = threadIdx.x & 63;
    int wv = threadIdx.x >> 6;
    int node = blockIdx.x * 4 + wv;
    if (node >= n) return;
    const float* xr = x7 + (long long)node * 128;
    float v0 = xr[lane], v1 = xr[64 + lane];
    float s1 = v0 * wfc2[lane] + v1 * wfc2[64 + lane];
    float s2 = v0 * wc3[lane] + v1 * wc3[64 + lane];
    #pragma unroll
    for (int o = 32; o > 0; o >>= 1) {
        s1 += __shfl_down(s1, o);
        s2 += __shfl_down(s2, o);
    }
    if (lane == 0) {
        out[node] = s1 + bfc2[0] + bc3[0];
        xw3[node] = s2;
    }
}

extern "C" void kernel_launch(void* const* d_in, const int* in_sizes, int n_in,
                              void* d_out, int out_size, void* d_ws, size_t ws_size,
                              hipStream_t stream) {
    const float* x       = (const float*)d_in[0];
    const int*   ei      = (const int*)d_in[1];
    const float* w_fc    = (const float*)d_in[2];
    const float* b_fc    = (const float*)d_in[3];
    const float* w_conv1 = (const float*)d_in[4];
    const float* b_conv1 = (const float*)d_in[5];
    const float* w_fc1   = (const float*)d_in[6];
    const float* b_fc1   = (const float*)d_in[7];
    const float* w_conv2 = (const float*)d_in[8];
    const float* b_conv2 = (const float*)d_in[9];
    const float* w_fc2   = (const float*)d_in[10];
    const float* b_fc2   = (const float*)d_in[11];
    const float* w_conv3 = (const float*)d_in[12];
    const float* b_conv3 = (const float*)d_in[13];

    const int N = in_sizes[0] / 64;       // 50000
    const int E = in_sizes[1] / 2;        // 800000
    const int* row = ei;
    const int* col = ei + E;

    const int nb = (N + 255) / 256;
    const int nblk = (N + 63) / 64;       // 782
    const int Mt = nblk * 4;              // 3128 row-tiles of 16

    // workspace layout (units of 4 bytes, chunks padded to 16B)
    char* p = (char*)d_ws;
    auto alloc = [&](size_t elems) {
        void* q = p; p += ((elems + 3) & ~(size_t)3) * 4; return q;
    };
    int*    degi    = (int*)   alloc(N);
    int*    excl    = (int*)   alloc(N);
    int*    bsum    = (int*)   alloc(256);
    int*    rowptr  = (int*)   alloc(N + 4);
    int*    cursor  = (int*)   alloc(N);
    int*    csr_row = (int*)   alloc(E);
    float*  csr_nrm = (float*) alloc(E);
    float*  dis     = (float*) alloc(N);
    float*  aggx    = (float*) alloc((size_t)N * 64);
    ushort* x3f     = (ushort*)alloc((size_t)Mt * 8192);   // 2*Mt*16*64*8 ushorts
    ushort* Bf      = (ushort*)alloc(131072);              // 2*16*16*64*8 ushorts
    float*  x5      = (float*) alloc((size_t)N * 128);
    float*  xw2     = (float*) alloc((size_t)N * 128);
    float*  xw3     = (float*) alloc(N);

    float* out = (float*)d_out;

    // ---- CSR build ----
    hipMemsetAsync(degi, 0, (size_t)N * sizeof(int), stream);
    k_count<<<(E + 255) / 256, 256, 0, stream>>>(col, degi, E);
    k_scan1<<<nb, 256, 0, stream>>>(degi, excl, bsum, N);
    k_scan2<<<1, 256, 0, stream>>>(bsum, nb);
    k_scan3<<<nb, 256, 0, stream>>>(excl, bsum, degi, rowptr, cursor, dis, N, E);
    k_scatter<<<(E + 255) / 256, 256, 0, stream>>>(row, col, dis, cursor, csr_row, csr_nrm, E);

    // weight split+transpose into B-fragment order (independent of CSR chain)
    k_prepB<<<32768 / 256, 256, 0, stream>>>(w_fc1, w_conv2, Bf);

    // conv1 propagate: aggx = A_norm @ x
    k_agg64_csr<<<(N + 3) / 4, 256, 0, stream>>>(x, rowptr, csr_row, csr_nrm, aggx, N);

    dim3 g1(nblk, 4);   // (782, 4): 64-row x 64-col tiles over 256 cols

    // x1 = relu(x @ w_fc + b_fc)          -> x3 cols [0,256)  (bf16 hi/lo frags)
    k_gemm_bf<<<g1, 256, 0, stream>>>(x, 64, w_fc, 256, b_fc, x3f, Mt, 0, N, 64);
    // x2 = relu(aggx @ w_conv1 + b_conv1) -> x3 cols [256,512)
    k_gemm_bf<<<g1, 256, 0, stream>>>(aggx, 64, w_conv1, 256, b_conv1, x3f, Mt, 256, N, 64);

    // x5 = relu(x3 @ w_fc1 + b_fc1) ; xw2 = x3 @ w_conv2   (LDS-free MFMA)
    k_gemm2_mfma<<<nblk, 256, 0, stream>>>(x3f, Bf, b_fc1, x5, xw2, N, Mt);

    // x7 = x5 + relu(A_norm @ xw2 + b_conv2)   (fused, in place in x5)
    k_agg128_x7<<<(N + 3) / 4, 256, 0, stream>>>(xw2, rowptr, csr_row, csr_nrm, b_conv2, x5, N);

    // out = x7 @ w_fc2 + b_fc2 + b_conv3 ; xw3 = x7 @ w_conv3
    k_dot<<<(N + 3) / 4, 256, 0, stream>>>(x5, w_fc2, b_fc2, w_conv3, b_conv3, out, xw3, N);

    // out += A_norm @ xw3
    k_agg1_csr<<<(N + 255) / 256, 256, 0, stream>>>(xw3, rowptr, csr_row, csr_nrm, out, N);
}

// Round 5
// 435.988 us; speedup vs baseline: 2.3411x; 1.1688x over previous
//
#include <hip/hip_runtime.h>
#include <hip/hip_bf16.h>

static constexpr int BM = 64, BN = 64, BK = 16;

typedef __attribute__((ext_vector_type(8))) short short8;
typedef __attribute__((ext_vector_type(4))) float f32x4;

__device__ __forceinline__ ushort bf16_bits(float v) {
    __hip_bfloat16 h = __float2bfloat16(v);
    return *reinterpret_cast<ushort*>(&h);
}
__device__ __forceinline__ float bf16_val(float v) {
    __hip_bfloat16 h = __float2bfloat16(v);
    return __bfloat162float(h);
}

// ---------------- CSR build ----------------

__global__ __launch_bounds__(256) void k_count(const int* __restrict__ col,
                                               int* __restrict__ degi, int E) {
    int e = blockIdx.x * 256 + threadIdx.x;
    if (e < E) atomicAdd(&degi[col[e]], 1);
}

__global__ __launch_bounds__(256) void k_scan1(const int* __restrict__ degi,
                                               int* __restrict__ excl,
                                               int* __restrict__ bsum, int n) {
    int i = blockIdx.x * 256 + threadIdx.x;
    int v = (i < n) ? degi[i] : 0;
    int lane = threadIdx.x & 63, w = threadIdx.x >> 6;
    int s = v;
    #pragma unroll
    for (int o = 1; o < 64; o <<= 1) {
        int t = __shfl_up(s, o);
        if (lane >= o) s += t;
    }
    __shared__ int wsum[4];
    if (lane == 63) wsum[w] = s;
    __syncthreads();
    int add = 0;
    for (int ww = 0; ww < w; ww++) add += wsum[ww];
    int incl = s + add;
    if (i < n) excl[i] = incl - v;
    if (threadIdx.x == 255) bsum[blockIdx.x] = incl;
}

__global__ __launch_bounds__(256) void k_scan2(int* __restrict__ bsum, int nb) {
    int i = threadIdx.x;
    int v = (i < nb) ? bsum[i] : 0;
    int lane = i & 63, w = i >> 6;
    int s = v;
    #pragma unroll
    for (int o = 1; o < 64; o <<= 1) {
        int t = __shfl_up(s, o);
        if (lane >= o) s += t;
    }
    __shared__ int wsum[4];
    if (lane == 63) wsum[w] = s;
    __syncthreads();
    int add = 0;
    for (int ww = 0; ww < w; ww++) add += wsum[ww];
    if (i < nb) bsum[i] = (s + add) - v;
}

__global__ __launch_bounds__(256) void k_scan3(const int* __restrict__ excl,
                                               const int* __restrict__ bsum,
                                               const int* __restrict__ degi,
                                               int* __restrict__ rowptr,
                                               int* __restrict__ cursor,
                                               float* __restrict__ dis,
                                               int n, int E) {
    int i = blockIdx.x * 256 + threadIdx.x;
    if (i < n) {
        int p = excl[i] + bsum[blockIdx.x];
        rowptr[i] = p;
        cursor[i] = p;
        int d = degi[i];
        dis[i] = d > 0 ? rsqrtf((float)d) : 0.f;
    }
    if (i == 0) rowptr[n] = E;
}

__global__ __launch_bounds__(256) void k_scatter(const int* __restrict__ row,
                                                 const int* __restrict__ col,
                                                 const float* __restrict__ dis,
                                                 int* __restrict__ cursor,
                                                 int* __restrict__ csr_row,
                                                 float* __restrict__ csr_nrm, int E) {
    int e = blockIdx.x * 256 + threadIdx.x;
    if (e >= E) return;
    int c = col[e], r = row[e];
    int p = atomicAdd(&cursor[c], 1);
    csr_row[p] = r;
    csr_nrm[p] = dis[r] * dis[c];
}

// ---------------- CSR aggregations (gather, no atomics) ----------------
// Batched (U=8) index prefetch + independent gathers for memory-level
// parallelism: the serial per-edge chain (idx load -> gather) was the round-4
// bottleneck (VALUBusy 13%, hbm 35%).

__global__ __launch_bounds__(256) void k_agg64_csr(const float* __restrict__ x,
                                                   const int* __restrict__ rowptr,
                                                   const int* __restrict__ csr_row,
                                                   const float* __restrict__ csr_nrm,
                                                   float* __restrict__ aggx, int n) {
    int node = blockIdx.x * 4 + (threadIdx.x >> 6);
    if (node >= n) return;
    int lane = threadIdx.x & 63;
    int s = rowptr[node], t = rowptr[node + 1];
    constexpr int U = 8;
    float acc = 0.f;
    int p = s;
    for (; p + U <= t; p += U) {
        int rr[U]; float ww[U];
        #pragma unroll
        for (int u = 0; u < U; u++) { rr[u] = csr_row[p + u]; ww[u] = csr_nrm[p + u]; }
        float vv[U];
        #pragma unroll
        for (int u = 0; u < U; u++) vv[u] = x[(long long)rr[u] * 64 + lane];
        #pragma unroll
        for (int u = 0; u < U; u++) acc += ww[u] * vv[u];
    }
    for (; p < t; ++p) {
        int r = csr_row[p];
        acc += csr_nrm[p] * x[(long long)r * 64 + lane];
    }
    aggx[(long long)node * 64 + lane] = acc;
}

__global__ __launch_bounds__(256) void k_agg128_x7(const float* __restrict__ xw,
                                                   const int* __restrict__ rowptr,
                                                   const int* __restrict__ csr_row,
                                                   const float* __restrict__ csr_nrm,
                                                   const float* __restrict__ b2,
                                                   float* __restrict__ x5, int n) {
    int node = blockIdx.x * 4 + (threadIdx.x >> 6);
    if (node >= n) return;
    int lane = threadIdx.x & 63;
    int s = rowptr[node], t = rowptr[node + 1];
    constexpr int U = 8;
    float2 acc = {0.f, 0.f};
    int p = s;
    for (; p + U <= t; p += U) {
        int rr[U]; float ww[U];
        #pragma unroll
        for (int u = 0; u < U; u++) { rr[u] = csr_row[p + u]; ww[u] = csr_nrm[p + u]; }
        float2 vv[U];
        #pragma unroll
        for (int u = 0; u < U; u++)
            vv[u] = *reinterpret_cast<const float2*>(&xw[(long long)rr[u] * 128 + lane * 2]);
        #pragma unroll
        for (int u = 0; u < U; u++) {
            acc.x += ww[u] * vv[u].x;
            acc.y += ww[u] * vv[u].y;
        }
    }
    for (; p < t; ++p) {
        int r = csr_row[p];
        float w = csr_nrm[p];
        float2 v = *reinterpret_cast<const float2*>(&xw[(long long)r * 128 + lane * 2]);
        acc.x += w * v.x;
        acc.y += w * v.y;
    }
    float2 b = *reinterpret_cast<const float2*>(&b2[lane * 2]);
    float2* o = reinterpret_cast<float2*>(&x5[(long long)node * 128 + lane * 2]);
    float2 cur = *o;
    cur.x += fmaxf(acc.x + b.x, 0.f);
    cur.y += fmaxf(acc.y + b.y, 0.f);
    *o = cur;
}

__global__ __launch_bounds__(256) void k_agg1_csr(const float* __restrict__ sv,
                                                  const int* __restrict__ rowptr,
                                                  const int* __restrict__ csr_row,
                                                  const float* __restrict__ csr_nrm,
                                                  float* __restrict__ out, int n) {
    int i = blockIdx.x * 256 + threadIdx.x;
    if (i >= n) return;
    int s = rowptr[i], t = rowptr[i + 1];
    float a = 0.f;
    #pragma unroll 4
    for (int p = s; p < t; ++p) a += csr_nrm[p] * sv[csr_row[p]];
    out[i] += a;
}

// ---------------- GEMMs ----------------

// fp32 vector GEMM (K=64 layers). Epilogue: relu(+bias), bf16 hi/lo split,
// stored directly in MFMA A-fragment order:
//   Af[arr][mtile][k0i][lane][8] ; lane = q*16 + (row&15),
//   element = x3[row][k0i*32 + q*8 + j], global x3 col = colbase + local col.
__global__ __launch_bounds__(256) void k_gemm_bf(const float* __restrict__ A, int lda,
                                                 const float* __restrict__ B, int ldb,
                                                 const float* __restrict__ bias,
                                                 ushort* __restrict__ Af,
                                                 int Mt, int colbase, int M, int K) {
    __shared__ float As[BK][BM + 4];
    __shared__ float Bs[BK][BN];
    int t = threadIdx.x;
    int tx = t & 7, ty = t >> 3;
    int row0 = blockIdx.x * BM;
    int col0 = blockIdx.y * BN;   // local col within this layer's 256

    float acc[2][8] = {};

    for (int kt = 0; kt < K; kt += BK) {
        #pragma unroll
        for (int i = 0; i < 4; i++) {
            int l = i * 256 + t;
            int m = l >> 4;
            int k = l & 15;
            int gm = row0 + m;
            float v = 0.f;
            if (gm < M) v = A[(long long)gm * lda + kt + k];
            As[k][m] = v;
        }
        #pragma unroll
        for (int i = 0; i < 4; i++) {
            int l = i * 256 + t;
            int nn = l & 63;
            int k = l >> 6;
            Bs[k][nn] = B[(long long)(kt + k) * ldb + col0 + nn];
        }
        __syncthreads();
        #pragma unroll
        for (int k = 0; k < BK; k++) {
            float a0 = As[k][ty * 2];
            float a1 = As[k][ty * 2 + 1];
            float4 b0 = *reinterpret_cast<const float4*>(&Bs[k][tx * 8]);
            float4 b1 = *reinterpret_cast<const float4*>(&Bs[k][tx * 8 + 4]);
            float b[8] = {b0.x, b0.y, b0.z, b0.w, b1.x, b1.y, b1.z, b1.w};
            #pragma unroll
            for (int j = 0; j < 8; j++) {
                acc[0][j] += a0 * b[j];
                acc[1][j] += a1 * b[j];
            }
        }
        __syncthreads();
    }

    int gn0 = col0 + tx * 8;          // local col in [0,256)
    int gcol = gn0 + colbase;         // x3 col in [0,512)
    int k0i = gcol >> 5;
    int q = (gcol >> 3) & 3;
    #pragma unroll
    for (int i = 0; i < 2; i++) {
        int gm = row0 + ty * 2 + i;   // grid covers exactly Mt*16 rows
        int mtile = gm >> 4, l = gm & 15;
        int lane = q * 16 + l;
        ushort hi[8], lo[8];
        #pragma unroll
        for (int j = 0; j < 8; j++) {
            float v = fmaxf(acc[i][j] + bias[gn0 + j], 0.f);
            float hf = bf16_val(v);
            hi[j] = bf16_bits(v);
            lo[j] = bf16_bits(v - hf);
        }
        size_t bh = (((size_t)mtile * 16 + k0i) * 64 + lane) * 8;
        size_t bl = (((size_t)(Mt + mtile) * 16 + k0i) * 64 + lane) * 8;
        *reinterpret_cast<int4*>(&Af[bh]) = *reinterpret_cast<const int4*>(hi);
        *reinterpret_cast<int4*>(&Af[bl]) = *reinterpret_cast<const int4*>(lo);
    }
}

// split+transpose weights into MFMA B-fragment order:
//   Bf[arr][k0i][nt][lane][8], element = W[k0i*32+(lane>>4)*8+j][nt*16+(lane&15)]
__global__ __launch_bounds__(256) void k_prepB(const float* __restrict__ w1,
                                               const float* __restrict__ w2,
                                               ushort* __restrict__ Bf) {
    int id = blockIdx.x * 256 + threadIdx.x;    // 2*16*16*64 = 32768
    if (id >= 32768) return;
    int lane = id & 63;
    int nt   = (id >> 6) & 15;
    int k0i  = (id >> 10) & 15;
    int arr  = id >> 14;
    int n = nt * 16 + (lane & 15);
    int kbase = k0i * 32 + (lane >> 4) * 8;
    ushort outv[8];
    #pragma unroll
    for (int j = 0; j < 8; j++) {
        int k = kbase + j;
        float v = (n < 128) ? w1[(long long)k * 128 + n]
                            : w2[(long long)k * 128 + (n - 128)];
        if (arr == 0) {
            outv[j] = bf16_bits(v);
        } else {
            float hf = bf16_val(v);
            outv[j] = bf16_bits(v - hf);
        }
    }
    *reinterpret_cast<int4*>(&Bf[(size_t)id * 8]) = *reinterpret_cast<const int4*>(outv);
}

// LDS-free split-precision MFMA dual GEMM:
//   [C1 | C2] = (Ah+Al)[M,512] @ (Bh+Bl)^T[512,256]  (3-term split)
__global__ __launch_bounds__(256) void k_gemm2_mfma(
    const ushort* __restrict__ Af, const ushort* __restrict__ Bf,
    const float* __restrict__ bias1,
    float* __restrict__ C1, float* __restrict__ C2, int M, int Mt) {
    const int t = threadIdx.x;
    const int lane = t & 63;
    const int wv = t >> 6;
    const int mt0 = blockIdx.x * 4;
    const int ln15 = lane & 15;
    const int quad = lane >> 4;

    f32x4 acc[4][4] = {};

    const size_t laneOff = (size_t)lane * 8;

    for (int k0i = 0; k0i < 16; k0i++) {
        short8 bh[4], bl[4];
        #pragma unroll
        for (int nt = 0; nt < 4; nt++) {
            size_t ib = (((size_t)k0i * 16) + (wv * 4 + nt)) * 512 + laneOff;
            bh[nt] = *reinterpret_cast<const short8*>(&Bf[ib]);
            bl[nt] = *reinterpret_cast<const short8*>(&Bf[ib + 131072]); // +16*16*64*8
        }
        #pragma unroll
        for (int mt = 0; mt < 4; mt++) {
            size_t ia = (((size_t)(mt0 + mt) * 16) + k0i) * 512 + laneOff;
            short8 ah = *reinterpret_cast<const short8*>(&Af[ia]);
            short8 al = *reinterpret_cast<const short8*>(&Af[ia + (size_t)Mt * 8192]);
            #pragma unroll
            for (int nt = 0; nt < 4; nt++) {
                acc[mt][nt] = __builtin_amdgcn_mfma_f32_16x16x32_bf16(ah, bh[nt], acc[mt][nt], 0, 0, 0);
                acc[mt][nt] = __builtin_amdgcn_mfma_f32_16x16x32_bf16(ah, bl[nt], acc[mt][nt], 0, 0, 0);
                acc[mt][nt] = __builtin_amdgcn_mfma_f32_16x16x32_bf16(al, bh[nt], acc[mt][nt], 0, 0, 0);
            }
        }
    }

    // epilogue: C/D layout col=lane&15, row=quad*4+reg
    #pragma unroll
    for (int mt = 0; mt < 4; mt++) {
        #pragma unroll
        for (int nt = 0; nt < 4; nt++) {
            int gn = wv * 64 + nt * 16 + ln15;   // 0..255
            #pragma unroll
            for (int r = 0; r < 4; r++) {
                int gm = mt0 * 16 + mt * 16 + quad * 4 + r;
                if (gm >= M) continue;
                float v = acc[mt][nt][r];
                if (gn < 128) {
                    C1[(long long)gm * 128 + gn] = fmaxf(v + bias1[gn], 0.f);
                } else {
                    C2[(long long)gm * 128 + (gn - 128)] = v;
                }
            }
        }
    }
}

// per node: out[n] = x7[n]·w_fc2 + b_fc2 + b_conv3 ; xw3[n] = x7[n]·w_conv3
__global__ __launch_bounds__(256) void k_dot(const float* __restrict__ x7,
                                             const float* __restrict__ wfc2,
                                             const float* __restrict__ bfc2,
                                             const float* __restrict__ wc3,
                                             const float* __restrict__ bc3,
                                             float* __restrict__ out,
                                             float* __restrict__ xw3, int n) {
    int lane = threadIdx.x & 63;
    int wv = threadIdx.x >> 6;
    int node = blockIdx.x * 4 + wv;
    if (node >= n) return;
    const float* xr = x7 + (long long)node * 128;
    float v0 = xr[lane], v1 = xr[64 + lane];
    float s1 = v0 * wfc2[lane] + v1 * wfc2[64 + lane];
    float s2 = v0 * wc3[lane] + v1 * wc3[64 + lane];
    #pragma unroll
    for (int o = 32; o > 0; o >>= 1) {
        s1 += __shfl_down(s1, o);
        s2 += __shfl_down(s2, o);
    }
    if (lane == 0) {
        out[node] = s1 + bfc2[0] + bc3[0];
        xw3[node] = s2;
    }
}

extern "C" void kernel_launch(void* const* d_in, const int* in_sizes, int n_in,
                              void* d_out, int out_size, void* d_ws, size_t ws_size,
                              hipStream_t stream) {
    const float* x       = (const float*)d_in[0];
    const int*   ei      = (const int*)d_in[1];
    const float* w_fc    = (const float*)d_in[2];
    const float* b_fc    = (const float*)d_in[3];
    const float* w_conv1 = (const float*)d_in[4];
    const float* b_conv1 = (const float*)d_in[5];
    const float* w_fc1   = (const float*)d_in[6];
    const float* b_fc1   = (const float*)d_in[7];
    const float* w_conv2 = (const float*)d_in[8];
    const float* b_conv2 = (const float*)d_in[9];
    const float* w_fc2   = (const float*)d_in[10];
    const float* b_fc2   = (const float*)d_in[11];
    const float* w_conv3 = (const float*)d_in[12];
    const float* b_conv3 = (const float*)d_in[13];

    const int N = in_sizes[0] / 64;       // 50000
    const int E = in_sizes[1] / 2;        // 800000
    const int* row = ei;
    const int* col = ei + E;

    const int nb = (N + 255) / 256;
    const int nblk = (N + 63) / 64;       // 782
    const int Mt = nblk * 4;              // 3128 row-tiles of 16

    // workspace layout (units of 4 bytes, chunks padded to 16B)
    char* p = (char*)d_ws;
    auto alloc = [&](size_t elems) {
        void* q = p; p += ((elems + 3) & ~(size_t)3) * 4; return q;
    };
    int*    degi    = (int*)   alloc(N);
    int*    excl    = (int*)   alloc(N);
    int*    bsum    = (int*)   alloc(256);
    int*    rowptr  = (int*)   alloc(N + 4);
    int*    cursor  = (int*)   alloc(N);
    int*    csr_row = (int*)   alloc(E);
    float*  csr_nrm = (float*) alloc(E);
    float*  dis     = (float*) alloc(N);
    float*  aggx    = (float*) alloc((size_t)N * 64);
    ushort* x3f     = (ushort*)alloc((size_t)Mt * 8192);   // 2*Mt*16*64*8 ushorts
    ushort* Bf      = (ushort*)alloc(131072);              // 2*16*16*64*8 ushorts
    float*  x5      = (float*) alloc((size_t)N * 128);
    float*  xw2     = (float*) alloc((size_t)N * 128);
    float*  xw3     = (float*) alloc(N);

    float* out = (float*)d_out;

    // ---- CSR build ----
    hipMemsetAsync(degi, 0, (size_t)N * sizeof(int), stream);
    k_count<<<(E + 255) / 256, 256, 0, stream>>>(col, degi, E);
    k_scan1<<<nb, 256, 0, stream>>>(degi, excl, bsum, N);
    k_scan2<<<1, 256, 0, stream>>>(bsum, nb);
    k_scan3<<<nb, 256, 0, stream>>>(excl, bsum, degi, rowptr, cursor, dis, N, E);
    k_scatter<<<(E + 255) / 256, 256, 0, stream>>>(row, col, dis, cursor, csr_row, csr_nrm, E);

    // weight split+transpose into B-fragment order (independent of CSR chain)
    k_prepB<<<32768 / 256, 256, 0, stream>>>(w_fc1, w_conv2, Bf);

    // conv1 propagate: aggx = A_norm @ x
    k_agg64_csr<<<(N + 3) / 4, 256, 0, stream>>>(x, rowptr, csr_row, csr_nrm, aggx, N);

    dim3 g1(nblk, 4);   // (782, 4): 64-row x 64-col tiles over 256 cols

    // x1 = relu(x @ w_fc + b_fc)          -> x3 cols [0,256)  (bf16 hi/lo frags)
    k_gemm_bf<<<g1, 256, 0, stream>>>(x, 64, w_fc, 256, b_fc, x3f, Mt, 0, N, 64);
    // x2 = relu(aggx @ w_conv1 + b_conv1) -> x3 cols [256,512)
    k_gemm_bf<<<g1, 256, 0, stream>>>(aggx, 64, w_conv1, 256, b_conv1, x3f, Mt, 256, N, 64);

    // x5 = relu(x3 @ w_fc1 + b_fc1) ; xw2 = x3 @ w_conv2   (LDS-free MFMA)
    k_gemm2_mfma<<<nblk, 256, 0, stream>>>(x3f, Bf, b_fc1, x5, xw2, N, Mt);

    // x7 = x5 + relu(A_norm @ xw2 + b_conv2)   (fused, in place in x5)
    k_agg128_x7<<<(N + 3) / 4, 256, 0, stream>>>(xw2, rowptr, csr_row, csr_nrm, b_conv2, x5, N);

    // out = x7 @ w_fc2 + b_fc2 + b_conv3 ; xw3 = x7 @ w_conv3
    k_dot<<<(N + 3) / 4, 256, 0, stream>>>(x5, w_fc2, b_fc2, w_conv3, b_conv3, out, xw3, N);

    // out += A_norm @ xw3
    k_agg1_csr<<<(N + 255) / 256, 256, 0, stream>>>(xw3, rowptr, csr_row, csr_nrm, out, N);
}

// Round 6
// 433.495 us; speedup vs baseline: 2.3545x; 1.0057x over previous
//
#include <hip/hip_runtime.h>
#include <hip/hip_bf16.h>

static constexpr int BM = 64, BN = 64, BK = 16;

typedef __attribute__((ext_vector_type(8))) short short8;
typedef __attribute__((ext_vector_type(4))) float f32x4;

__device__ __forceinline__ ushort bf16_bits(float v) {
    __hip_bfloat16 h = __float2bfloat16(v);
    return *reinterpret_cast<ushort*>(&h);
}
__device__ __forceinline__ float bf16_val(float v) {
    __hip_bfloat16 h = __float2bfloat16(v);
    return __bfloat162float(h);
}

// ---------------- CSR build ----------------

__global__ __launch_bounds__(256) void k_count(const int* __restrict__ col,
                                               int* __restrict__ degi, int E) {
    int e = blockIdx.x * 256 + threadIdx.x;
    if (e < E) atomicAdd(&degi[col[e]], 1);
}

__global__ __launch_bounds__(256) void k_scan1(const int* __restrict__ degi,
                                               int* __restrict__ excl,
                                               int* __restrict__ bsum, int n) {
    int i = blockIdx.x * 256 + threadIdx.x;
    int v = (i < n) ? degi[i] : 0;
    int lane = threadIdx.x & 63, w = threadIdx.x >> 6;
    int s = v;
    #pragma unroll
    for (int o = 1; o < 64; o <<= 1) {
        int t = __shfl_up(s, o);
        if (lane >= o) s += t;
    }
    __shared__ int wsum[4];
    if (lane == 63) wsum[w] = s;
    __syncthreads();
    int add = 0;
    for (int ww = 0; ww < w; ww++) add += wsum[ww];
    int incl = s + add;
    if (i < n) excl[i] = incl - v;
    if (threadIdx.x == 255) bsum[blockIdx.x] = incl;
}

__global__ __launch_bounds__(256) void k_scan2(int* __restrict__ bsum, int nb) {
    int i = threadIdx.x;
    int v = (i < nb) ? bsum[i] : 0;
    int lane = i & 63, w = i >> 6;
    int s = v;
    #pragma unroll
    for (int o = 1; o < 64; o <<= 1) {
        int t = __shfl_up(s, o);
        if (lane >= o) s += t;
    }
    __shared__ int wsum[4];
    if (lane == 63) wsum[w] = s;
    __syncthreads();
    int add = 0;
    for (int ww = 0; ww < w; ww++) add += wsum[ww];
    if (i < nb) bsum[i] = (s + add) - v;
}

__global__ __launch_bounds__(256) void k_scan3(const int* __restrict__ excl,
                                               const int* __restrict__ bsum,
                                               const int* __restrict__ degi,
                                               int* __restrict__ rowptr,
                                               int* __restrict__ cursor,
                                               float* __restrict__ dis,
                                               int n, int E) {
    int i = blockIdx.x * 256 + threadIdx.x;
    if (i < n) {
        int p = excl[i] + bsum[blockIdx.x];
        rowptr[i] = p;
        cursor[i] = p;
        int d = degi[i];
        dis[i] = d > 0 ? rsqrtf((float)d) : 0.f;
    }
    if (i == 0) rowptr[n] = E;
}

__global__ __launch_bounds__(256) void k_scatter(const int* __restrict__ row,
                                                 const int* __restrict__ col,
                                                 const float* __restrict__ dis,
                                                 int* __restrict__ cursor,
                                                 int* __restrict__ csr_row,
                                                 float* __restrict__ csr_nrm, int E) {
    int e = blockIdx.x * 256 + threadIdx.x;
    if (e >= E) return;
    int c = col[e], r = row[e];
    int p = atomicAdd(&cursor[c], 1);
    csr_row[p] = r;
    csr_nrm[p] = dis[r] * dis[c];
}

// ---------------- CSR aggregations (gather, no atomics) ----------------
// Batched (U=8) index prefetch + independent gathers for memory-level
// parallelism.

__global__ __launch_bounds__(256) void k_agg64_csr(const float* __restrict__ x,
                                                   const int* __restrict__ rowptr,
                                                   const int* __restrict__ csr_row,
                                                   const float* __restrict__ csr_nrm,
                                                   float* __restrict__ aggx, int n) {
    int node = blockIdx.x * 4 + (threadIdx.x >> 6);
    if (node >= n) return;
    int lane = threadIdx.x & 63;
    int s = rowptr[node], t = rowptr[node + 1];
    constexpr int U = 8;
    float acc = 0.f;
    int p = s;
    for (; p + U <= t; p += U) {
        int rr[U]; float ww[U];
        #pragma unroll
        for (int u = 0; u < U; u++) { rr[u] = csr_row[p + u]; ww[u] = csr_nrm[p + u]; }
        float vv[U];
        #pragma unroll
        for (int u = 0; u < U; u++) vv[u] = x[(long long)rr[u] * 64 + lane];
        #pragma unroll
        for (int u = 0; u < U; u++) acc += ww[u] * vv[u];
    }
    for (; p < t; ++p) {
        int r = csr_row[p];
        acc += csr_nrm[p] * x[(long long)r * 64 + lane];
    }
    aggx[(long long)node * 64 + lane] = acc;
}

__global__ __launch_bounds__(256) void k_agg128_x7(const float* __restrict__ xw,
                                                   const int* __restrict__ rowptr,
                                                   const int* __restrict__ csr_row,
                                                   const float* __restrict__ csr_nrm,
                                                   const float* __restrict__ b2,
                                                   float* __restrict__ x5, int n) {
    int node = blockIdx.x * 4 + (threadIdx.x >> 6);
    if (node >= n) return;
    int lane = threadIdx.x & 63;
    int s = rowptr[node], t = rowptr[node + 1];
    constexpr int U = 8;
    float2 acc = {0.f, 0.f};
    int p = s;
    for (; p + U <= t; p += U) {
        int rr[U]; float ww[U];
        #pragma unroll
        for (int u = 0; u < U; u++) { rr[u] = csr_row[p + u]; ww[u] = csr_nrm[p + u]; }
        float2 vv[U];
        #pragma unroll
        for (int u = 0; u < U; u++)
            vv[u] = *reinterpret_cast<const float2*>(&xw[(long long)rr[u] * 128 + lane * 2]);
        #pragma unroll
        for (int u = 0; u < U; u++) {
            acc.x += ww[u] * vv[u].x;
            acc.y += ww[u] * vv[u].y;
        }
    }
    for (; p < t; ++p) {
        int r = csr_row[p];
        float w = csr_nrm[p];
        float2 v = *reinterpret_cast<const float2*>(&xw[(long long)r * 128 + lane * 2]);
        acc.x += w * v.x;
        acc.y += w * v.y;
    }
    float2 b = *reinterpret_cast<const float2*>(&b2[lane * 2]);
    float2* o = reinterpret_cast<float2*>(&x5[(long long)node * 128 + lane * 2]);
    float2 cur = *o;
    cur.x += fmaxf(acc.x + b.x, 0.f);
    cur.y += fmaxf(acc.y + b.y, 0.f);
    *o = cur;
}

__global__ __launch_bounds__(256) void k_agg1_csr(const float* __restrict__ sv,
                                                  const int* __restrict__ rowptr,
                                                  const int* __restrict__ csr_row,
                                                  const float* __restrict__ csr_nrm,
                                                  float* __restrict__ out, int n) {
    int i = blockIdx.x * 256 + threadIdx.x;
    if (i >= n) return;
    int s = rowptr[i], t = rowptr[i + 1];
    float a = 0.f;
    #pragma unroll 4
    for (int p = s; p < t; ++p) a += csr_nrm[p] * sv[csr_row[p]];
    out[i] += a;
}

// ---------------- GEMMs ----------------

// fp32 vector GEMM (K=64 layers). Epilogue: relu(+bias), bf16 hi/lo split,
// stored directly in MFMA A-fragment order:
//   Af[arr][mtile][k0i][lane][8] ; lane = q*16 + (row&15),
//   element = x3[row][k0i*32 + q*8 + j], global x3 col = colbase + local col.
__global__ __launch_bounds__(256) void k_gemm_bf(const float* __restrict__ A, int lda,
                                                 const float* __restrict__ B, int ldb,
                                                 const float* __restrict__ bias,
                                                 ushort* __restrict__ Af,
                                                 int Mt, int colbase, int M, int K) {
    __shared__ float As[BK][BM + 4];
    __shared__ float Bs[BK][BN];
    int t = threadIdx.x;
    int tx = t & 7, ty = t >> 3;
    int row0 = blockIdx.x * BM;
    int col0 = blockIdx.y * BN;   // local col within this layer's 256

    float acc[2][8] = {};

    for (int kt = 0; kt < K; kt += BK) {
        #pragma unroll
        for (int i = 0; i < 4; i++) {
            int l = i * 256 + t;
            int m = l >> 4;
            int k = l & 15;
            int gm = row0 + m;
            float v = 0.f;
            if (gm < M) v = A[(long long)gm * lda + kt + k];
            As[k][m] = v;
        }
        #pragma unroll
        for (int i = 0; i < 4; i++) {
            int l = i * 256 + t;
            int nn = l & 63;
            int k = l >> 6;
            Bs[k][nn] = B[(long long)(kt + k) * ldb + col0 + nn];
        }
        __syncthreads();
        #pragma unroll
        for (int k = 0; k < BK; k++) {
            float a0 = As[k][ty * 2];
            float a1 = As[k][ty * 2 + 1];
            float4 b0 = *reinterpret_cast<const float4*>(&Bs[k][tx * 8]);
            float4 b1 = *reinterpret_cast<const float4*>(&Bs[k][tx * 8 + 4]);
            float b[8] = {b0.x, b0.y, b0.z, b0.w, b1.x, b1.y, b1.z, b1.w};
            #pragma unroll
            for (int j = 0; j < 8; j++) {
                acc[0][j] += a0 * b[j];
                acc[1][j] += a1 * b[j];
            }
        }
        __syncthreads();
    }

    int gn0 = col0 + tx * 8;          // local col in [0,256)
    int gcol = gn0 + colbase;         // x3 col in [0,512)
    int k0i = gcol >> 5;
    int q = (gcol >> 3) & 3;
    #pragma unroll
    for (int i = 0; i < 2; i++) {
        int gm = row0 + ty * 2 + i;   // grid covers exactly Mt*16 rows
        int mtile = gm >> 4, l = gm & 15;
        int lane = q * 16 + l;
        ushort hi[8], lo[8];
        #pragma unroll
        for (int j = 0; j < 8; j++) {
            float v = fmaxf(acc[i][j] + bias[gn0 + j], 0.f);
            float hf = bf16_val(v);
            hi[j] = bf16_bits(v);
            lo[j] = bf16_bits(v - hf);
        }
        size_t bh = (((size_t)mtile * 16 + k0i) * 64 + lane) * 8;
        size_t bl = (((size_t)(Mt + mtile) * 16 + k0i) * 64 + lane) * 8;
        *reinterpret_cast<int4*>(&Af[bh]) = *reinterpret_cast<const int4*>(hi);
        *reinterpret_cast<int4*>(&Af[bl]) = *reinterpret_cast<const int4*>(lo);
    }
}

// split+transpose weights into MFMA B-fragment order:
//   Bf[arr][k0i][nt][lane][8], element = W[k0i*32+(lane>>4)*8+j][nt*16+(lane&15)]
__global__ __launch_bounds__(256) void k_prepB(const float* __restrict__ w1,
                                               const float* __restrict__ w2,
                                               ushort* __restrict__ Bf) {
    int id = blockIdx.x * 256 + threadIdx.x;    // 2*16*16*64 = 32768
    if (id >= 32768) return;
    int lane = id & 63;
    int nt   = (id >> 6) & 15;
    int k0i  = (id >> 10) & 15;
    int arr  = id >> 14;
    int n = nt * 16 + (lane & 15);
    int kbase = k0i * 32 + (lane >> 4) * 8;
    ushort outv[8];
    #pragma unroll
    for (int j = 0; j < 8; j++) {
        int k = kbase + j;
        float v = (n < 128) ? w1[(long long)k * 128 + n]
                            : w2[(long long)k * 128 + (n - 128)];
        if (arr == 0) {
            outv[j] = bf16_bits(v);
        } else {
            float hf = bf16_val(v);
            outv[j] = bf16_bits(v - hf);
        }
    }
    *reinterpret_cast<int4*>(&Bf[(size_t)id * 8]) = *reinterpret_cast<const int4*>(outv);
}

// LDS-free split-precision MFMA dual GEMM with register double-buffered A:
//   [C1 | C2] = (Ah+Al)[M,512] @ (Bh+Bl)^T[512,256]  (3-term split)
// Per k-step: prefetch next A fragments (HBM/L3 latency) while 48 MFMAs run
// on the current ones; B is L2-resident (512 KB) and loaded just-in-time.
__global__ __launch_bounds__(256) void k_gemm2_mfma(
    const ushort* __restrict__ Af, const ushort* __restrict__ Bf,
    const float* __restrict__ bias1,
    float* __restrict__ C1, float* __restrict__ C2, int M, int Mt) {
    const int t = threadIdx.x;
    const int lane = t & 63;
    const int wv = t >> 6;
    const int mt0 = blockIdx.x * 4;
    const int ln15 = lane & 15;
    const int quad = lane >> 4;

    f32x4 acc[4][4] = {};

    const ushort* aPtr = Af + ((size_t)mt0 * 16) * 512 + (size_t)lane * 8;
    const size_t aLo = (size_t)Mt * 8192;       // lo-array offset (elements)
    const ushort* bPtr = Bf + ((size_t)wv * 4) * 512 + (size_t)lane * 8;
    const size_t bLo = 131072;                  // 16*16*64*8

    short8 ahC[4], alC[4];
    #pragma unroll
    for (int mt = 0; mt < 4; mt++) {
        const ushort* pa = aPtr + (size_t)mt * 16 * 512;   // k0i = 0
        ahC[mt] = *reinterpret_cast<const short8*>(pa);
        alC[mt] = *reinterpret_cast<const short8*>(pa + aLo);
    }

    for (int k0i = 0; k0i < 16; k0i++) {
        short8 ahN[4], alN[4];
        if (k0i < 15) {
            #pragma unroll
            for (int mt = 0; mt < 4; mt++) {
                const ushort* pa = aPtr + ((size_t)mt * 16 + k0i + 1) * 512;
                ahN[mt] = *reinterpret_cast<const short8*>(pa);
                alN[mt] = *reinterpret_cast<const short8*>(pa + aLo);
            }
        }
        short8 bh[4], bl[4];
        #pragma unroll
        for (int nt = 0; nt < 4; nt++) {
            const ushort* pb = bPtr + ((size_t)k0i * 16 + nt) * 512;
            bh[nt] = *reinterpret_cast<const short8*>(pb);
            bl[nt] = *reinterpret_cast<const short8*>(pb + bLo);
        }
        #pragma unroll
        for (int mt = 0; mt < 4; mt++)
            #pragma unroll
            for (int nt = 0; nt < 4; nt++) {
                acc[mt][nt] = __builtin_amdgcn_mfma_f32_16x16x32_bf16(ahC[mt], bh[nt], acc[mt][nt], 0, 0, 0);
                acc[mt][nt] = __builtin_amdgcn_mfma_f32_16x16x32_bf16(ahC[mt], bl[nt], acc[mt][nt], 0, 0, 0);
                acc[mt][nt] = __builtin_amdgcn_mfma_f32_16x16x32_bf16(alC[mt], bh[nt], acc[mt][nt], 0, 0, 0);
            }
        if (k0i < 15) {
            #pragma unroll
            for (int mt = 0; mt < 4; mt++) { ahC[mt] = ahN[mt]; alC[mt] = alN[mt]; }
        }
    }

    // epilogue: C/D layout col=lane&15, row=quad*4+reg
    #pragma unroll
    for (int mt = 0; mt < 4; mt++) {
        #pragma unroll
        for (int nt = 0; nt < 4; nt++) {
            int gn = wv * 64 + nt * 16 + ln15;   // 0..255
            #pragma unroll
            for (int r = 0; r < 4; r++) {
                int gm = mt0 * 16 + mt * 16 + quad * 4 + r;
                if (gm >= M) continue;
                float v = acc[mt][nt][r];
                if (gn < 128) {
                    C1[(long long)gm * 128 + gn] = fmaxf(v + bias1[gn], 0.f);
                } else {
                    C2[(long long)gm * 128 + (gn - 128)] = v;
                }
            }
        }
    }
}

// per node: out[n] = x7[n]·w_fc2 + b_fc2 + b_conv3 ; xw3[n] = x7[n]·w_conv3
__global__ __launch_bounds__(256) void k_dot(const float* __restrict__ x7,
                                             const float* __restrict__ wfc2,
                                             const float* __restrict__ bfc2,
                                             const float* __restrict__ wc3,
                                             const float* __restrict__ bc3,
                                             float* __restrict__ out,
                                             float* __restrict__ xw3, int n) {
    int lane = threadIdx.x & 63;
    int wv = threadIdx.x >> 6;
    int node = blockIdx.x * 4 + wv;
    if (node >= n) return;
    const float* xr = x7 + (long long)node * 128;
    float v0 = xr[lane], v1 = xr[64 + lane];
    float s1 = v0 * wfc2[lane] + v1 * wfc2[64 + lane];
    float s2 = v0 * wc3[lane] + v1 * wc3[64 + lane];
    #pragma unroll
    for (int o = 32; o > 0; o >>= 1) {
        s1 += __shfl_down(s1, o);
        s2 += __shfl_down(s2, o);
    }
    if (lane == 0) {
        out[node] = s1 + bfc2[0] + bc3[0];
        xw3[node] = s2;
    }
}

extern "C" void kernel_launch(void* const* d_in, const int* in_sizes, int n_in,
                              void* d_out, int out_size, void* d_ws, size_t ws_size,
                              hipStream_t stream) {
    const float* x       = (const float*)d_in[0];
    const int*   ei      = (const int*)d_in[1];
    const float* w_fc    = (const float*)d_in[2];
    const float* b_fc    = (const float*)d_in[3];
    const float* w_conv1 = (const float*)d_in[4];
    const float* b_conv1 = (const float*)d_in[5];
    const float* w_fc1   = (const float*)d_in[6];
    const float* b_fc1   = (const float*)d_in[7];
    const float* w_conv2 = (const float*)d_in[8];
    const float* b_conv2 = (const float*)d_in[9];
    const float* w_fc2   = (const float*)d_in[10];
    const float* b_fc2   = (const float*)d_in[11];
    const float* w_conv3 = (const float*)d_in[12];
    const float* b_conv3 = (const float*)d_in[13];

    const int N = in_sizes[0] / 64;       // 50000
    const int E = in_sizes[1] / 2;        // 800000
    const int* row = ei;
    const int* col = ei + E;

    const int nb = (N + 255) / 256;
    const int nblk = (N + 63) / 64;       // 782
    const int Mt = nblk * 4;              // 3128 row-tiles of 16

    // workspace layout (units of 4 bytes, chunks padded to 16B)
    char* p = (char*)d_ws;
    auto alloc = [&](size_t elems) {
        void* q = p; p += ((elems + 3) & ~(size_t)3) * 4; return q;
    };
    int*    degi    = (int*)   alloc(N);
    int*    excl    = (int*)   alloc(N);
    int*    bsum    = (int*)   alloc(256);
    int*    rowptr  = (int*)   alloc(N + 4);
    int*    cursor  = (int*)   alloc(N);
    int*    csr_row = (int*)   alloc(E);
    float*  csr_nrm = (float*) alloc(E);
    float*  dis     = (float*) alloc(N);
    float*  aggx    = (float*) alloc((size_t)N * 64);
    ushort* x3f     = (ushort*)alloc((size_t)Mt * 8192);   // 2*Mt*16*64*8 ushorts
    ushort* Bf      = (ushort*)alloc(131072);              // 2*16*16*64*8 ushorts
    float*  x5      = (float*) alloc((size_t)N * 128);
    float*  xw2     = (float*) alloc((size_t)N * 128);
    float*  xw3     = (float*) alloc(N);

    float* out = (float*)d_out;

    // ---- CSR build ----
    hipMemsetAsync(degi, 0, (size_t)N * sizeof(int), stream);
    k_count<<<(E + 255) / 256, 256, 0, stream>>>(col, degi, E);
    k_scan1<<<nb, 256, 0, stream>>>(degi, excl, bsum, N);
    k_scan2<<<1, 256, 0, stream>>>(bsum, nb);
    k_scan3<<<nb, 256, 0, stream>>>(excl, bsum, degi, rowptr, cursor, dis, N, E);
    k_scatter<<<(E + 255) / 256, 256, 0, stream>>>(row, col, dis, cursor, csr_row, csr_nrm, E);

    // weight split+transpose into B-fragment order (independent of CSR chain)
    k_prepB<<<32768 / 256, 256, 0, stream>>>(w_fc1, w_conv2, Bf);

    // conv1 propagate: aggx = A_norm @ x
    k_agg64_csr<<<(N + 3) / 4, 256, 0, stream>>>(x, rowptr, csr_row, csr_nrm, aggx, N);

    dim3 g1(nblk, 4);   // (782, 4): 64-row x 64-col tiles over 256 cols

    // x1 = relu(x @ w_fc + b_fc)          -> x3 cols [0,256)  (bf16 hi/lo frags)
    k_gemm_bf<<<g1, 256, 0, stream>>>(x, 64, w_fc, 256, b_fc, x3f, Mt, 0, N, 64);
    // x2 = relu(aggx @ w_conv1 + b_conv1) -> x3 cols [256,512)
    k_gemm_bf<<<g1, 256, 0, stream>>>(aggx, 64, w_conv1, 256, b_conv1, x3f, Mt, 256, N, 64);

    // x5 = relu(x3 @ w_fc1 + b_fc1) ; xw2 = x3 @ w_conv2   (LDS-free MFMA)
    k_gemm2_mfma<<<nblk, 256, 0, stream>>>(x3f, Bf, b_fc1, x5, xw2, N, Mt);

    // x7 = x5 + relu(A_norm @ xw2 + b_conv2)   (fused, in place in x5)
    k_agg128_x7<<<(N + 3) / 4, 256, 0, stream>>>(xw2, rowptr, csr_row, csr_nrm, b_conv2, x5, N);

    // out = x7 @ w_fc2 + b_fc2 + b_conv3 ; xw3 = x7 @ w_conv3
    k_dot<<<(N + 3) / 4, 256, 0, stream>>>(x5, w_fc2, b_fc2, w_conv3, b_conv3, out, xw3, N);

    // out += A_norm @ xw3
    k_agg1_csr<<<(N + 255) / 256, 256, 0, stream>>>(xw3, rowptr, csr_row, csr_nrm, out, N);
}

// Round 8
// 399.368 us; speedup vs baseline: 2.5557x; 1.0855x over previous
//
#include <hip/hip_runtime.h>
#include <hip/hip_bf16.h>

typedef __attribute__((ext_vector_type(8))) short short8;
typedef __attribute__((ext_vector_type(4))) float f32x4;

__device__ __forceinline__ ushort bf16_bits(float v) {
    __hip_bfloat16 h = __float2bfloat16(v);
    return *reinterpret_cast<ushort*>(&h);
}
__device__ __forceinline__ float bf16_val(float v) {
    __hip_bfloat16 h = __float2bfloat16(v);
    return __bfloat162float(h);
}
__device__ __forceinline__ float bfu_lo(uint u) {   // first (low-addr) bf16 of a pair
    uint t = u << 16; return __uint_as_float(t);
}
__device__ __forceinline__ float bfu_hi(uint u) {   // second bf16 of a pair
    uint t = u & 0xffff0000u; return __uint_as_float(t);
}
__device__ __forceinline__ float bfs(ushort h) {
    uint t = ((uint)h) << 16; return __uint_as_float(t);
}

// ---------------- CSR build ----------------

__global__ __launch_bounds__(256) void k_count(const int* __restrict__ col,
                                               int* __restrict__ degi, int E) {
    int e = blockIdx.x * 256 + threadIdx.x;
    if (e < E) atomicAdd(&degi[col[e]], 1);
}

__global__ __launch_bounds__(256) void k_scan1(const int* __restrict__ degi,
                                               int* __restrict__ excl,
                                               int* __restrict__ bsum, int n) {
    int i = blockIdx.x * 256 + threadIdx.x;
    int v = (i < n) ? degi[i] : 0;
    int lane = threadIdx.x & 63, w = threadIdx.x >> 6;
    int s = v;
    #pragma unroll
    for (int o = 1; o < 64; o <<= 1) {
        int t = __shfl_up(s, o);
        if (lane >= o) s += t;
    }
    __shared__ int wsum[4];
    if (lane == 63) wsum[w] = s;
    __syncthreads();
    int add = 0;
    for (int ww = 0; ww < w; ww++) add += wsum[ww];
    int incl = s + add;
    if (i < n) excl[i] = incl - v;
    if (threadIdx.x == 255) bsum[blockIdx.x] = incl;
}

__global__ __launch_bounds__(256) void k_scan2(int* __restrict__ bsum, int nb) {
    int i = threadIdx.x;
    int v = (i < nb) ? bsum[i] : 0;
    int lane = i & 63, w = i >> 6;
    int s = v;
    #pragma unroll
    for (int o = 1; o < 64; o <<= 1) {
        int t = __shfl_up(s, o);
        if (lane >= o) s += t;
    }
    __shared__ int wsum[4];
    if (lane == 63) wsum[w] = s;
    __syncthreads();
    int add = 0;
    for (int ww = 0; ww < w; ww++) add += wsum[ww];
    if (i < nb) bsum[i] = (s + add) - v;
}

__global__ __launch_bounds__(256) void k_scan3(const int* __restrict__ excl,
                                               const int* __restrict__ bsum,
                                               const int* __restrict__ degi,
                                               int* __restrict__ rowptr,
                                               int* __restrict__ cursor,
                                               float* __restrict__ dis,
                                               int n, int E) {
    int i = blockIdx.x * 256 + threadIdx.x;
    if (i < n) {
        int p = excl[i] + bsum[blockIdx.x];
        rowptr[i] = p;
        cursor[i] = p;
        int d = degi[i];
        dis[i] = d > 0 ? rsqrtf((float)d) : 0.f;
    }
    if (i == 0) rowptr[n] = E;
}

__global__ __launch_bounds__(256) void k_scatter(const int* __restrict__ row,
                                                 const int* __restrict__ col,
                                                 const float* __restrict__ dis,
                                                 int* __restrict__ cursor,
                                                 int* __restrict__ csr_row,
                                                 float* __restrict__ csr_nrm, int E) {
    int e = blockIdx.x * 256 + threadIdx.x;
    if (e >= E) return;
    int c = col[e], r = row[e];
    int p = atomicAdd(&cursor[c], 1);
    csr_row[p] = r;
    csr_nrm[p] = dis[r] * dis[c];
}

// ---------------- input split: x -> bf16 hi/lo ----------------

__global__ __launch_bounds__(256) void k_prepX(const float* __restrict__ x,
                                               ushort* __restrict__ xh,
                                               ushort* __restrict__ xl, int total4) {
    int i = blockIdx.x * 256 + threadIdx.x;
    if (i >= total4) return;
    float4 v = reinterpret_cast<const float4*>(x)[i];
    float vv[4] = {v.x, v.y, v.z, v.w};
    uint hv[2], lv[2];
    #pragma unroll
    for (int g = 0; g < 2; g++) {
        ushort h0 = bf16_bits(vv[g * 2]),     l0 = bf16_bits(vv[g * 2] - bf16_val(vv[g * 2]));
        ushort h1 = bf16_bits(vv[g * 2 + 1]), l1 = bf16_bits(vv[g * 2 + 1] - bf16_val(vv[g * 2 + 1]));
        hv[g] = (uint)h0 | ((uint)h1 << 16);
        lv[g] = (uint)l0 | ((uint)l1 << 16);
    }
    reinterpret_cast<uint2*>(xh)[i] = make_uint2(hv[0], hv[1]);
    reinterpret_cast<uint2*>(xl)[i] = make_uint2(lv[0], lv[1]);
}

// ---------------- CSR aggregations (gather, no atomics) ----------------

// aggx = A_norm @ x, gathering bf16 hi payload (128B/row); output split hi/lo bf16.
__global__ __launch_bounds__(256) void k_agg64_csr(const ushort* __restrict__ xh,
                                                   const int* __restrict__ rowptr,
                                                   const int* __restrict__ csr_row,
                                                   const float* __restrict__ csr_nrm,
                                                   ushort* __restrict__ agghi,
                                                   ushort* __restrict__ agglo, int n) {
    int node = blockIdx.x * 4 + (threadIdx.x >> 6);
    if (node >= n) return;
    int lane = threadIdx.x & 63;
    int s = rowptr[node], t = rowptr[node + 1];
    constexpr int U = 8;
    float acc = 0.f;
    int p = s;
    for (; p + U <= t; p += U) {
        int rr[U]; float ww[U];
        #pragma unroll
        for (int u = 0; u < U; u++) { rr[u] = csr_row[p + u]; ww[u] = csr_nrm[p + u]; }
        ushort vv[U];
        #pragma unroll
        for (int u = 0; u < U; u++) vv[u] = xh[(size_t)rr[u] * 64 + lane];
        #pragma unroll
        for (int u = 0; u < U; u++) acc += ww[u] * bfs(vv[u]);
    }
    for (; p < t; ++p)
        acc += csr_nrm[p] * bfs(xh[(size_t)csr_row[p] * 64 + lane]);
    float hf = bf16_val(acc);
    agghi[(size_t)node * 64 + lane] = bf16_bits(acc);
    agglo[(size_t)node * 64 + lane] = bf16_bits(acc - hf);
}

// x7 fused: x5 += relu(A_norm @ xw2 + b2); xw2 is packed bf16 (256B/row gather).
__global__ __launch_bounds__(256) void k_agg128_x7(const ushort* __restrict__ xw,
                                                   const int* __restrict__ rowptr,
                                                   const int* __restrict__ csr_row,
                                                   const float* __restrict__ csr_nrm,
                                                   const float* __restrict__ b2,
                                                   float* __restrict__ x5, int n) {
    int node = blockIdx.x * 4 + (threadIdx.x >> 6);
    if (node >= n) return;
    int lane = threadIdx.x & 63;
    int s = rowptr[node], t = rowptr[node + 1];
    constexpr int U = 8;
    float2 acc = {0.f, 0.f};
    int p = s;
    for (; p + U <= t; p += U) {
        int rr[U]; float ww[U];
        #pragma unroll
        for (int u = 0; u < U; u++) { rr[u] = csr_row[p + u]; ww[u] = csr_nrm[p + u]; }
        uint vv[U];
        #pragma unroll
        for (int u = 0; u < U; u++)
            vv[u] = *reinterpret_cast<const uint*>(&xw[(size_t)rr[u] * 128 + lane * 2]);
        #pragma unroll
        for (int u = 0; u < U; u++) {
            acc.x += ww[u] * bfu_lo(vv[u]);
            acc.y += ww[u] * bfu_hi(vv[u]);
        }
    }
    for (; p < t; ++p) {
        uint u = *reinterpret_cast<const uint*>(&xw[(size_t)csr_row[p] * 128 + lane * 2]);
        float w = csr_nrm[p];
        acc.x += w * bfu_lo(u);
        acc.y += w * bfu_hi(u);
    }
    float2 b = *reinterpret_cast<const float2*>(&b2[lane * 2]);
    float2* o = reinterpret_cast<float2*>(&x5[(size_t)node * 128 + lane * 2]);
    float2 cur = *o;
    cur.x += fmaxf(acc.x + b.x, 0.f);
    cur.y += fmaxf(acc.y + b.y, 0.f);
    *o = cur;
}

__global__ __launch_bounds__(256) void k_agg1_csr(const float* __restrict__ sv,
                                                  const int* __restrict__ rowptr,
                                                  const int* __restrict__ csr_row,
                                                  const float* __restrict__ csr_nrm,
                                                  float* __restrict__ out, int n) {
    int i = blockIdx.x * 256 + threadIdx.x;
    if (i >= n) return;
    int s = rowptr[i], t = rowptr[i + 1];
    float a = 0.f;
    #pragma unroll 4
    for (int p = s; p < t; ++p) a += csr_nrm[p] * sv[csr_row[p]];
    out[i] += a;
}

// ---------------- weight fragment packing ----------------

// K=64 layer weights [64][256] -> B-frag order:
//   Wf[arr][k0i(2)][nt(16)][lane][8], elem = W[k0i*32+(lane>>4)*8+j][nt*16+(lane&15)]
__global__ __launch_bounds__(256) void k_prepW64(const float* __restrict__ w0,
                                                 const float* __restrict__ w1,
                                                 ushort* __restrict__ W0f,
                                                 ushort* __restrict__ W1f) {
    int id = blockIdx.x * 256 + threadIdx.x;   // 2 mats * 4096
    if (id >= 8192) return;
    int mat = id >> 12;
    int rem = id & 4095;                       // arr*2048 + k0i*1024 + nt*64 + lane
    int lane = rem & 63;
    int nt = (rem >> 6) & 15;
    int k0i = (rem >> 10) & 1;
    int arr = rem >> 11;
    const float* w = mat ? w1 : w0;
    ushort* dst = mat ? W1f : W0f;
    int n = nt * 16 + (lane & 15);
    int kb = k0i * 32 + (lane >> 4) * 8;
    ushort o[8];
    #pragma unroll
    for (int j = 0; j < 8; j++) {
        float v = w[(size_t)(kb + j) * 256 + n];
        o[j] = arr ? bf16_bits(v - bf16_val(v)) : bf16_bits(v);
    }
    *reinterpret_cast<int4*>(&dst[(size_t)rem * 8]) = *reinterpret_cast<const int4*>(o);
}

// K=512 weights (w_fc1|w_conv2, [512][128] each) -> Bf[arr][k0i(16)][nt(16)][lane][8]
__global__ __launch_bounds__(256) void k_prepB(const float* __restrict__ w1,
                                               const float* __restrict__ w2,
                                               ushort* __restrict__ Bf) {
    int id = blockIdx.x * 256 + threadIdx.x;    // 2*16*16*64 = 32768
    if (id >= 32768) return;
    int lane = id & 63;
    int nt   = (id >> 6) & 15;
    int k0i  = (id >> 10) & 15;
    int arr  = id >> 14;
    int n = nt * 16 + (lane & 15);
    int kbase = k0i * 32 + (lane >> 4) * 8;
    ushort outv[8];
    #pragma unroll
    for (int j = 0; j < 8; j++) {
        int k = kbase + j;
        float v = (n < 128) ? w1[(size_t)k * 128 + n]
                            : w2[(size_t)k * 128 + (n - 128)];
        outv[j] = arr ? bf16_bits(v - bf16_val(v)) : bf16_bits(v);
    }
    *reinterpret_cast<int4*>(&Bf[(size_t)id * 8]) = *reinterpret_cast<const int4*>(outv);
}

// ---------------- MFMA GEMMs ----------------

// K=64 dual-layer MFMA GEMM (blockIdx.y = layer):
//   layer0: x3[:,0:256)  = relu((xh+xl)    @ (w_fc  h+l) + b_fc)
//   layer1: x3[:,256:512)= relu((agghi+lo) @ (w_conv1 h+l) + b_conv1)
// A in natural [node][64] bf16 layout; output written as x3f A-fragments.
__global__ __launch_bounds__(256) void k_mm64(
    const ushort* __restrict__ xh, const ushort* __restrict__ xl,
    const ushort* __restrict__ ah_, const ushort* __restrict__ al_,
    const ushort* __restrict__ W0f, const ushort* __restrict__ W1f,
    const float* __restrict__ b0, const float* __restrict__ b1,
    ushort* __restrict__ Af, int M, int Mt) {
    const int layer = blockIdx.y;
    const ushort* Ah = layer ? ah_ : xh;
    const ushort* Al = layer ? al_ : xl;
    const ushort* Wf = layer ? W1f : W0f;
    const float* bias = layer ? b1 : b0;
    const int colbase = layer * 256;

    const int t = threadIdx.x;
    const int lane = t & 63;
    const int wv = t >> 6;
    const int m0 = blockIdx.x * 64;
    const int ln15 = lane & 15;
    const int quad = lane >> 4;

    f32x4 acc[4][4] = {};

    #pragma unroll
    for (int k0i = 0; k0i < 2; k0i++) {
        short8 bh[4], bl[4];
        #pragma unroll
        for (int nt4 = 0; nt4 < 4; nt4++) {
            const ushort* pw = Wf + ((size_t)k0i * 16 + wv * 4 + nt4) * 512 + (size_t)lane * 8;
            bh[nt4] = *reinterpret_cast<const short8*>(pw);
            bl[nt4] = *reinterpret_cast<const short8*>(pw + 16384);   // arr=1 offset
        }
        #pragma unroll
        for (int mt = 0; mt < 4; mt++) {
            int gm = m0 + mt * 16 + ln15;
            int gmc = gm < M - 1 ? gm : M - 1;   // clamp: avoid OOB reads on tail rows
            size_t ia = (size_t)gmc * 64 + k0i * 32 + quad * 8;
            short8 ah = *reinterpret_cast<const short8*>(&Ah[ia]);
            short8 al = *reinterpret_cast<const short8*>(&Al[ia]);
            #pragma unroll
            for (int nt4 = 0; nt4 < 4; nt4++) {
                acc[mt][nt4] = __builtin_amdgcn_mfma_f32_16x16x32_bf16(ah, bh[nt4], acc[mt][nt4], 0, 0, 0);
                acc[mt][nt4] = __builtin_amdgcn_mfma_f32_16x16x32_bf16(ah, bl[nt4], acc[mt][nt4], 0, 0, 0);
                acc[mt][nt4] = __builtin_amdgcn_mfma_f32_16x16x32_bf16(al, bh[nt4], acc[mt][nt4], 0, 0, 0);
            }
        }
    }

    // epilogue: C layout col=lane&15, row=quad*4+r -> x3f fragment scatter
    // (write ALL rows incl. tail clamp-duplicates so no fragment stays poisoned)
    #pragma unroll
    for (int mt = 0; mt < 4; mt++) {
        #pragma unroll
        for (int nt4 = 0; nt4 < 4; nt4++) {
            int gn = wv * 64 + nt4 * 16 + ln15;      // local col 0..255
            int gcol = gn + colbase;                 // x3 col 0..511
            int k0f = gcol >> 5, qf = (gcol >> 3) & 3, j = gcol & 7;
            #pragma unroll
            for (int r = 0; r < 4; r++) {
                int gm = m0 + mt * 16 + quad * 4 + r;
                float v = fmaxf(acc[mt][nt4][r] + bias[gn], 0.f);
                float hf = bf16_val(v);
                size_t base = (((size_t)(gm >> 4)) * 16 + k0f) * 512 + (size_t)(qf * 16 + (gm & 15)) * 8 + j;
                Af[base] = bf16_bits(v);
                Af[base + (size_t)Mt * 8192] = bf16_bits(v - hf);
            }
        }
    }
}

// LDS-free split-precision MFMA dual GEMM with register double-buffered A:
//   [C1 | C2] = (Ah+Al)[M,512] @ (Bh+Bl)^T[512,256]
//   C1 = relu(+bias1) -> x5 (fp32) ; C2 -> xw2 (packed bf16, gather payload)
__global__ __launch_bounds__(256) void k_gemm2_mfma(
    const ushort* __restrict__ Af, const ushort* __restrict__ Bf,
    const float* __restrict__ bias1,
    float* __restrict__ C1, ushort* __restrict__ C2, int M, int Mt) {
    const int t = threadIdx.x;
    const int lane = t & 63;
    const int wv = t >> 6;
    const int mt0 = blockIdx.x * 4;
    const int ln15 = lane & 15;
    const int quad = lane >> 4;

    f32x4 acc[4][4] = {};

    const ushort* aPtr = Af + ((size_t)mt0 * 16) * 512 + (size_t)lane * 8;
    const size_t aLo = (size_t)Mt * 8192;
    const ushort* bPtr = Bf + ((size_t)wv * 4) * 512 + (size_t)lane * 8;
    const size_t bLo = 131072;

    short8 ahC[4], alC[4];
    #pragma unroll
    for (int mt = 0; mt < 4; mt++) {
        const ushort* pa = aPtr + (size_t)mt * 16 * 512;
        ahC[mt] = *reinterpret_cast<const short8*>(pa);
        alC[mt] = *reinterpret_cast<const short8*>(pa + aLo);
    }

    for (int k0i = 0; k0i < 16; k0i++) {
        short8 ahN[4], alN[4];
        if (k0i < 15) {
            #pragma unroll
            for (int mt = 0; mt < 4; mt++) {
                const ushort* pa = aPtr + ((size_t)mt * 16 + k0i + 1) * 512;
                ahN[mt] = *reinterpret_cast<const short8*>(pa);
                alN[mt] = *reinterpret_cast<const short8*>(pa + aLo);
            }
        }
        short8 bh[4], bl[4];
        #pragma unroll
        for (int nt = 0; nt < 4; nt++) {
            const ushort* pb = bPtr + ((size_t)k0i * 16 + nt) * 512;
            bh[nt] = *reinterpret_cast<const short8*>(pb);
            bl[nt] = *reinterpret_cast<const short8*>(pb + bLo);
        }
        #pragma unroll
        for (int mt = 0; mt < 4; mt++)
            #pragma unroll
            for (int nt = 0; nt < 4; nt++) {
                acc[mt][nt] = __builtin_amdgcn_mfma_f32_16x16x32_bf16(ahC[mt], bh[nt], acc[mt][nt], 0, 0, 0);
                acc[mt][nt] = __builtin_amdgcn_mfma_f32_16x16x32_bf16(ahC[mt], bl[nt], acc[mt][nt], 0, 0, 0);
                acc[mt][nt] = __builtin_amdgcn_mfma_f32_16x16x32_bf16(alC[mt], bh[nt], acc[mt][nt], 0, 0, 0);
            }
        if (k0i < 15) {
            #pragma unroll
            for (int mt = 0; mt < 4; mt++) { ahC[mt] = ahN[mt]; alC[mt] = alN[mt]; }
        }
    }

    #pragma unroll
    for (int mt = 0; mt < 4; mt++) {
        #pragma unroll
        for (int nt = 0; nt < 4; nt++) {
            int gn = wv * 64 + nt * 16 + ln15;   // 0..255
            #pragma unroll
            for (int r = 0; r < 4; r++) {
                int gm = mt0 * 16 + mt * 16 + quad * 4 + r;
                if (gm >= M) continue;
                float v = acc[mt][nt][r];
                if (gn < 128) {
                    C1[(size_t)gm * 128 + gn] = fmaxf(v + bias1[gn], 0.f);
                } else {
                    C2[(size_t)gm * 128 + (gn - 128)] = bf16_bits(v);
                }
            }
        }
    }
}

// per node: out[n] = x7[n]·w_fc2 + b_fc2 + b_conv3 ; xw3[n] = x7[n]·w_conv3
__global__ __launch_bounds__(256) void k_dot(const float* __restrict__ x7,
                                             const float* __restrict__ wfc2,
                                             const float* __restrict__ bfc2,
                                             const float* __restrict__ wc3,
                                             const float* __restrict__ bc3,
                                             float* __restrict__ out,
                                             float* __restrict__ xw3, int n) {
    int lane = threadIdx.x & 63;
    int wv = threadIdx.x >> 6;
    int node = blockIdx.x * 4 + wv;
    if (node >= n) return;
    const float* xr = x7 + (size_t)node * 128;
    float v0 = xr[lane], v1 = xr[64 + lane];
    float s1 = v0 * wfc2[lane] + v1 * wfc2[64 + lane];
    float s2 = v0 * wc3[lane] + v1 * wc3[64 + lane];
    #pragma unroll
    for (int o = 32; o > 0; o >>= 1) {
        s1 += __shfl_down(s1, o);
        s2 += __shfl_down(s2, o);
    }
    if (lane == 0) {
        out[node] = s1 + bfc2[0] + bc3[0];
        xw3[node] = s2;
    }
}

extern "C" void kernel_launch(void* const* d_in, const int* in_sizes, int n_in,
                              void* d_out, int out_size, void* d_ws, size_t ws_size,
                              hipStream_t stream) {
    const float* x       = (const float*)d_in[0];
    const int*   ei      = (const int*)d_in[1];
    const float* w_fc    = (const float*)d_in[2];
    const float* b_fc    = (const float*)d_in[3];
    const float* w_conv1 = (const float*)d_in[4];
    const float* b_conv1 = (const float*)d_in[5];
    const float* w_fc1   = (const float*)d_in[6];
    const float* b_fc1   = (const float*)d_in[7];
    const float* w_conv2 = (const float*)d_in[8];
    const float* b_conv2 = (const float*)d_in[9];
    const float* w_fc2   = (const float*)d_in[10];
    const float* b_fc2   = (const float*)d_in[11];
    const float* w_conv3 = (const float*)d_in[12];
    const float* b_conv3 = (const float*)d_in[13];

    const int N = in_sizes[0] / 64;       // 50000
    const int E = in_sizes[1] / 2;        // 800000
    const int* row = ei;
    const int* col = ei + E;

    const int nb = (N + 255) / 256;
    const int nblk = (N + 63) / 64;       // 782
    const int Mt = nblk * 4;              // 3128 row-tiles of 16

    // workspace layout. alloc() takes 4-BYTE units (chunks padded to 16B).
    // bf16 buffers: count ushorts, divide by 2.
    char* p = (char*)d_ws;
    auto alloc = [&](size_t elems) {
        void* q = p; p += ((elems + 3) & ~(size_t)3) * 4; return q;
    };
    int*    degi    = (int*)   alloc(N);
    int*    excl    = (int*)   alloc(N);
    int*    bsum    = (int*)   alloc(256);
    int*    rowptr  = (int*)   alloc(N + 4);
    int*    cursor  = (int*)   alloc(N);
    int*    csr_row = (int*)   alloc(E);
    float*  csr_nrm = (float*) alloc(E);
    float*  dis     = (float*) alloc(N);
    ushort* xh      = (ushort*)alloc((size_t)N * 32);      // N*64 bf16 = N*32 words
    ushort* xl      = (ushort*)alloc((size_t)N * 32);
    ushort* agghi   = (ushort*)alloc((size_t)N * 32);
    ushort* agglo   = (ushort*)alloc((size_t)N * 32);
    ushort* x3f     = (ushort*)alloc((size_t)Mt * 8192);   // 2 arrays, Mt*16384 ushorts
    ushort* Bf      = (ushort*)alloc(131072);              // 262144 ushorts
    ushort* W0f     = (ushort*)alloc(16384);               // 32768 ushorts
    ushort* W1f     = (ushort*)alloc(16384);
    float*  x5      = (float*) alloc((size_t)N * 128);
    ushort* xw2     = (ushort*)alloc((size_t)N * 64);      // N*128 bf16 = N*64 words
    float*  xw3     = (float*) alloc(N);

    float* out = (float*)d_out;

    // ---- CSR build ----
    hipMemsetAsync(degi, 0, (size_t)N * sizeof(int), stream);
    k_count<<<(E + 255) / 256, 256, 0, stream>>>(col, degi, E);
    k_scan1<<<nb, 256, 0, stream>>>(degi, excl, bsum, N);
    k_scan2<<<1, 256, 0, stream>>>(bsum, nb);
    k_scan3<<<nb, 256, 0, stream>>>(excl, bsum, degi, rowptr, cursor, dis, N, E);
    k_scatter<<<(E + 255) / 256, 256, 0, stream>>>(row, col, dis, cursor, csr_row, csr_nrm, E);

    // input split + weight fragment packing (independent of CSR chain)
    k_prepX<<<(N * 16 + 255) / 256, 256, 0, stream>>>(x, xh, xl, N * 16);
    k_prepW64<<<8192 / 256, 256, 0, stream>>>(w_fc, w_conv1, W0f, W1f);
    k_prepB<<<32768 / 256, 256, 0, stream>>>(w_fc1, w_conv2, Bf);

    // conv1 propagate: agg = A_norm @ x (bf16 payload), output split hi/lo
    k_agg64_csr<<<(N + 3) / 4, 256, 0, stream>>>(xh, rowptr, csr_row, csr_nrm, agghi, agglo, N);

    // x1/x2 layers via MFMA -> x3f fragments
    k_mm64<<<dim3(nblk, 2), 256, 0, stream>>>(xh, xl, agghi, agglo, W0f, W1f,
                                              b_fc, b_conv1, x3f, N, Mt);

    // x5 = relu(x3 @ w_fc1 + b_fc1) ; xw2 = x3 @ w_conv2 (bf16 packed)
    k_gemm2_mfma<<<nblk, 256, 0, stream>>>(x3f, Bf, b_fc1, x5, xw2, N, Mt);

    // x7 = x5 + relu(A_norm @ xw2 + b_conv2)   (fused, in place in x5)
    k_agg128_x7<<<(N + 3) / 4, 256, 0, stream>>>(xw2, rowptr, csr_row, csr_nrm, b_conv2, x5, N);

    // out = x7 @ w_fc2 + b_fc2 + b_conv3 ; xw3 = x7 @ w_conv3
    k_dot<<<(N + 3) / 4, 256, 0, stream>>>(x5, w_fc2, b_fc2, w_conv3, b_conv3, out, xw3, N);

    // out += A_norm @ xw3
    k_agg1_csr<<<(N + 255) / 256, 256, 0, stream>>>(xw3, rowptr, csr_row, csr_nrm, out, N);
}

// Round 9
// 366.267 us; speedup vs baseline: 2.7867x; 1.0904x over previous
//
#include <hip/hip_runtime.h>
#include <hip/hip_bf16.h>

typedef __attribute__((ext_vector_type(8))) short short8;
typedef __attribute__((ext_vector_type(4))) float f32x4;

__device__ __forceinline__ ushort bf16_bits(float v) {
    __hip_bfloat16 h = __float2bfloat16(v);
    return *reinterpret_cast<ushort*>(&h);
}
__device__ __forceinline__ float bf16_val(float v) {
    __hip_bfloat16 h = __float2bfloat16(v);
    return __bfloat162float(h);
}
__device__ __forceinline__ float bfu_lo(uint u) {   // first (low-addr) bf16 of a pair
    uint t = u << 16; return __uint_as_float(t);
}
__device__ __forceinline__ float bfu_hi(uint u) {   // second bf16 of a pair
    uint t = u & 0xffff0000u; return __uint_as_float(t);
}
__device__ __forceinline__ float bfs(ushort h) {
    uint t = ((uint)h) << 16; return __uint_as_float(t);
}

// ---------------- CSR build ----------------

__global__ __launch_bounds__(256) void k_count(const int* __restrict__ col,
                                               int* __restrict__ degi, int E) {
    int e = blockIdx.x * 256 + threadIdx.x;
    if (e < E) atomicAdd(&degi[col[e]], 1);
}

__global__ __launch_bounds__(256) void k_scan1(const int* __restrict__ degi,
                                               int* __restrict__ excl,
                                               int* __restrict__ bsum, int n) {
    int i = blockIdx.x * 256 + threadIdx.x;
    int v = (i < n) ? degi[i] : 0;
    int lane = threadIdx.x & 63, w = threadIdx.x >> 6;
    int s = v;
    #pragma unroll
    for (int o = 1; o < 64; o <<= 1) {
        int t = __shfl_up(s, o);
        if (lane >= o) s += t;
    }
    __shared__ int wsum[4];
    if (lane == 63) wsum[w] = s;
    __syncthreads();
    int add = 0;
    for (int ww = 0; ww < w; ww++) add += wsum[ww];
    int incl = s + add;
    if (i < n) excl[i] = incl - v;
    if (threadIdx.x == 255) bsum[blockIdx.x] = incl;
}

__global__ __launch_bounds__(256) void k_scan2(int* __restrict__ bsum, int nb) {
    int i = threadIdx.x;
    int v = (i < nb) ? bsum[i] : 0;
    int lane = i & 63, w = i >> 6;
    int s = v;
    #pragma unroll
    for (int o = 1; o < 64; o <<= 1) {
        int t = __shfl_up(s, o);
        if (lane >= o) s += t;
    }
    __shared__ int wsum[4];
    if (lane == 63) wsum[w] = s;
    __syncthreads();
    int add = 0;
    for (int ww = 0; ww < w; ww++) add += wsum[ww];
    if (i < nb) bsum[i] = (s + add) - v;
}

__global__ __launch_bounds__(256) void k_scan3(const int* __restrict__ excl,
                                               const int* __restrict__ bsum,
                                               const int* __restrict__ degi,
                                               int* __restrict__ rowptr,
                                               int* __restrict__ cursor,
                                               float* __restrict__ dis,
                                               int n, int E) {
    int i = blockIdx.x * 256 + threadIdx.x;
    if (i < n) {
        int p = excl[i] + bsum[blockIdx.x];
        rowptr[i] = p;
        cursor[i] = p;
        int d = degi[i];
        dis[i] = d > 0 ? rsqrtf((float)d) : 0.f;
    }
    if (i == 0) rowptr[n] = E;
}

__global__ __launch_bounds__(256) void k_scatter(const int* __restrict__ row,
                                                 const int* __restrict__ col,
                                                 const float* __restrict__ dis,
                                                 int* __restrict__ cursor,
                                                 int* __restrict__ csr_row,
                                                 float* __restrict__ csr_nrm, int E) {
    int e = blockIdx.x * 256 + threadIdx.x;
    if (e >= E) return;
    int c = col[e], r = row[e];
    int p = atomicAdd(&cursor[c], 1);
    csr_row[p] = r;
    csr_nrm[p] = dis[r] * dis[c];
}

// ---------------- input split: x -> bf16 hi/lo ----------------

__global__ __launch_bounds__(256) void k_prepX(const float* __restrict__ x,
                                               ushort* __restrict__ xh,
                                               ushort* __restrict__ xl, int total4) {
    int i = blockIdx.x * 256 + threadIdx.x;
    if (i >= total4) return;
    float4 v = reinterpret_cast<const float4*>(x)[i];
    float vv[4] = {v.x, v.y, v.z, v.w};
    uint hv[2], lv[2];
    #pragma unroll
    for (int g = 0; g < 2; g++) {
        ushort h0 = bf16_bits(vv[g * 2]),     l0 = bf16_bits(vv[g * 2] - bf16_val(vv[g * 2]));
        ushort h1 = bf16_bits(vv[g * 2 + 1]), l1 = bf16_bits(vv[g * 2 + 1] - bf16_val(vv[g * 2 + 1]));
        hv[g] = (uint)h0 | ((uint)h1 << 16);
        lv[g] = (uint)l0 | ((uint)l1 << 16);
    }
    reinterpret_cast<uint2*>(xh)[i] = make_uint2(hv[0], hv[1]);
    reinterpret_cast<uint2*>(xl)[i] = make_uint2(lv[0], lv[1]);
}

// ---------------- CSR aggregations (gather, no atomics) ----------------

// aggx = A_norm @ x, gathering bf16 hi payload (128B/row); output split hi/lo bf16.
__global__ __launch_bounds__(256) void k_agg64_csr(const ushort* __restrict__ xh,
                                                   const int* __restrict__ rowptr,
                                                   const int* __restrict__ csr_row,
                                                   const float* __restrict__ csr_nrm,
                                                   ushort* __restrict__ agghi,
                                                   ushort* __restrict__ agglo, int n) {
    int node = blockIdx.x * 4 + (threadIdx.x >> 6);
    if (node >= n) return;
    int lane = threadIdx.x & 63;
    int s = rowptr[node], t = rowptr[node + 1];
    constexpr int U = 8;
    float acc = 0.f;
    int p = s;
    for (; p + U <= t; p += U) {
        int rr[U]; float ww[U];
        #pragma unroll
        for (int u = 0; u < U; u++) { rr[u] = csr_row[p + u]; ww[u] = csr_nrm[p + u]; }
        ushort vv[U];
        #pragma unroll
        for (int u = 0; u < U; u++) vv[u] = xh[(size_t)rr[u] * 64 + lane];
        #pragma unroll
        for (int u = 0; u < U; u++) acc += ww[u] * bfs(vv[u]);
    }
    for (; p < t; ++p)
        acc += csr_nrm[p] * bfs(xh[(size_t)csr_row[p] * 64 + lane]);
    float hf = bf16_val(acc);
    agghi[(size_t)node * 64 + lane] = bf16_bits(acc);
    agglo[(size_t)node * 64 + lane] = bf16_bits(acc - hf);
}

// x7 fused: x5 += relu(A_norm @ xw2 + b2); xw2 is packed bf16 (256B/row gather).
__global__ __launch_bounds__(256) void k_agg128_x7(const ushort* __restrict__ xw,
                                                   const int* __restrict__ rowptr,
                                                   const int* __restrict__ csr_row,
                                                   const float* __restrict__ csr_nrm,
                                                   const float* __restrict__ b2,
                                                   float* __restrict__ x5, int n) {
    int node = blockIdx.x * 4 + (threadIdx.x >> 6);
    if (node >= n) return;
    int lane = threadIdx.x & 63;
    int s = rowptr[node], t = rowptr[node + 1];
    constexpr int U = 8;
    float2 acc = {0.f, 0.f};
    int p = s;
    for (; p + U <= t; p += U) {
        int rr[U]; float ww[U];
        #pragma unroll
        for (int u = 0; u < U; u++) { rr[u] = csr_row[p + u]; ww[u] = csr_nrm[p + u]; }
        uint vv[U];
        #pragma unroll
        for (int u = 0; u < U; u++)
            vv[u] = *reinterpret_cast<const uint*>(&xw[(size_t)rr[u] * 128 + lane * 2]);
        #pragma unroll
        for (int u = 0; u < U; u++) {
            acc.x += ww[u] * bfu_lo(vv[u]);
            acc.y += ww[u] * bfu_hi(vv[u]);
        }
    }
    for (; p < t; ++p) {
        uint u = *reinterpret_cast<const uint*>(&xw[(size_t)csr_row[p] * 128 + lane * 2]);
        float w = csr_nrm[p];
        acc.x += w * bfu_lo(u);
        acc.y += w * bfu_hi(u);
    }
    float2 b = *reinterpret_cast<const float2*>(&b2[lane * 2]);
    float2* o = reinterpret_cast<float2*>(&x5[(size_t)node * 128 + lane * 2]);
    float2 cur = *o;
    cur.x += fmaxf(acc.x + b.x, 0.f);
    cur.y += fmaxf(acc.y + b.y, 0.f);
    *o = cur;
}

__global__ __launch_bounds__(256) void k_agg1_csr(const float* __restrict__ sv,
                                                  const int* __restrict__ rowptr,
                                                  const int* __restrict__ csr_row,
                                                  const float* __restrict__ csr_nrm,
                                                  float* __restrict__ out, int n) {
    int i = blockIdx.x * 256 + threadIdx.x;
    if (i >= n) return;
    int s = rowptr[i], t = rowptr[i + 1];
    float a = 0.f;
    #pragma unroll 4
    for (int p = s; p < t; ++p) a += csr_nrm[p] * sv[csr_row[p]];
    out[i] += a;
}

// ---------------- weight fragment packing ----------------

// K=64 layer weights [64][256] -> B-frag order:
//   Wf[arr][k0i(2)][nt(16)][lane][8], elem = W[k0i*32+(lane>>4)*8+j][nt*16+(lane&15)]
__global__ __launch_bounds__(256) void k_prepW64(const float* __restrict__ w0,
                                                 const float* __restrict__ w1,
                                                 ushort* __restrict__ W0f,
                                                 ushort* __restrict__ W1f) {
    int id = blockIdx.x * 256 + threadIdx.x;   // 2 mats * 4096
    if (id >= 8192) return;
    int mat = id >> 12;
    int rem = id & 4095;                       // arr*2048 + k0i*1024 + nt*64 + lane
    int lane = rem & 63;
    int nt = (rem >> 6) & 15;
    int k0i = (rem >> 10) & 1;
    int arr = rem >> 11;
    const float* w = mat ? w1 : w0;
    ushort* dst = mat ? W1f : W0f;
    int n = nt * 16 + (lane & 15);
    int kb = k0i * 32 + (lane >> 4) * 8;
    ushort o[8];
    #pragma unroll
    for (int j = 0; j < 8; j++) {
        float v = w[(size_t)(kb + j) * 256 + n];
        o[j] = arr ? bf16_bits(v - bf16_val(v)) : bf16_bits(v);
    }
    *reinterpret_cast<int4*>(&dst[(size_t)rem * 8]) = *reinterpret_cast<const int4*>(o);
}

// K=512 weights (w_fc1|w_conv2, [512][128] each) -> Bf[arr][k0i(16)][nt(16)][lane][8]
__global__ __launch_bounds__(256) void k_prepB(const float* __restrict__ w1,
                                               const float* __restrict__ w2,
                                               ushort* __restrict__ Bf) {
    int id = blockIdx.x * 256 + threadIdx.x;    // 2*16*16*64 = 32768
    if (id >= 32768) return;
    int lane = id & 63;
    int nt   = (id >> 6) & 15;
    int k0i  = (id >> 10) & 15;
    int arr  = id >> 14;
    int n = nt * 16 + (lane & 15);
    int kbase = k0i * 32 + (lane >> 4) * 8;
    ushort outv[8];
    #pragma unroll
    for (int j = 0; j < 8; j++) {
        int k = kbase + j;
        float v = (n < 128) ? w1[(size_t)k * 128 + n]
                            : w2[(size_t)k * 128 + (n - 128)];
        outv[j] = arr ? bf16_bits(v - bf16_val(v)) : bf16_bits(v);
    }
    *reinterpret_cast<int4*>(&Bf[(size_t)id * 8]) = *reinterpret_cast<const int4*>(outv);
}

// ---------------- MFMA GEMMs ----------------

// K=64 dual-layer MFMA GEMM (blockIdx.y = layer):
//   layer0: x3[:,0:256)  = relu((xh+xl)    @ (w_fc  h+l) + b_fc)
//   layer1: x3[:,256:512)= relu((agghi+lo) @ (w_conv1 h+l) + b_conv1)
// A in natural [node][64] bf16 layout; output written as x3f A-fragments
// in SINGLE bf16 (hi only) — the K=512 GEMM runs a 2-term split.
__global__ __launch_bounds__(256) void k_mm64(
    const ushort* __restrict__ xh, const ushort* __restrict__ xl,
    const ushort* __restrict__ ah_, const ushort* __restrict__ al_,
    const ushort* __restrict__ W0f, const ushort* __restrict__ W1f,
    const float* __restrict__ b0, const float* __restrict__ b1,
    ushort* __restrict__ Af, int M) {
    const int layer = blockIdx.y;
    const ushort* Ah = layer ? ah_ : xh;
    const ushort* Al = layer ? al_ : xl;
    const ushort* Wf = layer ? W1f : W0f;
    const float* bias = layer ? b1 : b0;
    const int colbase = layer * 256;

    const int t = threadIdx.x;
    const int lane = t & 63;
    const int wv = t >> 6;
    const int m0 = blockIdx.x * 64;
    const int ln15 = lane & 15;
    const int quad = lane >> 4;

    f32x4 acc[4][4] = {};

    #pragma unroll
    for (int k0i = 0; k0i < 2; k0i++) {
        short8 bh[4], bl[4];
        #pragma unroll
        for (int nt4 = 0; nt4 < 4; nt4++) {
            const ushort* pw = Wf + ((size_t)k0i * 16 + wv * 4 + nt4) * 512 + (size_t)lane * 8;
            bh[nt4] = *reinterpret_cast<const short8*>(pw);
            bl[nt4] = *reinterpret_cast<const short8*>(pw + 16384);   // arr=1 offset
        }
        #pragma unroll
        for (int mt = 0; mt < 4; mt++) {
            int gm = m0 + mt * 16 + ln15;
            int gmc = gm < M - 1 ? gm : M - 1;   // clamp: avoid OOB reads on tail rows
            size_t ia = (size_t)gmc * 64 + k0i * 32 + quad * 8;
            short8 ah = *reinterpret_cast<const short8*>(&Ah[ia]);
            short8 al = *reinterpret_cast<const short8*>(&Al[ia]);
            #pragma unroll
            for (int nt4 = 0; nt4 < 4; nt4++) {
                acc[mt][nt4] = __builtin_amdgcn_mfma_f32_16x16x32_bf16(ah, bh[nt4], acc[mt][nt4], 0, 0, 0);
                acc[mt][nt4] = __builtin_amdgcn_mfma_f32_16x16x32_bf16(ah, bl[nt4], acc[mt][nt4], 0, 0, 0);
                acc[mt][nt4] = __builtin_amdgcn_mfma_f32_16x16x32_bf16(al, bh[nt4], acc[mt][nt4], 0, 0, 0);
            }
        }
    }

    // epilogue: C layout col=lane&15, row=quad*4+r -> x3f fragment scatter (hi only)
    #pragma unroll
    for (int mt = 0; mt < 4; mt++) {
        #pragma unroll
        for (int nt4 = 0; nt4 < 4; nt4++) {
            int gn = wv * 64 + nt4 * 16 + ln15;      // local col 0..255
            int gcol = gn + colbase;                 // x3 col 0..511
            int k0f = gcol >> 5, qf = (gcol >> 3) & 3, j = gcol & 7;
            #pragma unroll
            for (int r = 0; r < 4; r++) {
                int gm = m0 + mt * 16 + quad * 4 + r;
                float v = fmaxf(acc[mt][nt4][r] + bias[gn], 0.f);
                size_t base = (((size_t)(gm >> 4)) * 16 + k0f) * 512 + (size_t)(qf * 16 + (gm & 15)) * 8 + j;
                Af[base] = bf16_bits(v);
            }
        }
    }
}

// LDS-free 2-term split MFMA dual GEMM, A and B register double-buffered:
//   [C1 | C2] = A[M,512] @ (Bh+Bl)^T[512,256]   (A single bf16, B hi/lo split)
//   C1 = relu(+bias1) -> x5 (fp32) ; C2 -> xw2 (packed bf16, gather payload)
__global__ __launch_bounds__(256) void k_gemm2_mfma(
    const ushort* __restrict__ Af, const ushort* __restrict__ Bf,
    const float* __restrict__ bias1,
    float* __restrict__ C1, ushort* __restrict__ C2, int M) {
    const int t = threadIdx.x;
    const int lane = t & 63;
    const int wv = t >> 6;
    const int mt0 = blockIdx.x * 4;
    const int ln15 = lane & 15;
    const int quad = lane >> 4;

    f32x4 acc[4][4] = {};

    const ushort* aPtr = Af + ((size_t)mt0 * 16) * 512 + (size_t)lane * 8;
    const ushort* bPtr = Bf + ((size_t)wv * 4) * 512 + (size_t)lane * 8;
    const size_t bLo = 131072;      // 16*16*64*8

    short8 aC[4], bhC[4], blC[4];
    #pragma unroll
    for (int mt = 0; mt < 4; mt++)
        aC[mt] = *reinterpret_cast<const short8*>(aPtr + (size_t)mt * 16 * 512);
    #pragma unroll
    for (int nt = 0; nt < 4; nt++) {
        const ushort* pb = bPtr + (size_t)nt * 512;
        bhC[nt] = *reinterpret_cast<const short8*>(pb);
        blC[nt] = *reinterpret_cast<const short8*>(pb + bLo);
    }

    for (int k0i = 0; k0i < 16; k0i++) {
        short8 aN[4], bhN[4], blN[4];
        if (k0i < 15) {
            #pragma unroll
            for (int mt = 0; mt < 4; mt++)
                aN[mt] = *reinterpret_cast<const short8*>(aPtr + ((size_t)mt * 16 + k0i + 1) * 512);
            #pragma unroll
            for (int nt = 0; nt < 4; nt++) {
                const ushort* pb = bPtr + ((size_t)(k0i + 1) * 16 + nt) * 512;
                bhN[nt] = *reinterpret_cast<const short8*>(pb);
                blN[nt] = *reinterpret_cast<const short8*>(pb + bLo);
            }
        }
        #pragma unroll
        for (int mt = 0; mt < 4; mt++)
            #pragma unroll
            for (int nt = 0; nt < 4; nt++) {
                acc[mt][nt] = __builtin_amdgcn_mfma_f32_16x16x32_bf16(aC[mt], bhC[nt], acc[mt][nt], 0, 0, 0);
                acc[mt][nt] = __builtin_amdgcn_mfma_f32_16x16x32_bf16(aC[mt], blC[nt], acc[mt][nt], 0, 0, 0);
            }
        if (k0i < 15) {
            #pragma unroll
            for (int mt = 0; mt < 4; mt++) aC[mt] = aN[mt];
            #pragma unroll
            for (int nt = 0; nt < 4; nt++) { bhC[nt] = bhN[nt]; blC[nt] = blN[nt]; }
        }
    }

    #pragma unroll
    for (int mt = 0; mt < 4; mt++) {
        #pragma unroll
        for (int nt = 0; nt < 4; nt++) {
            int gn = wv * 64 + nt * 16 + ln15;   // 0..255
            #pragma unroll
            for (int r = 0; r < 4; r++) {
                int gm = mt0 * 16 + mt * 16 + quad * 4 + r;
                if (gm >= M) continue;
                float v = acc[mt][nt][r];
                if (gn < 128) {
                    C1[(size_t)gm * 128 + gn] = fmaxf(v + bias1[gn], 0.f);
                } else {
                    C2[(size_t)gm * 128 + (gn - 128)] = bf16_bits(v);
                }
            }
        }
    }
}

// per node: out[n] = x7[n]·w_fc2 + b_fc2 + b_conv3 ; xw3[n] = x7[n]·w_conv3
__global__ __launch_bounds__(256) void k_dot(const float* __restrict__ x7,
                                             const float* __restrict__ wfc2,
                                             const float* __restrict__ bfc2,
                                             const float* __restrict__ wc3,
                                             const float* __restrict__ bc3,
                                             float* __restrict__ out,
                                             float* __restrict__ xw3, int n) {
    int lane = threadIdx.x & 63;
    int wv = threadIdx.x >> 6;
    int node = blockIdx.x * 4 + wv;
    if (node >= n) return;
    const float* xr = x7 + (size_t)node * 128;
    float v0 = xr[lane], v1 = xr[64 + lane];
    float s1 = v0 * wfc2[lane] + v1 * wfc2[64 + lane];
    float s2 = v0 * wc3[lane] + v1 * wc3[64 + lane];
    #pragma unroll
    for (int o = 32; o > 0; o >>= 1) {
        s1 += __shfl_down(s1, o);
        s2 += __shfl_down(s2, o);
    }
    if (lane == 0) {
        out[node] = s1 + bfc2[0] + bc3[0];
        xw3[node] = s2;
    }
}

extern "C" void kernel_launch(void* const* d_in, const int* in_sizes, int n_in,
                              void* d_out, int out_size, void* d_ws, size_t ws_size,
                              hipStream_t stream) {
    const float* x       = (const float*)d_in[0];
    const int*   ei      = (const int*)d_in[1];
    const float* w_fc    = (const float*)d_in[2];
    const float* b_fc    = (const float*)d_in[3];
    const float* w_conv1 = (const float*)d_in[4];
    const float* b_conv1 = (const float*)d_in[5];
    const float* w_fc1   = (const float*)d_in[6];
    const float* b_fc1   = (const float*)d_in[7];
    const float* w_conv2 = (const float*)d_in[8];
    const float* b_conv2 = (const float*)d_in[9];
    const float* w_fc2   = (const float*)d_in[10];
    const float* b_fc2   = (const float*)d_in[11];
    const float* w_conv3 = (const float*)d_in[12];
    const float* b_conv3 = (const float*)d_in[13];

    const int N = in_sizes[0] / 64;       // 50000
    const int E = in_sizes[1] / 2;        // 800000
    const int* row = ei;
    const int* col = ei + E;

    const int nb = (N + 255) / 256;
    const int nblk = (N + 63) / 64;       // 782
    const int Mt = nblk * 4;              // 3128 row-tiles of 16

    // workspace layout. alloc() takes 4-BYTE units (chunks padded to 16B).
    char* p = (char*)d_ws;
    auto alloc = [&](size_t elems) {
        void* q = p; p += ((elems + 3) & ~(size_t)3) * 4; return q;
    };
    int*    degi    = (int*)   alloc(N);
    int*    excl    = (int*)   alloc(N);
    int*    bsum    = (int*)   alloc(256);
    int*    rowptr  = (int*)   alloc(N + 4);
    int*    cursor  = (int*)   alloc(N);
    int*    csr_row = (int*)   alloc(E);
    float*  csr_nrm = (float*) alloc(E);
    float*  dis     = (float*) alloc(N);
    ushort* xh      = (ushort*)alloc((size_t)N * 32);      // N*64 bf16 = N*32 words
    ushort* xl      = (ushort*)alloc((size_t)N * 32);
    ushort* agghi   = (ushort*)alloc((size_t)N * 32);
    ushort* agglo   = (ushort*)alloc((size_t)N * 32);
    ushort* x3f     = (ushort*)alloc((size_t)Mt * 4096);   // hi only: Mt*16*64*8 ushorts
    ushort* Bf      = (ushort*)alloc(131072);              // 262144 ushorts
    ushort* W0f     = (ushort*)alloc(16384);               // 32768 ushorts
    ushort* W1f     = (ushort*)alloc(16384);
    float*  x5      = (float*) alloc((size_t)N * 128);
    ushort* xw2     = (ushort*)alloc((size_t)N * 64);      // N*128 bf16 = N*64 words
    float*  xw3     = (float*) alloc(N);

    float* out = (float*)d_out;

    // ---- CSR build ----
    hipMemsetAsync(degi, 0, (size_t)N * sizeof(int), stream);
    k_count<<<(E + 255) / 256, 256, 0, stream>>>(col, degi, E);
    k_scan1<<<nb, 256, 0, stream>>>(degi, excl, bsum, N);
    k_scan2<<<1, 256, 0, stream>>>(bsum, nb);
    k_scan3<<<nb, 256, 0, stream>>>(excl, bsum, degi, rowptr, cursor, dis, N, E);
    k_scatter<<<(E + 255) / 256, 256, 0, stream>>>(row, col, dis, cursor, csr_row, csr_nrm, E);

    // input split + weight fragment packing (independent of CSR chain)
    k_prepX<<<(N * 16 + 255) / 256, 256, 0, stream>>>(x, xh, xl, N * 16);
    k_prepW64<<<8192 / 256, 256, 0, stream>>>(w_fc, w_conv1, W0f, W1f);
    k_prepB<<<32768 / 256, 256, 0, stream>>>(w_fc1, w_conv2, Bf);

    // conv1 propagate: agg = A_norm @ x (bf16 payload), output split hi/lo
    k_agg64_csr<<<(N + 3) / 4, 256, 0, stream>>>(xh, rowptr, csr_row, csr_nrm, agghi, agglo, N);

    // x1/x2 layers via MFMA -> x3f fragments (single bf16)
    k_mm64<<<dim3(nblk, 2), 256, 0, stream>>>(xh, xl, agghi, agglo, W0f, W1f,
                                              b_fc, b_conv1, x3f, N);

    // x5 = relu(x3 @ w_fc1 + b_fc1) ; xw2 = x3 @ w_conv2 (bf16 packed)
    k_gemm2_mfma<<<nblk, 256, 0, stream>>>(x3f, Bf, b_fc1, x5, xw2, N);

    // x7 = x5 + relu(A_norm @ xw2 + b_conv2)   (fused, in place in x5)
    k_agg128_x7<<<(N + 3) / 4, 256, 0, stream>>>(xw2, rowptr, csr_row, csr_nrm, b_conv2, x5, N);

    // out = x7 @ w_fc2 + b_fc2 + b_conv3 ; xw3 = x7 @ w_conv3
    k_dot<<<(N + 3) / 4, 256, 0, stream>>>(x5, w_fc2, b_fc2, w_conv3, b_conv3, out, xw3, N);

    // out += A_norm @ xw3
    k_agg1_csr<<<(N + 255) / 256, 256, 0, stream>>>(xw3, rowptr, csr_row, csr_nrm, out, N);
}

// Round 10
// 361.026 us; speedup vs baseline: 2.8271x; 1.0145x over previous
//
#include <hip/hip_runtime.h>
#include <hip/hip_bf16.h>

typedef __attribute__((ext_vector_type(8))) short short8;
typedef __attribute__((ext_vector_type(4))) float f32x4;

__device__ __forceinline__ ushort bf16_bits(float v) {
    __hip_bfloat16 h = __float2bfloat16(v);
    return *reinterpret_cast<ushort*>(&h);
}
__device__ __forceinline__ float bf16_val(float v) {
    __hip_bfloat16 h = __float2bfloat16(v);
    return __bfloat162float(h);
}
__device__ __forceinline__ float bfu_lo(uint u) {   // first (low-addr) bf16 of a pair
    uint t = u << 16; return __uint_as_float(t);
}
__device__ __forceinline__ float bfu_hi(uint u) {   // second bf16 of a pair
    uint t = u & 0xffff0000u; return __uint_as_float(t);
}
__device__ __forceinline__ float bfs(ushort h) {
    uint t = ((uint)h) << 16; return __uint_as_float(t);
}

// ---------------- CSR build ----------------

__global__ __launch_bounds__(256) void k_count(const int* __restrict__ col,
                                               int* __restrict__ degi, int E) {
    int e = blockIdx.x * 256 + threadIdx.x;
    if (e < E) atomicAdd(&degi[col[e]], 1);
}

__global__ __launch_bounds__(256) void k_scan1(const int* __restrict__ degi,
                                               int* __restrict__ excl,
                                               int* __restrict__ bsum, int n) {
    int i = blockIdx.x * 256 + threadIdx.x;
    int v = (i < n) ? degi[i] : 0;
    int lane = threadIdx.x & 63, w = threadIdx.x >> 6;
    int s = v;
    #pragma unroll
    for (int o = 1; o < 64; o <<= 1) {
        int t = __shfl_up(s, o);
        if (lane >= o) s += t;
    }
    __shared__ int wsum[4];
    if (lane == 63) wsum[w] = s;
    __syncthreads();
    int add = 0;
    for (int ww = 0; ww < w; ww++) add += wsum[ww];
    int incl = s + add;
    if (i < n) excl[i] = incl - v;
    if (threadIdx.x == 255) bsum[blockIdx.x] = incl;
}

__global__ __launch_bounds__(256) void k_scan2(int* __restrict__ bsum, int nb) {
    int i = threadIdx.x;
    int v = (i < nb) ? bsum[i] : 0;
    int lane = i & 63, w = i >> 6;
    int s = v;
    #pragma unroll
    for (int o = 1; o < 64; o <<= 1) {
        int t = __shfl_up(s, o);
        if (lane >= o) s += t;
    }
    __shared__ int wsum[4];
    if (lane == 63) wsum[w] = s;
    __syncthreads();
    int add = 0;
    for (int ww = 0; ww < w; ww++) add += wsum[ww];
    if (i < nb) bsum[i] = (s + add) - v;
}

__global__ __launch_bounds__(256) void k_scan3(const int* __restrict__ excl,
                                               const int* __restrict__ bsum,
                                               const int* __restrict__ degi,
                                               int* __restrict__ rowptr,
                                               int* __restrict__ cursor,
                                               float* __restrict__ dis,
                                               int n, int E) {
    int i = blockIdx.x * 256 + threadIdx.x;
    if (i < n) {
        int p = excl[i] + bsum[blockIdx.x];
        rowptr[i] = p;
        cursor[i] = p;
        int d = degi[i];
        dis[i] = d > 0 ? rsqrtf((float)d) : 0.f;
    }
    if (i == 0) rowptr[n] = E;
}

__global__ __launch_bounds__(256) void k_scatter(const int* __restrict__ row,
                                                 const int* __restrict__ col,
                                                 const float* __restrict__ dis,
                                                 int* __restrict__ cursor,
                                                 int* __restrict__ csr_row,
                                                 float* __restrict__ csr_nrm, int E) {
    int e = blockIdx.x * 256 + threadIdx.x;
    if (e >= E) return;
    int c = col[e], r = row[e];
    int p = atomicAdd(&cursor[c], 1);
    csr_row[p] = r;
    csr_nrm[p] = dis[r] * dis[c];
}

// ---------------- input split: x -> bf16 hi/lo ----------------

__global__ __launch_bounds__(256) void k_prepX(const float* __restrict__ x,
                                               ushort* __restrict__ xh,
                                               ushort* __restrict__ xl, int total4) {
    int i = blockIdx.x * 256 + threadIdx.x;
    if (i >= total4) return;
    float4 v = reinterpret_cast<const float4*>(x)[i];
    float vv[4] = {v.x, v.y, v.z, v.w};
    uint hv[2], lv[2];
    #pragma unroll
    for (int g = 0; g < 2; g++) {
        ushort h0 = bf16_bits(vv[g * 2]),     l0 = bf16_bits(vv[g * 2] - bf16_val(vv[g * 2]));
        ushort h1 = bf16_bits(vv[g * 2 + 1]), l1 = bf16_bits(vv[g * 2 + 1] - bf16_val(vv[g * 2 + 1]));
        hv[g] = (uint)h0 | ((uint)h1 << 16);
        lv[g] = (uint)l0 | ((uint)l1 << 16);
    }
    reinterpret_cast<uint2*>(xh)[i] = make_uint2(hv[0], hv[1]);
    reinterpret_cast<uint2*>(xl)[i] = make_uint2(lv[0], lv[1]);
}

// ---------------- CSR aggregations (gather, no atomics) ----------------

// aggx = A_norm @ x, gathering bf16 hi payload (128B/row); output split hi/lo bf16.
__global__ __launch_bounds__(256) void k_agg64_csr(const ushort* __restrict__ xh,
                                                   const int* __restrict__ rowptr,
                                                   const int* __restrict__ csr_row,
                                                   const float* __restrict__ csr_nrm,
                                                   ushort* __restrict__ agghi,
                                                   ushort* __restrict__ agglo, int n) {
    int node = blockIdx.x * 4 + (threadIdx.x >> 6);
    if (node >= n) return;
    int lane = threadIdx.x & 63;
    int s = rowptr[node], t = rowptr[node + 1];
    constexpr int U = 8;
    float acc = 0.f;
    int p = s;
    for (; p + U <= t; p += U) {
        int rr[U]; float ww[U];
        #pragma unroll
        for (int u = 0; u < U; u++) { rr[u] = csr_row[p + u]; ww[u] = csr_nrm[p + u]; }
        ushort vv[U];
        #pragma unroll
        for (int u = 0; u < U; u++) vv[u] = xh[(size_t)rr[u] * 64 + lane];
        #pragma unroll
        for (int u = 0; u < U; u++) acc += ww[u] * bfs(vv[u]);
    }
    for (; p < t; ++p)
        acc += csr_nrm[p] * bfs(xh[(size_t)csr_row[p] * 64 + lane]);
    float hf = bf16_val(acc);
    agghi[(size_t)node * 64 + lane] = bf16_bits(acc);
    agglo[(size_t)node * 64 + lane] = bf16_bits(acc - hf);
}

// Fused: x7 = x5 + relu(A_norm @ xw2 + b2)  (x7 kept in registers only), then
//   out[node] = x7·w_fc2 + b_fc2 + b_conv3 ; xw3[node] = x7·w_conv3
// One wave per node; xw2 is packed bf16 (256B/row gather); x5 read-only.
__global__ __launch_bounds__(256) void k_agg128_x7dot(
    const ushort* __restrict__ xw,
    const int* __restrict__ rowptr,
    const int* __restrict__ csr_row,
    const float* __restrict__ csr_nrm,
    const float* __restrict__ b2,
    const float* __restrict__ x5,
    const float* __restrict__ wfc2, const float* __restrict__ bfc2,
    const float* __restrict__ wc3,  const float* __restrict__ bc3,
    float* __restrict__ out, float* __restrict__ xw3, int n) {
    int node = blockIdx.x * 4 + (threadIdx.x >> 6);
    if (node >= n) return;
    int lane = threadIdx.x & 63;
    int s = rowptr[node], t = rowptr[node + 1];
    constexpr int U = 8;
    float2 acc = {0.f, 0.f};
    int p = s;
    for (; p + U <= t; p += U) {
        int rr[U]; float ww[U];
        #pragma unroll
        for (int u = 0; u < U; u++) { rr[u] = csr_row[p + u]; ww[u] = csr_nrm[p + u]; }
        uint vv[U];
        #pragma unroll
        for (int u = 0; u < U; u++)
            vv[u] = *reinterpret_cast<const uint*>(&xw[(size_t)rr[u] * 128 + lane * 2]);
        #pragma unroll
        for (int u = 0; u < U; u++) {
            acc.x += ww[u] * bfu_lo(vv[u]);
            acc.y += ww[u] * bfu_hi(vv[u]);
        }
    }
    for (; p < t; ++p) {
        uint u = *reinterpret_cast<const uint*>(&xw[(size_t)csr_row[p] * 128 + lane * 2]);
        float w = csr_nrm[p];
        acc.x += w * bfu_lo(u);
        acc.y += w * bfu_hi(u);
    }
    float2 b = *reinterpret_cast<const float2*>(&b2[lane * 2]);
    float2 cur = *reinterpret_cast<const float2*>(&x5[(size_t)node * 128 + lane * 2]);
    cur.x += fmaxf(acc.x + b.x, 0.f);          // x7, register-only
    cur.y += fmaxf(acc.y + b.y, 0.f);

    float2 w1 = *reinterpret_cast<const float2*>(&wfc2[lane * 2]);
    float2 w2 = *reinterpret_cast<const float2*>(&wc3[lane * 2]);
    float s1 = cur.x * w1.x + cur.y * w1.y;
    float s2 = cur.x * w2.x + cur.y * w2.y;
    #pragma unroll
    for (int o = 32; o > 0; o >>= 1) {
        s1 += __shfl_down(s1, o);
        s2 += __shfl_down(s2, o);
    }
    if (lane == 0) {
        out[node] = s1 + bfc2[0] + bc3[0];
        xw3[node] = s2;
    }
}

__global__ __launch_bounds__(256) void k_agg1_csr(const float* __restrict__ sv,
                                                  const int* __restrict__ rowptr,
                                                  const int* __restrict__ csr_row,
                                                  const float* __restrict__ csr_nrm,
                                                  float* __restrict__ out, int n) {
    int i = blockIdx.x * 256 + threadIdx.x;
    if (i >= n) return;
    int s = rowptr[i], t = rowptr[i + 1];
    float a = 0.f;
    #pragma unroll 4
    for (int p = s; p < t; ++p) a += csr_nrm[p] * sv[csr_row[p]];
    out[i] += a;
}

// ---------------- weight fragment packing ----------------

// K=64 layer weights [64][256] -> B-frag order:
//   Wf[arr][k0i(2)][nt(16)][lane][8], elem = W[k0i*32+(lane>>4)*8+j][nt*16+(lane&15)]
__global__ __launch_bounds__(256) void k_prepW64(const float* __restrict__ w0,
                                                 const float* __restrict__ w1,
                                                 ushort* __restrict__ W0f,
                                                 ushort* __restrict__ W1f) {
    int id = blockIdx.x * 256 + threadIdx.x;   // 2 mats * 4096
    if (id >= 8192) return;
    int mat = id >> 12;
    int rem = id & 4095;                       // arr*2048 + k0i*1024 + nt*64 + lane
    int lane = rem & 63;
    int nt = (rem >> 6) & 15;
    int k0i = (rem >> 10) & 1;
    int arr = rem >> 11;
    const float* w = mat ? w1 : w0;
    ushort* dst = mat ? W1f : W0f;
    int n = nt * 16 + (lane & 15);
    int kb = k0i * 32 + (lane >> 4) * 8;
    ushort o[8];
    #pragma unroll
    for (int j = 0; j < 8; j++) {
        float v = w[(size_t)(kb + j) * 256 + n];
        o[j] = arr ? bf16_bits(v - bf16_val(v)) : bf16_bits(v);
    }
    *reinterpret_cast<int4*>(&dst[(size_t)rem * 8]) = *reinterpret_cast<const int4*>(o);
}

// K=512 weights (w_fc1|w_conv2, [512][128] each) -> Bf[arr][k0i(16)][nt(16)][lane][8]
__global__ __launch_bounds__(256) void k_prepB(const float* __restrict__ w1,
                                               const float* __restrict__ w2,
                                               ushort* __restrict__ Bf) {
    int id = blockIdx.x * 256 + threadIdx.x;    // 2*16*16*64 = 32768
    if (id >= 32768) return;
    int lane = id & 63;
    int nt   = (id >> 6) & 15;
    int k0i  = (id >> 10) & 15;
    int arr  = id >> 14;
    int n = nt * 16 + (lane & 15);
    int kbase = k0i * 32 + (lane >> 4) * 8;
    ushort outv[8];
    #pragma unroll
    for (int j = 0; j < 8; j++) {
        int k = kbase + j;
        float v = (n < 128) ? w1[(size_t)k * 128 + n]
                            : w2[(size_t)k * 128 + (n - 128)];
        outv[j] = arr ? bf16_bits(v - bf16_val(v)) : bf16_bits(v);
    }
    *reinterpret_cast<int4*>(&Bf[(size_t)id * 8]) = *reinterpret_cast<const int4*>(outv);
}

// ---------------- MFMA GEMMs ----------------

// K=64 dual-layer MFMA GEMM (blockIdx.y = layer):
//   layer0: x3[:,0:256)  = relu((xh+xl)    @ (w_fc  h+l) + b_fc)
//   layer1: x3[:,256:512)= relu((agghi+lo) @ (w_conv1 h+l) + b_conv1)
// A in natural [node][64] bf16 layout; output written as x3f A-fragments
// in SINGLE bf16 (hi only) — the K=512 GEMM runs a 2-term split.
__global__ __launch_bounds__(256) void k_mm64(
    const ushort* __restrict__ xh, const ushort* __restrict__ xl,
    const ushort* __restrict__ ah_, const ushort* __restrict__ al_,
    const ushort* __restrict__ W0f, const ushort* __restrict__ W1f,
    const float* __restrict__ b0, const float* __restrict__ b1,
    ushort* __restrict__ Af, int M) {
    const int layer = blockIdx.y;
    const ushort* Ah = layer ? ah_ : xh;
    const ushort* Al = layer ? al_ : xl;
    const ushort* Wf = layer ? W1f : W0f;
    const float* bias = layer ? b1 : b0;
    const int colbase = layer * 256;

    const int t = threadIdx.x;
    const int lane = t & 63;
    const int wv = t >> 6;
    const int m0 = blockIdx.x * 64;
    const int ln15 = lane & 15;
    const int quad = lane >> 4;

    f32x4 acc[4][4] = {};

    #pragma unroll
    for (int k0i = 0; k0i < 2; k0i++) {
        short8 bh[4], bl[4];
        #pragma unroll
        for (int nt4 = 0; nt4 < 4; nt4++) {
            const ushort* pw = Wf + ((size_t)k0i * 16 + wv * 4 + nt4) * 512 + (size_t)lane * 8;
            bh[nt4] = *reinterpret_cast<const short8*>(pw);
            bl[nt4] = *reinterpret_cast<const short8*>(pw + 16384);   // arr=1 offset
        }
        #pragma unroll
        for (int mt = 0; mt < 4; mt++) {
            int gm = m0 + mt * 16 + ln15;
            int gmc = gm < M - 1 ? gm : M - 1;   // clamp: avoid OOB reads on tail rows
            size_t ia = (size_t)gmc * 64 + k0i * 32 + quad * 8;
            short8 ah = *reinterpret_cast<const short8*>(&Ah[ia]);
            short8 al = *reinterpret_cast<const short8*>(&Al[ia]);
            #pragma unroll
            for (int nt4 = 0; nt4 < 4; nt4++) {
                acc[mt][nt4] = __builtin_amdgcn_mfma_f32_16x16x32_bf16(ah, bh[nt4], acc[mt][nt4], 0, 0, 0);
                acc[mt][nt4] = __builtin_amdgcn_mfma_f32_16x16x32_bf16(ah, bl[nt4], acc[mt][nt4], 0, 0, 0);
                acc[mt][nt4] = __builtin_amdgcn_mfma_f32_16x16x32_bf16(al, bh[nt4], acc[mt][nt4], 0, 0, 0);
            }
        }
    }

    // epilogue: C layout col=lane&15, row=quad*4+r -> x3f fragment scatter (hi only)
    #pragma unroll
    for (int mt = 0; mt < 4; mt++) {
        #pragma unroll
        for (int nt4 = 0; nt4 < 4; nt4++) {
            int gn = wv * 64 + nt4 * 16 + ln15;      // local col 0..255
            int gcol = gn + colbase;                 // x3 col 0..511
            int k0f = gcol >> 5, qf = (gcol >> 3) & 3, j = gcol & 7;
            #pragma unroll
            for (int r = 0; r < 4; r++) {
                int gm = m0 + mt * 16 + quad * 4 + r;
                float v = fmaxf(acc[mt][nt4][r] + bias[gn], 0.f);
                size_t base = (((size_t)(gm >> 4)) * 16 + k0f) * 512 + (size_t)(qf * 16 + (gm & 15)) * 8 + j;
                Af[base] = bf16_bits(v);
            }
        }
    }
}

// LDS-free 2-term split MFMA dual GEMM, 32-row blocks for occupancy (round-9
// profile: Occupancy 12%, MfmaUtil 18% -> TLP-starved). A and B register
// double-buffered; A single bf16, B hi/lo split.
//   [C1 | C2] = A[M,512] @ (Bh+Bl)^T[512,256]
//   C1 = relu(+bias1) -> x5 (fp32) ; C2 -> xw2 (packed bf16, gather payload)
__global__ __launch_bounds__(256) void k_gemm2_mfma(
    const ushort* __restrict__ Af, const ushort* __restrict__ Bf,
    const float* __restrict__ bias1,
    float* __restrict__ C1, ushort* __restrict__ C2, int M) {
    const int t = threadIdx.x;
    const int lane = t & 63;
    const int wv = t >> 6;
    const int mt0 = blockIdx.x * 2;          // two 16-row tiles per block
    const int ln15 = lane & 15;
    const int quad = lane >> 4;

    f32x4 acc[2][4] = {};

    const ushort* aPtr = Af + ((size_t)mt0 * 16) * 512 + (size_t)lane * 8;
    const ushort* bPtr = Bf + ((size_t)wv * 4) * 512 + (size_t)lane * 8;
    const size_t bLo = 131072;      // 16*16*64*8

    short8 aC[2], bhC[4], blC[4];
    #pragma unroll
    for (int mt = 0; mt < 2; mt++)
        aC[mt] = *reinterpret_cast<const short8*>(aPtr + (size_t)mt * 16 * 512);
    #pragma unroll
    for (int nt = 0; nt < 4; nt++) {
        const ushort* pb = bPtr + (size_t)nt * 512;
        bhC[nt] = *reinterpret_cast<const short8*>(pb);
        blC[nt] = *reinterpret_cast<const short8*>(pb + bLo);
    }

    for (int k0i = 0; k0i < 16; k0i++) {
        short8 aN[2], bhN[4], blN[4];
        if (k0i < 15) {
            #pragma unroll
            for (int mt = 0; mt < 2; mt++)
                aN[mt] = *reinterpret_cast<const short8*>(aPtr + ((size_t)mt * 16 + k0i + 1) * 512);
            #pragma unroll
            for (int nt = 0; nt < 4; nt++) {
                const ushort* pb = bPtr + ((size_t)(k0i + 1) * 16 + nt) * 512;
                bhN[nt] = *reinterpret_cast<const short8*>(pb);
                blN[nt] = *reinterpret_cast<const short8*>(pb + bLo);
            }
        }
        #pragma unroll
        for (int mt = 0; mt < 2; mt++)
            #pragma unroll
            for (int nt = 0; nt < 4; nt++) {
                acc[mt][nt] = __builtin_amdgcn_mfma_f32_16x16x32_bf16(aC[mt], bhC[nt], acc[mt][nt], 0, 0, 0);
                acc[mt][nt] = __builtin_amdgcn_mfma_f32_16x16x32_bf16(aC[mt], blC[nt], acc[mt][nt], 0, 0, 0);
            }
        if (k0i < 15) {
            #pragma unroll
            for (int mt = 0; mt < 2; mt++) aC[mt] = aN[mt];
            #pragma unroll
            for (int nt = 0; nt < 4; nt++) { bhC[nt] = bhN[nt]; blC[nt] = blN[nt]; }
        }
    }

    #pragma unroll
    for (int mt = 0; mt < 2; mt++) {
        #pragma unroll
        for (int nt = 0; nt < 4; nt++) {
            int gn = wv * 64 + nt * 16 + ln15;   // 0..255
            #pragma unroll
            for (int r = 0; r < 4; r++) {
                int gm = (mt0 + mt) * 16 + quad * 4 + r;
                if (gm >= M) continue;
                float v = acc[mt][nt][r];
                if (gn < 128) {
                    C1[(size_t)gm * 128 + gn] = fmaxf(v + bias1[gn], 0.f);
                } else {
                    C2[(size_t)gm * 128 + (gn - 128)] = bf16_bits(v);
                }
            }
        }
    }
}

extern "C" void kernel_launch(void* const* d_in, const int* in_sizes, int n_in,
                              void* d_out, int out_size, void* d_ws, size_t ws_size,
                              hipStream_t stream) {
    const float* x       = (const float*)d_in[0];
    const int*   ei      = (const int*)d_in[1];
    const float* w_fc    = (const float*)d_in[2];
    const float* b_fc    = (const float*)d_in[3];
    const float* w_conv1 = (const float*)d_in[4];
    const float* b_conv1 = (const float*)d_in[5];
    const float* w_fc1   = (const float*)d_in[6];
    const float* b_fc1   = (const float*)d_in[7];
    const float* w_conv2 = (const float*)d_in[8];
    const float* b_conv2 = (const float*)d_in[9];
    const float* w_fc2   = (const float*)d_in[10];
    const float* b_fc2   = (const float*)d_in[11];
    const float* w_conv3 = (const float*)d_in[12];
    const float* b_conv3 = (const float*)d_in[13];

    const int N = in_sizes[0] / 64;       // 50000
    const int E = in_sizes[1] / 2;        // 800000
    const int* row = ei;
    const int* col = ei + E;

    const int nb = (N + 255) / 256;
    const int nblk = (N + 63) / 64;       // 782  (64-row blocks, mm64)
    const int nblk2 = (N + 31) / 32;      // 1563 (32-row blocks, gemm2)
    const int Mt = nblk * 4;              // 3128 row-tiles of 16

    // workspace layout. alloc() takes 4-BYTE units (chunks padded to 16B).
    char* p = (char*)d_ws;
    auto alloc = [&](size_t elems) {
        void* q = p; p += ((elems + 3) & ~(size_t)3) * 4; return q;
    };
    int*    degi    = (int*)   alloc(N);
    int*    excl    = (int*)   alloc(N);
    int*    bsum    = (int*)   alloc(256);
    int*    rowptr  = (int*)   alloc(N + 4);
    int*    cursor  = (int*)   alloc(N);
    int*    csr_row = (int*)   alloc(E);
    float*  csr_nrm = (float*) alloc(E);
    float*  dis     = (float*) alloc(N);
    ushort* xh      = (ushort*)alloc((size_t)N * 32);      // N*64 bf16 = N*32 words
    ushort* xl      = (ushort*)alloc((size_t)N * 32);
    ushort* agghi   = (ushort*)alloc((size_t)N * 32);
    ushort* agglo   = (ushort*)alloc((size_t)N * 32);
    ushort* x3f     = (ushort*)alloc((size_t)Mt * 4096);   // hi only: Mt*16*64*8 ushorts
    ushort* Bf      = (ushort*)alloc(131072);              // 262144 ushorts
    ushort* W0f     = (ushort*)alloc(16384);               // 32768 ushorts
    ushort* W1f     = (ushort*)alloc(16384);
    float*  x5      = (float*) alloc((size_t)N * 128);
    ushort* xw2     = (ushort*)alloc((size_t)N * 64);      // N*128 bf16 = N*64 words
    float*  xw3     = (float*) alloc(N);

    float* out = (float*)d_out;

    // ---- CSR build ----
    hipMemsetAsync(degi, 0, (size_t)N * sizeof(int), stream);
    k_count<<<(E + 255) / 256, 256, 0, stream>>>(col, degi, E);
    k_scan1<<<nb, 256, 0, stream>>>(degi, excl, bsum, N);
    k_scan2<<<1, 256, 0, stream>>>(bsum, nb);
    k_scan3<<<nb, 256, 0, stream>>>(excl, bsum, degi, rowptr, cursor, dis, N, E);
    k_scatter<<<(E + 255) / 256, 256, 0, stream>>>(row, col, dis, cursor, csr_row, csr_nrm, E);

    // input split + weight fragment packing (independent of CSR chain)
    k_prepX<<<(N * 16 + 255) / 256, 256, 0, stream>>>(x, xh, xl, N * 16);
    k_prepW64<<<8192 / 256, 256, 0, stream>>>(w_fc, w_conv1, W0f, W1f);
    k_prepB<<<32768 / 256, 256, 0, stream>>>(w_fc1, w_conv2, Bf);

    // conv1 propagate: agg = A_norm @ x (bf16 payload), output split hi/lo
    k_agg64_csr<<<(N + 3) / 4, 256, 0, stream>>>(xh, rowptr, csr_row, csr_nrm, agghi, agglo, N);

    // x1/x2 layers via MFMA -> x3f fragments (single bf16)
    k_mm64<<<dim3(nblk, 2), 256, 0, stream>>>(xh, xl, agghi, agglo, W0f, W1f,
                                              b_fc, b_conv1, x3f, N);

    // x5 = relu(x3 @ w_fc1 + b_fc1) ; xw2 = x3 @ w_conv2 (bf16 packed)
    k_gemm2_mfma<<<nblk2, 256, 0, stream>>>(x3f, Bf, b_fc1, x5, xw2, N);

    // x7 = x5 + relu(A_norm @ xw2 + b_conv2) in registers; fused dual dot ->
    // out = x7·w_fc2 + b_fc2 + b_conv3 ; xw3 = x7·w_conv3
    k_agg128_x7dot<<<(N + 3) / 4, 256, 0, stream>>>(
        xw2, rowptr, csr_row, csr_nrm, b_conv2, x5,
        w_fc2, b_fc2, w_conv3, b_conv3, out, xw3, N);

    // out += A_norm @ xw3
    k_agg1_csr<<<(N + 255) / 256, 256, 0, stream>>>(xw3, rowptr, csr_row, csr_nrm, out, N);
}

// Round 11
// 346.286 us; speedup vs baseline: 2.9475x; 1.0426x over previous
//
#include <hip/hip_runtime.h>
#include <hip/hip_bf16.h>

typedef __attribute__((ext_vector_type(8))) short short8;
typedef __attribute__((ext_vector_type(4))) float f32x4;

__device__ __forceinline__ ushort bf16_bits(float v) {
    __hip_bfloat16 h = __float2bfloat16(v);
    return *reinterpret_cast<ushort*>(&h);
}
__device__ __forceinline__ float bf16_val(float v) {
    __hip_bfloat16 h = __float2bfloat16(v);
    return __bfloat162float(h);
}
__device__ __forceinline__ float bfu_lo(uint u) {   // first (low-addr) bf16 of a pair
    uint t = u << 16; return __uint_as_float(t);
}
__device__ __forceinline__ float bfu_hi(uint u) {   // second bf16 of a pair
    uint t = u & 0xffff0000u; return __uint_as_float(t);
}

// ---------------- CSR build ----------------

__global__ __launch_bounds__(256) void k_count(const int* __restrict__ col,
                                               int* __restrict__ degi, int E) {
    int e = blockIdx.x * 256 + threadIdx.x;
    if (e < E) atomicAdd(&degi[col[e]], 1);
}

__global__ __launch_bounds__(256) void k_scan1(const int* __restrict__ degi,
                                               int* __restrict__ excl,
                                               int* __restrict__ bsum, int n) {
    int i = blockIdx.x * 256 + threadIdx.x;
    int v = (i < n) ? degi[i] : 0;
    int lane = threadIdx.x & 63, w = threadIdx.x >> 6;
    int s = v;
    #pragma unroll
    for (int o = 1; o < 64; o <<= 1) {
        int t = __shfl_up(s, o);
        if (lane >= o) s += t;
    }
    __shared__ int wsum[4];
    if (lane == 63) wsum[w] = s;
    __syncthreads();
    int add = 0;
    for (int ww = 0; ww < w; ww++) add += wsum[ww];
    int incl = s + add;
    if (i < n) excl[i] = incl - v;
    if (threadIdx.x == 255) bsum[blockIdx.x] = incl;
}

__global__ __launch_bounds__(256) void k_scan2(int* __restrict__ bsum, int nb) {
    int i = threadIdx.x;
    int v = (i < nb) ? bsum[i] : 0;
    int lane = i & 63, w = i >> 6;
    int s = v;
    #pragma unroll
    for (int o = 1; o < 64; o <<= 1) {
        int t = __shfl_up(s, o);
        if (lane >= o) s += t;
    }
    __shared__ int wsum[4];
    if (lane == 63) wsum[w] = s;
    __syncthreads();
    int add = 0;
    for (int ww = 0; ww < w; ww++) add += wsum[ww];
    if (i < nb) bsum[i] = (s + add) - v;
}

__global__ __launch_bounds__(256) void k_scan3(const int* __restrict__ excl,
                                               const int* __restrict__ bsum,
                                               const int* __restrict__ degi,
                                               int* __restrict__ rowptr,
                                               int* __restrict__ cursor,
                                               float* __restrict__ dis,
                                               int n, int E) {
    int i = blockIdx.x * 256 + threadIdx.x;
    if (i < n) {
        int p = excl[i] + bsum[blockIdx.x];
        rowptr[i] = p;
        cursor[i] = p;
        int d = degi[i];
        dis[i] = d > 0 ? rsqrtf((float)d) : 0.f;
    }
    if (i == 0) rowptr[n] = E;
}

// CSR slot scatter, packed: one 8B store per edge (round-10 profile showed
// two 4B scattered stores -> 83MB HBM write amp; one int2 halves sector touches)
__global__ __launch_bounds__(256) void k_scatter(const int* __restrict__ row,
                                                 const int* __restrict__ col,
                                                 const float* __restrict__ dis,
                                                 int* __restrict__ cursor,
                                                 int2* __restrict__ csr, int E) {
    int e = blockIdx.x * 256 + threadIdx.x;
    if (e >= E) return;
    int c = col[e], r = row[e];
    int p = atomicAdd(&cursor[c], 1);
    csr[p] = make_int2(r, __float_as_int(dis[r] * dis[c]));
}

// ---------------- input split: x -> bf16 hi/lo ----------------

__global__ __launch_bounds__(256) void k_prepX(const float* __restrict__ x,
                                               ushort* __restrict__ xh,
                                               ushort* __restrict__ xl, int total4) {
    int i = blockIdx.x * 256 + threadIdx.x;
    if (i >= total4) return;
    float4 v = reinterpret_cast<const float4*>(x)[i];
    float vv[4] = {v.x, v.y, v.z, v.w};
    uint hv[2], lv[2];
    #pragma unroll
    for (int g = 0; g < 2; g++) {
        ushort h0 = bf16_bits(vv[g * 2]),     l0 = bf16_bits(vv[g * 2] - bf16_val(vv[g * 2]));
        ushort h1 = bf16_bits(vv[g * 2 + 1]), l1 = bf16_bits(vv[g * 2 + 1] - bf16_val(vv[g * 2 + 1]));
        hv[g] = (uint)h0 | ((uint)h1 << 16);
        lv[g] = (uint)l0 | ((uint)l1 << 16);
    }
    reinterpret_cast<uint2*>(xh)[i] = make_uint2(hv[0], hv[1]);
    reinterpret_cast<uint2*>(xl)[i] = make_uint2(lv[0], lv[1]);
}

// ---------------- CSR aggregations (gather, no atomics) ----------------

// aggx = A_norm @ x: TWO nodes per wave (half-wave each, uint = 2 bf16/lane)
// -> 256B gathered per memory instruction instead of 128B.
__global__ __launch_bounds__(256) void k_agg64_csr(const ushort* __restrict__ xh,
                                                   const int* __restrict__ rowptr,
                                                   const int2* __restrict__ csr,
                                                   ushort* __restrict__ agghi,
                                                   ushort* __restrict__ agglo, int n) {
    int node = blockIdx.x * 8 + (threadIdx.x >> 5);
    if (node >= n) return;
    int lane = threadIdx.x & 31;           // half-wave lane: 2 dims per lane
    int s = rowptr[node], t = rowptr[node + 1];
    constexpr int U = 8;
    float2 acc = {0.f, 0.f};
    int p = s;
    for (; p + U <= t; p += U) {
        int rr[U]; float ww[U];
        #pragma unroll
        for (int u = 0; u < U; u++) {
            int2 q = csr[p + u];
            rr[u] = q.x; ww[u] = __int_as_float(q.y);
        }
        uint vv[U];
        #pragma unroll
        for (int u = 0; u < U; u++)
            vv[u] = *reinterpret_cast<const uint*>(&xh[(size_t)rr[u] * 64 + lane * 2]);
        #pragma unroll
        for (int u = 0; u < U; u++) {
            acc.x += ww[u] * bfu_lo(vv[u]);
            acc.y += ww[u] * bfu_hi(vv[u]);
        }
    }
    for (; p < t; ++p) {
        int2 q = csr[p];
        float w = __int_as_float(q.y);
        uint u = *reinterpret_cast<const uint*>(&xh[(size_t)q.x * 64 + lane * 2]);
        acc.x += w * bfu_lo(u);
        acc.y += w * bfu_hi(u);
    }
    float hx = bf16_val(acc.x), hy = bf16_val(acc.y);
    uint hpack = (uint)bf16_bits(acc.x) | ((uint)bf16_bits(acc.y) << 16);
    uint lpack = (uint)bf16_bits(acc.x - hx) | ((uint)bf16_bits(acc.y - hy) << 16);
    *reinterpret_cast<uint*>(&agghi[(size_t)node * 64 + lane * 2]) = hpack;
    *reinterpret_cast<uint*>(&agglo[(size_t)node * 64 + lane * 2]) = lpack;
}

// Fused: x7 = x5 + relu(A_norm @ xw2 + b2)  (x7 kept in registers only), then
//   out[node] = x7·w_fc2 + b_fc2 + b_conv3 ; xw3[node] = x7·w_conv3
// One wave per node; xw2 is packed bf16 (256B/row gather); x5 read-only.
__global__ __launch_bounds__(256) void k_agg128_x7dot(
    const ushort* __restrict__ xw,
    const int* __restrict__ rowptr,
    const int2* __restrict__ csr,
    const float* __restrict__ b2,
    const float* __restrict__ x5,
    const float* __restrict__ wfc2, const float* __restrict__ bfc2,
    const float* __restrict__ wc3,  const float* __restrict__ bc3,
    float* __restrict__ out, float* __restrict__ xw3, int n) {
    int node = blockIdx.x * 4 + (threadIdx.x >> 6);
    if (node >= n) return;
    int lane = threadIdx.x & 63;
    int s = rowptr[node], t = rowptr[node + 1];
    constexpr int U = 8;
    float2 acc = {0.f, 0.f};
    int p = s;
    for (; p + U <= t; p += U) {
        int rr[U]; float ww[U];
        #pragma unroll
        for (int u = 0; u < U; u++) {
            int2 q = csr[p + u];
            rr[u] = q.x; ww[u] = __int_as_float(q.y);
        }
        uint vv[U];
        #pragma unroll
        for (int u = 0; u < U; u++)
            vv[u] = *reinterpret_cast<const uint*>(&xw[(size_t)rr[u] * 128 + lane * 2]);
        #pragma unroll
        for (int u = 0; u < U; u++) {
            acc.x += ww[u] * bfu_lo(vv[u]);
            acc.y += ww[u] * bfu_hi(vv[u]);
        }
    }
    for (; p < t; ++p) {
        int2 q = csr[p];
        float w = __int_as_float(q.y);
        uint u = *reinterpret_cast<const uint*>(&xw[(size_t)q.x * 128 + lane * 2]);
        acc.x += w * bfu_lo(u);
        acc.y += w * bfu_hi(u);
    }
    float2 b = *reinterpret_cast<const float2*>(&b2[lane * 2]);
    float2 cur = *reinterpret_cast<const float2*>(&x5[(size_t)node * 128 + lane * 2]);
    cur.x += fmaxf(acc.x + b.x, 0.f);          // x7, register-only
    cur.y += fmaxf(acc.y + b.y, 0.f);

    float2 w1 = *reinterpret_cast<const float2*>(&wfc2[lane * 2]);
    float2 w2 = *reinterpret_cast<const float2*>(&wc3[lane * 2]);
    float s1 = cur.x * w1.x + cur.y * w1.y;
    float s2 = cur.x * w2.x + cur.y * w2.y;
    #pragma unroll
    for (int o = 32; o > 0; o >>= 1) {
        s1 += __shfl_down(s1, o);
        s2 += __shfl_down(s2, o);
    }
    if (lane == 0) {
        out[node] = s1 + bfc2[0] + bc3[0];
        xw3[node] = s2;
    }
}

__global__ __launch_bounds__(256) void k_agg1_csr(const float* __restrict__ sv,
                                                  const int* __restrict__ rowptr,
                                                  const int2* __restrict__ csr,
                                                  float* __restrict__ out, int n) {
    int i = blockIdx.x * 256 + threadIdx.x;
    if (i >= n) return;
    int s = rowptr[i], t = rowptr[i + 1];
    float a = 0.f;
    #pragma unroll 4
    for (int p = s; p < t; ++p) {
        int2 q = csr[p];
        a += __int_as_float(q.y) * sv[q.x];
    }
    out[i] += a;
}

// ---------------- weight fragment packing ----------------

// K=64 layer weights [64][256] -> B-frag order:
//   Wf[arr][k0i(2)][nt(16)][lane][8], elem = W[k0i*32+(lane>>4)*8+j][nt*16+(lane&15)]
__global__ __launch_bounds__(256) void k_prepW64(const float* __restrict__ w0,
                                                 const float* __restrict__ w1,
                                                 ushort* __restrict__ W0f,
                                                 ushort* __restrict__ W1f) {
    int id = blockIdx.x * 256 + threadIdx.x;   // 2 mats * 4096
    if (id >= 8192) return;
    int mat = id >> 12;
    int rem = id & 4095;                       // arr*2048 + k0i*1024 + nt*64 + lane
    int lane = rem & 63;
    int nt = (rem >> 6) & 15;
    int k0i = (rem >> 10) & 1;
    int arr = rem >> 11;
    const float* w = mat ? w1 : w0;
    ushort* dst = mat ? W1f : W0f;
    int n = nt * 16 + (lane & 15);
    int kb = k0i * 32 + (lane >> 4) * 8;
    ushort o[8];
    #pragma unroll
    for (int j = 0; j < 8; j++) {
        float v = w[(size_t)(kb + j) * 256 + n];
        o[j] = arr ? bf16_bits(v - bf16_val(v)) : bf16_bits(v);
    }
    *reinterpret_cast<int4*>(&dst[(size_t)rem * 8]) = *reinterpret_cast<const int4*>(o);
}

// K=512 weights (w_fc1|w_conv2, [512][128] each) -> Bf[arr][k0i(16)][nt(16)][lane][8]
__global__ __launch_bounds__(256) void k_prepB(const float* __restrict__ w1,
                                               const float* __restrict__ w2,
                                               ushort* __restrict__ Bf) {
    int id = blockIdx.x * 256 + threadIdx.x;    // 2*16*16*64 = 32768
    if (id >= 32768) return;
    int lane = id & 63;
    int nt   = (id >> 6) & 15;
    int k0i  = (id >> 10) & 15;
    int arr  = id >> 14;
    int n = nt * 16 + (lane & 15);
    int kbase = k0i * 32 + (lane >> 4) * 8;
    ushort outv[8];
    #pragma unroll
    for (int j = 0; j < 8; j++) {
        int k = kbase + j;
        float v = (n < 128) ? w1[(size_t)k * 128 + n]
                            : w2[(size_t)k * 128 + (n - 128)];
        outv[j] = arr ? bf16_bits(v - bf16_val(v)) : bf16_bits(v);
    }
    *reinterpret_cast<int4*>(&Bf[(size_t)id * 8]) = *reinterpret_cast<const int4*>(outv);
}

// ---------------- MFMA GEMMs ----------------

// K=64 dual-layer MFMA GEMM (blockIdx.y = layer):
//   layer0: x3[:,0:256)  = relu((xh+xl)    @ (w_fc  h+l) + b_fc)
//   layer1: x3[:,256:512)= relu((agghi+lo) @ (w_conv1 h+l) + b_conv1)
// A in natural [node][64] bf16 layout; output written as x3f A-fragments
// in SINGLE bf16 (hi only) — the K=512 GEMM runs a 2-term split.
__global__ __launch_bounds__(256) void k_mm64(
    const ushort* __restrict__ xh, const ushort* __restrict__ xl,
    const ushort* __restrict__ ah_, const ushort* __restrict__ al_,
    const ushort* __restrict__ W0f, const ushort* __restrict__ W1f,
    const float* __restrict__ b0, const float* __restrict__ b1,
    ushort* __restrict__ Af, int M) {
    const int layer = blockIdx.y;
    const ushort* Ah = layer ? ah_ : xh;
    const ushort* Al = layer ? al_ : xl;
    const ushort* Wf = layer ? W1f : W0f;
    const float* bias = layer ? b1 : b0;
    const int colbase = layer * 256;

    const int t = threadIdx.x;
    const int lane = t & 63;
    const int wv = t >> 6;
    const int m0 = blockIdx.x * 64;
    const int ln15 = lane & 15;
    const int quad = lane >> 4;

    f32x4 acc[4][4] = {};

    #pragma unroll
    for (int k0i = 0; k0i < 2; k0i++) {
        short8 bh[4], bl[4];
        #pragma unroll
        for (int nt4 = 0; nt4 < 4; nt4++) {
            const ushort* pw = Wf + ((size_t)k0i * 16 + wv * 4 + nt4) * 512 + (size_t)lane * 8;
            bh[nt4] = *reinterpret_cast<const short8*>(pw);
            bl[nt4] = *reinterpret_cast<const short8*>(pw + 16384);   // arr=1 offset
        }
        #pragma unroll
        for (int mt = 0; mt < 4; mt++) {
            int gm = m0 + mt * 16 + ln15;
            int gmc = gm < M - 1 ? gm : M - 1;   // clamp: avoid OOB reads on tail rows
            size_t ia = (size_t)gmc * 64 + k0i * 32 + quad * 8;
            short8 ah = *reinterpret_cast<const short8*>(&Ah[ia]);
            short8 al = *reinterpret_cast<const short8*>(&Al[ia]);
            #pragma unroll
            for (int nt4 = 0; nt4 < 4; nt4++) {
                acc[mt][nt4] = __builtin_amdgcn_mfma_f32_16x16x32_bf16(ah, bh[nt4], acc[mt][nt4], 0, 0, 0);
                acc[mt][nt4] = __builtin_amdgcn_mfma_f32_16x16x32_bf16(ah, bl[nt4], acc[mt][nt4], 0, 0, 0);
                acc[mt][nt4] = __builtin_amdgcn_mfma_f32_16x16x32_bf16(al, bh[nt4], acc[mt][nt4], 0, 0, 0);
            }
        }
    }

    // epilogue: C layout col=lane&15, row=quad*4+r -> x3f fragment scatter (hi only)
    #pragma unroll
    for (int mt = 0; mt < 4; mt++) {
        #pragma unroll
        for (int nt4 = 0; nt4 < 4; nt4++) {
            int gn = wv * 64 + nt4 * 16 + ln15;      // local col 0..255
            int gcol = gn + colbase;                 // x3 col 0..511
            int k0f = gcol >> 5, qf = (gcol >> 3) & 3, j = gcol & 7;
            #pragma unroll
            for (int r = 0; r < 4; r++) {
                int gm = m0 + mt * 16 + quad * 4 + r;
                float v = fmaxf(acc[mt][nt4][r] + bias[gn], 0.f);
                size_t base = (((size_t)(gm >> 4)) * 16 + k0f) * 512 + (size_t)(qf * 16 + (gm & 15)) * 8 + j;
                Af[base] = bf16_bits(v);
            }
        }
    }
}

// LDS-free 2-term split MFMA dual GEMM, 32-row blocks for occupancy.
// A and B register double-buffered; A single bf16, B hi/lo split.
//   [C1 | C2] = A[M,512] @ (Bh+Bl)^T[512,256]
//   C1 = relu(+bias1) -> x5 (fp32) ; C2 -> xw2 (packed bf16, gather payload)
__global__ __launch_bounds__(256) void k_gemm2_mfma(
    const ushort* __restrict__ Af, const ushort* __restrict__ Bf,
    const float* __restrict__ bias1,
    float* __restrict__ C1, ushort* __restrict__ C2, int M) {
    const int t = threadIdx.x;
    const int lane = t & 63;
    const int wv = t >> 6;
    const int mt0 = blockIdx.x * 2;          // two 16-row tiles per block
    const int ln15 = lane & 15;
    const int quad = lane >> 4;

    f32x4 acc[2][4] = {};

    const ushort* aPtr = Af + ((size_t)mt0 * 16) * 512 + (size_t)lane * 8;
    const ushort* bPtr = Bf + ((size_t)wv * 4) * 512 + (size_t)lane * 8;
    const size_t bLo = 131072;      // 16*16*64*8

    short8 aC[2], bhC[4], blC[4];
    #pragma unroll
    for (int mt = 0; mt < 2; mt++)
        aC[mt] = *reinterpret_cast<const short8*>(aPtr + (size_t)mt * 16 * 512);
    #pragma unroll
    for (int nt = 0; nt < 4; nt++) {
        const ushort* pb = bPtr + (size_t)nt * 512;
        bhC[nt] = *reinterpret_cast<const short8*>(pb);
        blC[nt] = *reinterpret_cast<const short8*>(pb + bLo);
    }

    for (int k0i = 0; k0i < 16; k0i++) {
        short8 aN[2], bhN[4], blN[4];
        if (k0i < 15) {
            #pragma unroll
            for (int mt = 0; mt < 2; mt++)
                aN[mt] = *reinterpret_cast<const short8*>(aPtr + ((size_t)mt * 16 + k0i + 1) * 512);
            #pragma unroll
            for (int nt = 0; nt < 4; nt++) {
                const ushort* pb = bPtr + ((size_t)(k0i + 1) * 16 + nt) * 512;
                bhN[nt] = *reinterpret_cast<const short8*>(pb);
                blN[nt] = *reinterpret_cast<const short8*>(pb + bLo);
            }
        }
        #pragma unroll
        for (int mt = 0; mt < 2; mt++)
            #pragma unroll
            for (int nt = 0; nt < 4; nt++) {
                acc[mt][nt] = __builtin_amdgcn_mfma_f32_16x16x32_bf16(aC[mt], bhC[nt], acc[mt][nt], 0, 0, 0);
                acc[mt][nt] = __builtin_amdgcn_mfma_f32_16x16x32_bf16(aC[mt], blC[nt], acc[mt][nt], 0, 0, 0);
            }
        if (k0i < 15) {
            #pragma unroll
            for (int mt = 0; mt < 2; mt++) aC[mt] = aN[mt];
            #pragma unroll
            for (int nt = 0; nt < 4; nt++) { bhC[nt] = bhN[nt]; blC[nt] = blN[nt]; }
        }
    }

    #pragma unroll
    for (int mt = 0; mt < 2; mt++) {
        #pragma unroll
        for (int nt = 0; nt < 4; nt++) {
            int gn = wv * 64 + nt * 16 + ln15;   // 0..255
            #pragma unroll
            for (int r = 0; r < 4; r++) {
                int gm = (mt0 + mt) * 16 + quad * 4 + r;
                if (gm >= M) continue;
                float v = acc[mt][nt][r];
                if (gn < 128) {
                    C1[(size_t)gm * 128 + gn] = fmaxf(v + bias1[gn], 0.f);
                } else {
                    C2[(size_t)gm * 128 + (gn - 128)] = bf16_bits(v);
                }
            }
        }
    }
}

extern "C" void kernel_launch(void* const* d_in, const int* in_sizes, int n_in,
                              void* d_out, int out_size, void* d_ws, size_t ws_size,
                              hipStream_t stream) {
    const float* x       = (const float*)d_in[0];
    const int*   ei      = (const int*)d_in[1];
    const float* w_fc    = (const float*)d_in[2];
    const float* b_fc    = (const float*)d_in[3];
    const float* w_conv1 = (const float*)d_in[4];
    const float* b_conv1 = (const float*)d_in[5];
    const float* w_fc1   = (const float*)d_in[6];
    const float* b_fc1   = (const float*)d_in[7];
    const float* w_conv2 = (const float*)d_in[8];
    const float* b_conv2 = (const float*)d_in[9];
    const float* w_fc2   = (const float*)d_in[10];
    const float* b_fc2   = (const float*)d_in[11];
    const float* w_conv3 = (const float*)d_in[12];
    const float* b_conv3 = (const float*)d_in[13];

    const int N = in_sizes[0] / 64;       // 50000
    const int E = in_sizes[1] / 2;        // 800000
    const int* row = ei;
    const int* col = ei + E;

    const int nb = (N + 255) / 256;
    const int nblk = (N + 63) / 64;       // 782  (64-row blocks, mm64)
    const int nblk2 = (N + 31) / 32;      // 1563 (32-row blocks, gemm2)
    const int Mt = nblk * 4;              // 3128 row-tiles of 16

    // workspace layout. alloc() takes 4-BYTE units (chunks padded to 16B).
    char* p = (char*)d_ws;
    auto alloc = [&](size_t elems) {
        void* q = p; p += ((elems + 3) & ~(size_t)3) * 4; return q;
    };
    int*    degi    = (int*)   alloc(N);
    int*    excl    = (int*)   alloc(N);
    int*    bsum    = (int*)   alloc(256);
    int*    rowptr  = (int*)   alloc(N + 4);
    int*    cursor  = (int*)   alloc(N);
    int2*   csr     = (int2*)  alloc((size_t)E * 2);       // packed {row, nrm}
    float*  dis     = (float*) alloc(N);
    ushort* xh      = (ushort*)alloc((size_t)N * 32);      // N*64 bf16 = N*32 words
    ushort* xl      = (ushort*)alloc((size_t)N * 32);
    ushort* agghi   = (ushort*)alloc((size_t)N * 32);
    ushort* agglo   = (ushort*)alloc((size_t)N * 32);
    ushort* x3f     = (ushort*)alloc((size_t)Mt * 4096);   // hi only: Mt*16*64*8 ushorts
    ushort* Bf      = (ushort*)alloc(131072);              // 262144 ushorts
    ushort* W0f     = (ushort*)alloc(16384);               // 32768 ushorts
    ushort* W1f     = (ushort*)alloc(16384);
    float*  x5      = (float*) alloc((size_t)N * 128);
    ushort* xw2     = (ushort*)alloc((size_t)N * 64);      // N*128 bf16 = N*64 words
    float*  xw3     = (float*) alloc(N);

    float* out = (float*)d_out;

    // ---- CSR build ----
    hipMemsetAsync(degi, 0, (size_t)N * sizeof(int), stream);
    k_count<<<(E + 255) / 256, 256, 0, stream>>>(col, degi, E);
    k_scan1<<<nb, 256, 0, stream>>>(degi, excl, bsum, N);
    k_scan2<<<1, 256, 0, stream>>>(bsum, nb);
    k_scan3<<<nb, 256, 0, stream>>>(excl, bsum, degi, rowptr, cursor, dis, N, E);
    k_scatter<<<(E + 255) / 256, 256, 0, stream>>>(row, col, dis, cursor, csr, E);

    // input split + weight fragment packing (independent of CSR chain)
    k_prepX<<<(N * 16 + 255) / 256, 256, 0, stream>>>(x, xh, xl, N * 16);
    k_prepW64<<<8192 / 256, 256, 0, stream>>>(w_fc, w_conv1, W0f, W1f);
    k_prepB<<<32768 / 256, 256, 0, stream>>>(w_fc1, w_conv2, Bf);

    // conv1 propagate: agg = A_norm @ x (bf16 payload), 2 nodes/wave
    k_agg64_csr<<<(N + 7) / 8, 256, 0, stream>>>(xh, rowptr, csr, agghi, agglo, N);

    // x1/x2 layers via MFMA -> x3f fragments (single bf16)
    k_mm64<<<dim3(nblk, 2), 256, 0, stream>>>(xh, xl, agghi, agglo, W0f, W1f,
                                              b_fc, b_conv1, x3f, N);

    // x5 = relu(x3 @ w_fc1 + b_fc1) ; xw2 = x3 @ w_conv2 (bf16 packed)
    k_gemm2_mfma<<<nblk2, 256, 0, stream>>>(x3f, Bf, b_fc1, x5, xw2, N);

    // x7 = x5 + relu(A_norm @ xw2 + b_conv2) in registers; fused dual dot ->
    // out = x7·w_fc2 + b_fc2 + b_conv3 ; xw3 = x7·w_conv3
    k_agg128_x7dot<<<(N + 3) / 4, 256, 0, stream>>>(
        xw2, rowptr, csr, b_conv2, x5,
        w_fc2, b_fc2, w_conv3, b_conv3, out, xw3, N);

    // out += A_norm @ xw3
    k_agg1_csr<<<(N + 255) / 256, 256, 0, stream>>>(xw3, rowptr, csr, out, N);
}

// Round 12
// 328.378 us; speedup vs baseline: 3.1082x; 1.0545x over previous
//
#include <hip/hip_runtime.h>
#include <hip/hip_bf16.h>

typedef __attribute__((ext_vector_type(8))) short short8;
typedef __attribute__((ext_vector_type(4))) float f32x4;

__device__ __forceinline__ ushort bf16_bits(float v) {
    __hip_bfloat16 h = __float2bfloat16(v);
    return *reinterpret_cast<ushort*>(&h);
}
__device__ __forceinline__ float bf16_val(float v) {
    __hip_bfloat16 h = __float2bfloat16(v);
    return __bfloat162float(h);
}
__device__ __forceinline__ float bfu_lo(uint u) {   // first (low-addr) bf16 of a pair
    uint t = u << 16; return __uint_as_float(t);
}
__device__ __forceinline__ float bfu_hi(uint u) {   // second bf16 of a pair
    uint t = u & 0xffff0000u; return __uint_as_float(t);
}

// ---------------- CSR build ----------------

__global__ __launch_bounds__(256) void k_count(const int* __restrict__ col,
                                               int* __restrict__ degi, int E) {
    int e = blockIdx.x * 256 + threadIdx.x;
    if (e < E) atomicAdd(&degi[col[e]], 1);
}

__global__ __launch_bounds__(256) void k_scan1(const int* __restrict__ degi,
                                               int* __restrict__ excl,
                                               int* __restrict__ bsum, int n) {
    int i = blockIdx.x * 256 + threadIdx.x;
    int v = (i < n) ? degi[i] : 0;
    int lane = threadIdx.x & 63, w = threadIdx.x >> 6;
    int s = v;
    #pragma unroll
    for (int o = 1; o < 64; o <<= 1) {
        int t = __shfl_up(s, o);
        if (lane >= o) s += t;
    }
    __shared__ int wsum[4];
    if (lane == 63) wsum[w] = s;
    __syncthreads();
    int add = 0;
    for (int ww = 0; ww < w; ww++) add += wsum[ww];
    int incl = s + add;
    if (i < n) excl[i] = incl - v;
    if (threadIdx.x == 255) bsum[blockIdx.x] = incl;
}

__global__ __launch_bounds__(256) void k_scan2(int* __restrict__ bsum, int nb) {
    int i = threadIdx.x;
    int v = (i < nb) ? bsum[i] : 0;
    int lane = i & 63, w = i >> 6;
    int s = v;
    #pragma unroll
    for (int o = 1; o < 64; o <<= 1) {
        int t = __shfl_up(s, o);
        if (lane >= o) s += t;
    }
    __shared__ int wsum[4];
    if (lane == 63) wsum[w] = s;
    __syncthreads();
    int add = 0;
    for (int ww = 0; ww < w; ww++) add += wsum[ww];
    if (i < nb) bsum[i] = (s + add) - v;
}

__global__ __launch_bounds__(256) void k_scan3(const int* __restrict__ excl,
                                               const int* __restrict__ bsum,
                                               const int* __restrict__ degi,
                                               int* __restrict__ rowptr,
                                               int* __restrict__ cursor,
                                               float* __restrict__ dis,
                                               int n, int E) {
    int i = blockIdx.x * 256 + threadIdx.x;
    if (i < n) {
        int p = excl[i] + bsum[blockIdx.x];
        rowptr[i] = p;
        cursor[i] = p;
        int d = degi[i];
        dis[i] = d > 0 ? rsqrtf((float)d) : 0.f;
    }
    if (i == 0) rowptr[n] = E;
}

// CSR slot scatter, packed: one 8B store per edge.
__global__ __launch_bounds__(256) void k_scatter(const int* __restrict__ row,
                                                 const int* __restrict__ col,
                                                 const float* __restrict__ dis,
                                                 int* __restrict__ cursor,
                                                 int2* __restrict__ csr, int E) {
    int e = blockIdx.x * 256 + threadIdx.x;
    if (e >= E) return;
    int c = col[e], r = row[e];
    int p = atomicAdd(&cursor[c], 1);
    csr[p] = make_int2(r, __float_as_int(dis[r] * dis[c]));
}

// ---------------- input split: x -> bf16 hi/lo ----------------

__global__ __launch_bounds__(256) void k_prepX(const float* __restrict__ x,
                                               ushort* __restrict__ xh,
                                               ushort* __restrict__ xl, int total4) {
    int i = blockIdx.x * 256 + threadIdx.x;
    if (i >= total4) return;
    float4 v = reinterpret_cast<const float4*>(x)[i];
    float vv[4] = {v.x, v.y, v.z, v.w};
    uint hv[2], lv[2];
    #pragma unroll
    for (int g = 0; g < 2; g++) {
        ushort h0 = bf16_bits(vv[g * 2]),     l0 = bf16_bits(vv[g * 2] - bf16_val(vv[g * 2]));
        ushort h1 = bf16_bits(vv[g * 2 + 1]), l1 = bf16_bits(vv[g * 2 + 1] - bf16_val(vv[g * 2 + 1]));
        hv[g] = (uint)h0 | ((uint)h1 << 16);
        lv[g] = (uint)l0 | ((uint)l1 << 16);
    }
    reinterpret_cast<uint2*>(xh)[i] = make_uint2(hv[0], hv[1]);
    reinterpret_cast<uint2*>(xl)[i] = make_uint2(lv[0], lv[1]);
}

// ---------------- CSR aggregations (gather, no atomics) ----------------

// aggx = A_norm @ x: TWO nodes per wave (half-wave each, uint = 2 bf16/lane).
__global__ __launch_bounds__(256) void k_agg64_csr(const ushort* __restrict__ xh,
                                                   const int* __restrict__ rowptr,
                                                   const int2* __restrict__ csr,
                                                   ushort* __restrict__ agghi,
                                                   ushort* __restrict__ agglo, int n) {
    int node = blockIdx.x * 8 + (threadIdx.x >> 5);
    if (node >= n) return;
    int lane = threadIdx.x & 31;           // half-wave lane: 2 dims per lane
    int s = rowptr[node], t = rowptr[node + 1];
    constexpr int U = 8;
    float2 acc = {0.f, 0.f};
    int p = s;
    for (; p + U <= t; p += U) {
        int rr[U]; float ww[U];
        #pragma unroll
        for (int u = 0; u < U; u++) {
            int2 q = csr[p + u];
            rr[u] = q.x; ww[u] = __int_as_float(q.y);
        }
        uint vv[U];
        #pragma unroll
        for (int u = 0; u < U; u++)
            vv[u] = *reinterpret_cast<const uint*>(&xh[(size_t)rr[u] * 64 + lane * 2]);
        #pragma unroll
        for (int u = 0; u < U; u++) {
            acc.x += ww[u] * bfu_lo(vv[u]);
            acc.y += ww[u] * bfu_hi(vv[u]);
        }
    }
    for (; p < t; ++p) {
        int2 q = csr[p];
        float w = __int_as_float(q.y);
        uint u = *reinterpret_cast<const uint*>(&xh[(size_t)q.x * 64 + lane * 2]);
        acc.x += w * bfu_lo(u);
        acc.y += w * bfu_hi(u);
    }
    float hx = bf16_val(acc.x), hy = bf16_val(acc.y);
    uint hpack = (uint)bf16_bits(acc.x) | ((uint)bf16_bits(acc.y) << 16);
    uint lpack = (uint)bf16_bits(acc.x - hx) | ((uint)bf16_bits(acc.y - hy) << 16);
    *reinterpret_cast<uint*>(&agghi[(size_t)node * 64 + lane * 2]) = hpack;
    *reinterpret_cast<uint*>(&agglo[(size_t)node * 64 + lane * 2]) = lpack;
}

// Fused: x7 = x5 + relu(A_norm @ xw2 + b2)  (x7 register-only), then
//   out[node] = x7·w_fc2 + b_fc2 + b_conv3 ; xw3[node] = x7·w_conv3
__global__ __launch_bounds__(256) void k_agg128_x7dot(
    const ushort* __restrict__ xw,
    const int* __restrict__ rowptr,
    const int2* __restrict__ csr,
    const float* __restrict__ b2,
    const float* __restrict__ x5,
    const float* __restrict__ wfc2, const float* __restrict__ bfc2,
    const float* __restrict__ wc3,  const float* __restrict__ bc3,
    float* __restrict__ out, float* __restrict__ xw3, int n) {
    int node = blockIdx.x * 4 + (threadIdx.x >> 6);
    if (node >= n) return;
    int lane = threadIdx.x & 63;
    int s = rowptr[node], t = rowptr[node + 1];
    constexpr int U = 8;
    float2 acc = {0.f, 0.f};
    int p = s;
    for (; p + U <= t; p += U) {
        int rr[U]; float ww[U];
        #pragma unroll
        for (int u = 0; u < U; u++) {
            int2 q = csr[p + u];
            rr[u] = q.x; ww[u] = __int_as_float(q.y);
        }
        uint vv[U];
        #pragma unroll
        for (int u = 0; u < U; u++)
            vv[u] = *reinterpret_cast<const uint*>(&xw[(size_t)rr[u] * 128 + lane * 2]);
        #pragma unroll
        for (int u = 0; u < U; u++) {
            acc.x += ww[u] * bfu_lo(vv[u]);
            acc.y += ww[u] * bfu_hi(vv[u]);
        }
    }
    for (; p < t; ++p) {
        int2 q = csr[p];
        float w = __int_as_float(q.y);
        uint u = *reinterpret_cast<const uint*>(&xw[(size_t)q.x * 128 + lane * 2]);
        acc.x += w * bfu_lo(u);
        acc.y += w * bfu_hi(u);
    }
    float2 b = *reinterpret_cast<const float2*>(&b2[lane * 2]);
    float2 cur = *reinterpret_cast<const float2*>(&x5[(size_t)node * 128 + lane * 2]);
    cur.x += fmaxf(acc.x + b.x, 0.f);          // x7, register-only
    cur.y += fmaxf(acc.y + b.y, 0.f);

    float2 w1 = *reinterpret_cast<const float2*>(&wfc2[lane * 2]);
    float2 w2 = *reinterpret_cast<const float2*>(&wc3[lane * 2]);
    float s1 = cur.x * w1.x + cur.y * w1.y;
    float s2 = cur.x * w2.x + cur.y * w2.y;
    #pragma unroll
    for (int o = 32; o > 0; o >>= 1) {
        s1 += __shfl_down(s1, o);
        s2 += __shfl_down(s2, o);
    }
    if (lane == 0) {
        out[node] = s1 + bfc2[0] + bc3[0];
        xw3[node] = s2;
    }
}

__global__ __launch_bounds__(256) void k_agg1_csr(const float* __restrict__ sv,
                                                  const int* __restrict__ rowptr,
                                                  const int2* __restrict__ csr,
                                                  float* __restrict__ out, int n) {
    int i = blockIdx.x * 256 + threadIdx.x;
    if (i >= n) return;
    int s = rowptr[i], t = rowptr[i + 1];
    float a = 0.f;
    #pragma unroll 4
    for (int p = s; p < t; ++p) {
        int2 q = csr[p];
        a += __int_as_float(q.y) * sv[q.x];
    }
    out[i] += a;
}

// ---------------- weight fragment packing ----------------

// K=64 layer weights [64][256] -> B-frag order (hi + lo arrays; mm64 stays 3-term)
__global__ __launch_bounds__(256) void k_prepW64(const float* __restrict__ w0,
                                                 const float* __restrict__ w1,
                                                 ushort* __restrict__ W0f,
                                                 ushort* __restrict__ W1f) {
    int id = blockIdx.x * 256 + threadIdx.x;   // 2 mats * 4096
    if (id >= 8192) return;
    int mat = id >> 12;
    int rem = id & 4095;                       // arr*2048 + k0i*1024 + nt*64 + lane
    int lane = rem & 63;
    int nt = (rem >> 6) & 15;
    int k0i = (rem >> 10) & 1;
    int arr = rem >> 11;
    const float* w = mat ? w1 : w0;
    ushort* dst = mat ? W1f : W0f;
    int n = nt * 16 + (lane & 15);
    int kb = k0i * 32 + (lane >> 4) * 8;
    ushort o[8];
    #pragma unroll
    for (int j = 0; j < 8; j++) {
        float v = w[(size_t)(kb + j) * 256 + n];
        o[j] = arr ? bf16_bits(v - bf16_val(v)) : bf16_bits(v);
    }
    *reinterpret_cast<int4*>(&dst[(size_t)rem * 8]) = *reinterpret_cast<const int4*>(o);
}

// K=512 weights (w_fc1|w_conv2) -> Bf[k0i(16)][nt(16)][lane][8], single bf16
// (round-12: dropped the lo array — gemm2 runs pure bf16 on B; accuracy
// budget analysis gives ~4e-4 std added on x5/xw2, margin is 1.95e-3 vs 9e-3)
__global__ __launch_bounds__(256) void k_prepB(const float* __restrict__ w1,
                                               const float* __restrict__ w2,
                                               ushort* __restrict__ Bf) {
    int id = blockIdx.x * 256 + threadIdx.x;    // 16*16*64 = 16384
    if (id >= 16384) return;
    int lane = id & 63;
    int nt   = (id >> 6) & 15;
    int k0i  = (id >> 10) & 15;
    int n = nt * 16 + (lane & 15);
    int kbase = k0i * 32 + (lane >> 4) * 8;
    ushort outv[8];
    #pragma unroll
    for (int j = 0; j < 8; j++) {
        int k = kbase + j;
        float v = (n < 128) ? w1[(size_t)k * 128 + n]
                            : w2[(size_t)k * 128 + (n - 128)];
        outv[j] = bf16_bits(v);
    }
    *reinterpret_cast<int4*>(&Bf[(size_t)id * 8]) = *reinterpret_cast<const int4*>(outv);
}

// ---------------- MFMA GEMMs ----------------

// K=64 dual-layer MFMA GEMM (blockIdx.y = layer): unchanged 3-term split.
__global__ __launch_bounds__(256) void k_mm64(
    const ushort* __restrict__ xh, const ushort* __restrict__ xl,
    const ushort* __restrict__ ah_, const ushort* __restrict__ al_,
    const ushort* __restrict__ W0f, const ushort* __restrict__ W1f,
    const float* __restrict__ b0, const float* __restrict__ b1,
    ushort* __restrict__ Af, int M) {
    const int layer = blockIdx.y;
    const ushort* Ah = layer ? ah_ : xh;
    const ushort* Al = layer ? al_ : xl;
    const ushort* Wf = layer ? W1f : W0f;
    const float* bias = layer ? b1 : b0;
    const int colbase = layer * 256;

    const int t = threadIdx.x;
    const int lane = t & 63;
    const int wv = t >> 6;
    const int m0 = blockIdx.x * 64;
    const int ln15 = lane & 15;
    const int quad = lane >> 4;

    f32x4 acc[4][4] = {};

    #pragma unroll
    for (int k0i = 0; k0i < 2; k0i++) {
        short8 bh[4], bl[4];
        #pragma unroll
        for (int nt4 = 0; nt4 < 4; nt4++) {
            const ushort* pw = Wf + ((size_t)k0i * 16 + wv * 4 + nt4) * 512 + (size_t)lane * 8;
            bh[nt4] = *reinterpret_cast<const short8*>(pw);
            bl[nt4] = *reinterpret_cast<const short8*>(pw + 16384);   // arr=1 offset
        }
        #pragma unroll
        for (int mt = 0; mt < 4; mt++) {
            int gm = m0 + mt * 16 + ln15;
            int gmc = gm < M - 1 ? gm : M - 1;   // clamp: avoid OOB reads on tail rows
            size_t ia = (size_t)gmc * 64 + k0i * 32 + quad * 8;
            short8 ah = *reinterpret_cast<const short8*>(&Ah[ia]);
            short8 al = *reinterpret_cast<const short8*>(&Al[ia]);
            #pragma unroll
            for (int nt4 = 0; nt4 < 4; nt4++) {
                acc[mt][nt4] = __builtin_amdgcn_mfma_f32_16x16x32_bf16(ah, bh[nt4], acc[mt][nt4], 0, 0, 0);
                acc[mt][nt4] = __builtin_amdgcn_mfma_f32_16x16x32_bf16(ah, bl[nt4], acc[mt][nt4], 0, 0, 0);
                acc[mt][nt4] = __builtin_amdgcn_mfma_f32_16x16x32_bf16(al, bh[nt4], acc[mt][nt4], 0, 0, 0);
            }
        }
    }

    // epilogue: C layout col=lane&15, row=quad*4+r -> x3f fragment scatter (hi only)
    #pragma unroll
    for (int mt = 0; mt < 4; mt++) {
        #pragma unroll
        for (int nt4 = 0; nt4 < 4; nt4++) {
            int gn = wv * 64 + nt4 * 16 + ln15;      // local col 0..255
            int gcol = gn + colbase;                 // x3 col 0..511
            int k0f = gcol >> 5, qf = (gcol >> 3) & 3, j = gcol & 7;
            #pragma unroll
            for (int r = 0; r < 4; r++) {
                int gm = m0 + mt * 16 + quad * 4 + r;
                float v = fmaxf(acc[mt][nt4][r] + bias[gn], 0.f);
                size_t base = (((size_t)(gm >> 4)) * 16 + k0f) * 512 + (size_t)(qf * 16 + (gm & 15)) * 8 + j;
                Af[base] = bf16_bits(v);
            }
        }
    }
}

// LDS-free pure-bf16 MFMA dual GEMM, 32-row blocks, A and B register
// double-buffered. Round-11 post-mortem: B L2 re-read (2 arrays x 512KB/blk)
// + per-iter load:MFMA chain was the floor — single-bf16 B halves both.
//   [C1 | C2] = A[M,512] @ B^T[512,256]
//   C1 = relu(+bias1) -> x5 (fp32) ; C2 -> xw2 (packed bf16, gather payload)
__global__ __launch_bounds__(256) void k_gemm2_mfma(
    const ushort* __restrict__ Af, const ushort* __restrict__ Bf,
    const float* __restrict__ bias1,
    float* __restrict__ C1, ushort* __restrict__ C2, int M) {
    const int t = threadIdx.x;
    const int lane = t & 63;
    const int wv = t >> 6;
    const int mt0 = blockIdx.x * 2;          // two 16-row tiles per block
    const int ln15 = lane & 15;
    const int quad = lane >> 4;

    f32x4 acc[2][4] = {};

    const ushort* aPtr = Af + ((size_t)mt0 * 16) * 512 + (size_t)lane * 8;
    const ushort* bPtr = Bf + ((size_t)wv * 4) * 512 + (size_t)lane * 8;

    short8 aC[2], bC[4];
    #pragma unroll
    for (int mt = 0; mt < 2; mt++)
        aC[mt] = *reinterpret_cast<const short8*>(aPtr + (size_t)mt * 16 * 512);
    #pragma unroll
    for (int nt = 0; nt < 4; nt++)
        bC[nt] = *reinterpret_cast<const short8*>(bPtr + (size_t)nt * 512);

    for (int k0i = 0; k0i < 16; k0i++) {
        short8 aN[2], bN[4];
        if (k0i < 15) {
            #pragma unroll
            for (int mt = 0; mt < 2; mt++)
                aN[mt] = *reinterpret_cast<const short8*>(aPtr + ((size_t)mt * 16 + k0i + 1) * 512);
            #pragma unroll
            for (int nt = 0; nt < 4; nt++)
                bN[nt] = *reinterpret_cast<const short8*>(bPtr + ((size_t)(k0i + 1) * 16 + nt) * 512);
        }
        #pragma unroll
        for (int mt = 0; mt < 2; mt++)
            #pragma unroll
            for (int nt = 0; nt < 4; nt++)
                acc[mt][nt] = __builtin_amdgcn_mfma_f32_16x16x32_bf16(aC[mt], bC[nt], acc[mt][nt], 0, 0, 0);
        if (k0i < 15) {
            #pragma unroll
            for (int mt = 0; mt < 2; mt++) aC[mt] = aN[mt];
            #pragma unroll
            for (int nt = 0; nt < 4; nt++) bC[nt] = bN[nt];
        }
    }

    #pragma unroll
    for (int mt = 0; mt < 2; mt++) {
        #pragma unroll
        for (int nt = 0; nt < 4; nt++) {
            int gn = wv * 64 + nt * 16 + ln15;   // 0..255
            #pragma unroll
            for (int r = 0; r < 4; r++) {
                int gm = (mt0 + mt) * 16 + quad * 4 + r;
                if (gm >= M) continue;
                float v = acc[mt][nt][r];
                if (gn < 128) {
                    C1[(size_t)gm * 128 + gn] = fmaxf(v + bias1[gn], 0.f);
                } else {
                    C2[(size_t)gm * 128 + (gn - 128)] = bf16_bits(v);
                }
            }
        }
    }
}

extern "C" void kernel_launch(void* const* d_in, const int* in_sizes, int n_in,
                              void* d_out, int out_size, void* d_ws, size_t ws_size,
                              hipStream_t stream) {
    const float* x       = (const float*)d_in[0];
    const int*   ei      = (const int*)d_in[1];
    const float* w_fc    = (const float*)d_in[2];
    const float* b_fc    = (const float*)d_in[3];
    const float* w_conv1 = (const float*)d_in[4];
    const float* b_conv1 = (const float*)d_in[5];
    const float* w_fc1   = (const float*)d_in[6];
    const float* b_fc1   = (const float*)d_in[7];
    const float* w_conv2 = (const float*)d_in[8];
    const float* b_conv2 = (const float*)d_in[9];
    const float* w_fc2   = (const float*)d_in[10];
    const float* b_fc2   = (const float*)d_in[11];
    const float* w_conv3 = (const float*)d_in[12];
    const float* b_conv3 = (const float*)d_in[13];

    const int N = in_sizes[0] / 64;       // 50000
    const int E = in_sizes[1] / 2;        // 800000
    const int* row = ei;
    const int* col = ei + E;

    const int nb = (N + 255) / 256;
    const int nblk = (N + 63) / 64;       // 782  (64-row blocks, mm64)
    const int nblk2 = (N + 31) / 32;      // 1563 (32-row blocks, gemm2)
    const int Mt = nblk * 4;              // 3128 row-tiles of 16

    // workspace layout. alloc() takes 4-BYTE units (chunks padded to 16B).
    char* p = (char*)d_ws;
    auto alloc = [&](size_t elems) {
        void* q = p; p += ((elems + 3) & ~(size_t)3) * 4; return q;
    };
    int*    degi    = (int*)   alloc(N);
    int*    excl    = (int*)   alloc(N);
    int*    bsum    = (int*)   alloc(256);
    int*    rowptr  = (int*)   alloc(N + 4);
    int*    cursor  = (int*)   alloc(N);
    int2*   csr     = (int2*)  alloc((size_t)E * 2);       // packed {row, nrm}
    float*  dis     = (float*) alloc(N);
    ushort* xh      = (ushort*)alloc((size_t)N * 32);      // N*64 bf16 = N*32 words
    ushort* xl      = (ushort*)alloc((size_t)N * 32);
    ushort* agghi   = (ushort*)alloc((size_t)N * 32);
    ushort* agglo   = (ushort*)alloc((size_t)N * 32);
    ushort* x3f     = (ushort*)alloc((size_t)Mt * 4096);   // hi only: Mt*16*64*8 ushorts
    ushort* Bf      = (ushort*)alloc(65536);               // single bf16: 131072 ushorts
    ushort* W0f     = (ushort*)alloc(16384);               // 32768 ushorts
    ushort* W1f     = (ushort*)alloc(16384);
    float*  x5      = (float*) alloc((size_t)N * 128);
    ushort* xw2     = (ushort*)alloc((size_t)N * 64);      // N*128 bf16 = N*64 words
    float*  xw3     = (float*) alloc(N);

    float* out = (float*)d_out;

    // ---- CSR build ----
    hipMemsetAsync(degi, 0, (size_t)N * sizeof(int), stream);
    k_count<<<(E + 255) / 256, 256, 0, stream>>>(col, degi, E);
    k_scan1<<<nb, 256, 0, stream>>>(degi, excl, bsum, N);
    k_scan2<<<1, 256, 0, stream>>>(bsum, nb);
    k_scan3<<<nb, 256, 0, stream>>>(excl, bsum, degi, rowptr, cursor, dis, N, E);
    k_scatter<<<(E + 255) / 256, 256, 0, stream>>>(row, col, dis, cursor, csr, E);

    // input split + weight fragment packing (independent of CSR chain)
    k_prepX<<<(N * 16 + 255) / 256, 256, 0, stream>>>(x, xh, xl, N * 16);
    k_prepW64<<<8192 / 256, 256, 0, stream>>>(w_fc, w_conv1, W0f, W1f);
    k_prepB<<<16384 / 256, 256, 0, stream>>>(w_fc1, w_conv2, Bf);

    // conv1 propagate: agg = A_norm @ x (bf16 payload), 2 nodes/wave
    k_agg64_csr<<<(N + 7) / 8, 256, 0, stream>>>(xh, rowptr, csr, agghi, agglo, N);

    // x1/x2 layers via MFMA -> x3f fragments (single bf16)
    k_mm64<<<dim3(nblk, 2), 256, 0, stream>>>(xh, xl, agghi, agglo, W0f, W1f,
                                              b_fc, b_conv1, x3f, N);

    // x5 = relu(x3 @ w_fc1 + b_fc1) ; xw2 = x3 @ w_conv2 (pure bf16 MFMA)
    k_gemm2_mfma<<<nblk2, 256, 0, stream>>>(x3f, Bf, b_fc1, x5, xw2, N);

    // x7 = x5 + relu(A_norm @ xw2 + b_conv2) in registers; fused dual dot ->
    // out = x7·w_fc2 + b_fc2 + b_conv3 ; xw3 = x7·w_conv3
    k_agg128_x7dot<<<(N + 3) / 4, 256, 0, stream>>>(
        xw2, rowptr, csr, b_conv2, x5,
        w_fc2, b_fc2, w_conv3, b_conv3, out, xw3, N);

    // out += A_norm @ xw3
    k_agg1_csr<<<(N + 255) / 256, 256, 0, stream>>>(xw3, rowptr, csr, out, N);
}